// Round 9
// baseline (5474.534 us; speedup 1.0000x reference)
//
#include <hip/hip_runtime.h>

typedef unsigned short u16;
typedef unsigned int u32;
typedef __attribute__((ext_vector_type(8))) short bf16x8;
typedef __attribute__((ext_vector_type(4))) float f32x4;

#define SEQ 1024
#define DM 768
#define NH 12
#define HD2 64
#define NLAYER 4
#define NVOCAB 50257
#define BT 2048  // B*T

__device__ __forceinline__ u16 f2bf(float f) {
  union { float f; u32 u; } v; v.f = f;
  u32 r = v.u + 0x7FFFu + ((v.u >> 16) & 1u);
  return (u16)(r >> 16);
}
__device__ __forceinline__ float bf2f(u16 u) {
  union { u32 u; float f; } v; v.u = ((u32)u) << 16;
  return v.f;
}

__device__ __forceinline__ void glds16(const u16* g, u16* l) {
  __builtin_amdgcn_global_load_lds(
      (const __attribute__((address_space(1))) u32*)(const void*)g,
      (__attribute__((address_space(3))) u32*)(void*)l, 16, 0, 0);
}

// ---------------- embedding ----------------
__global__ void k_embed(const int* __restrict__ idx, const float* __restrict__ wte,
                        float* __restrict__ xf) {
  int r = blockIdx.x;
  int tok = idx[r];
  const float* s = wte + (size_t)tok * DM;
  float* d = xf + (size_t)r * DM;
  for (int c = threadIdx.x; c < DM; c += 256) d[c] = s[c];
}

// ---------------- rope trig tables: [SEQ][16] cos/sin ----------------
__global__ void k_trig(float* __restrict__ ctab, float* __restrict__ stab) {
  int gid = blockIdx.x * 256 + threadIdx.x;  // over SEQ*16
  int tt = gid >> 4, j = gid & 15;
  float inv = powf(10000.f, -(float)j * (1.f / 32.f));
  float ang = (float)tt * inv;
  ctab[gid] = cosf(ang);
  stab[gid] = sinf(ang);
}

// ------- transpose + f32->bf16: in[R,C] f32 -> out[C,R] bf16 (64x64 tile) ----
__global__ void k_cvtT(const float* __restrict__ in, u16* __restrict__ out,
                       int R, int C) {
  __shared__ u16 t[64][68];
  int c0 = blockIdx.x * 64, r0 = blockIdx.y * 64;  // R always multiple of 64
  int tx = threadIdx.x & 15, ty = threadIdx.x >> 4;
  int c = c0 + tx * 4;
#pragma unroll
  for (int i = 0; i < 4; ++i) {
    int r = r0 + ty + i * 16;
    float4 v = make_float4(0.f, 0.f, 0.f, 0.f);
    if (c + 3 < C) {
      v = *(const float4*)&in[(size_t)r * C + c];
    } else {
      if (c + 0 < C) v.x = in[(size_t)r * C + c];
      if (c + 1 < C) v.y = in[(size_t)r * C + c + 1];
      if (c + 2 < C) v.z = in[(size_t)r * C + c + 2];
      if (c + 3 < C) v.w = in[(size_t)r * C + c + 3];
    }
    t[ty + i * 16][tx * 4 + 0] = f2bf(v.x);
    t[ty + i * 16][tx * 4 + 1] = f2bf(v.y);
    t[ty + i * 16][tx * 4 + 2] = f2bf(v.z);
    t[ty + i * 16][tx * 4 + 3] = f2bf(v.w);
  }
  __syncthreads();
  int wl = threadIdx.x & 31, grp = threadIdx.x >> 5;
#pragma unroll
  for (int it = 0; it < 8; ++it) {
    int cc = it * 8 + grp;
    int gcol = c0 + cc;
    if (gcol < C) {
      u32 wv = (u32)t[2 * wl][cc] | ((u32)t[2 * wl + 1][cc] << 16);
      *(u32*)&out[(size_t)gcol * R + r0 + 2 * wl] = wv;
    }
  }
}

// ---------------- block reductions (256 thr = 4 waves) ----------------
__device__ __forceinline__ float bsum(float v, float* red) {
#pragma unroll
  for (int o = 32; o > 0; o >>= 1) v += __shfl_down(v, o);
  if ((threadIdx.x & 63) == 0) red[threadIdx.x >> 6] = v;
  __syncthreads();
  if (threadIdx.x == 0) red[4] = red[0] + red[1] + red[2] + red[3];
  __syncthreads();
  return red[4];
}

// ---------------- dual layernorm (both read same x) ----------------
__global__ void k_ln(const float* __restrict__ x, const float* __restrict__ g1,
                     const float* __restrict__ b1, const float* __restrict__ g2,
                     const float* __restrict__ b2, u16* __restrict__ o1,
                     u16* __restrict__ o2) {
  __shared__ float red[8];
  int r = blockIdx.x;
  int t = threadIdx.x;
  const float* xr = x + (size_t)r * DM;
  float v0 = xr[t], v1 = xr[t + 256], v2 = xr[t + 512];
  float mean = bsum(v0 + v1 + v2, red) * (1.f / DM);
  float d0 = v0 - mean, d1 = v1 - mean, d2 = v2 - mean;
  float var = bsum(d0 * d0 + d1 * d1 + d2 * d2, red) * (1.f / DM);
  float rstd = rsqrtf(var + 1e-5f);
  u16* p1 = o1 + (size_t)r * DM;
  p1[t]       = f2bf(d0 * rstd * g1[t]       + b1[t]);
  p1[t + 256] = f2bf(d1 * rstd * g1[t + 256] + b1[t + 256]);
  p1[t + 512] = f2bf(d2 * rstd * g1[t + 512] + b1[t + 512]);
  if (o2) {
    u16* p2 = o2 + (size_t)r * DM;
    p2[t]       = f2bf(d0 * rstd * g2[t]       + b2[t]);
    p2[t + 256] = f2bf(d1 * rstd * g2[t + 256] + b2[t + 256]);
    p2[t + 512] = f2bf(d2 * rstd * g2[t + 512] + b2[t + 512]);
  }
}

// ---------------- fused flash attention, glds-staged double-buffered K/V ----
__global__ void k_attn(const u16* __restrict__ qr, const u16* __restrict__ kr,
                       const u16* __restrict__ vT, u16* __restrict__ yb) {
  int ti = (int)gridDim.x - 1 - (int)blockIdx.x;  // big tiles first
  int bh = blockIdx.y;
  __shared__ u16 Ps[64 * 72];       // Q staging, then P tile (wave-private rows)
  __shared__ u16 Ks[2][4096];       // [64][64] XOR-swizzled
  __shared__ u16 Vs[2][4096];
  int tid = threadIdx.x;
  int rr = tid >> 2, cc = tid & 3;
  int w = tid >> 6, l = tid & 63;
  int rl = l & 15, g = l >> 4;
  {
    const u16* gq = qr + ((size_t)bh * SEQ + ti * 64 + rr) * HD2;
    *(uint4*)&Ps[rr * 72 + cc * 8]      = *(const uint4*)(gq + cc * 8);
    *(uint4*)&Ps[rr * 72 + cc * 8 + 32] = *(const uint4*)(gq + cc * 8 + 32);
  }
  int srow = w * 8 + (l >> 3);
  int gs = (l & 7) ^ (l >> 3);
  const u16* gkb = kr + (size_t)bh * SEQ * HD2;
  const u16* gvb = vT + (size_t)bh * HD2 * SEQ;
  glds16(gkb + (size_t)srow * 64 + gs * 8,        &Ks[0][w * 512]);
  glds16(gkb + (size_t)(32 + srow) * 64 + gs * 8, &Ks[0][2048 + w * 512]);
  glds16(gvb + (size_t)srow * SEQ + gs * 8,       &Vs[0][w * 512]);
  glds16(gvb + (size_t)(32 + srow) * SEQ + gs * 8,&Vs[0][2048 + w * 512]);
  __syncthreads();
  bf16x8 aq0 = *(const bf16x8*)&Ps[(w * 16 + rl) * 72 + g * 8];
  bf16x8 aq1 = *(const bf16x8*)&Ps[(w * 16 + rl) * 72 + 32 + g * 8];
  float m[4], lsum[4];
  f32x4 oacc[4] = {};
#pragma unroll
  for (int r2 = 0; r2 < 4; ++r2) { m[r2] = -3.0e38f; lsum[r2] = 0.f; }
  int qloc = w * 16 + g * 4;
  int sw = rl & 7;
  int cur = 0;
  for (int kt = 0; kt <= ti; ++kt) {
    if (kt < ti) {
      int nx = cur ^ 1;
      glds16(gkb + (size_t)((kt + 1) * 64 + srow) * 64 + gs * 8,      &Ks[nx][w * 512]);
      glds16(gkb + (size_t)((kt + 1) * 64 + 32 + srow) * 64 + gs * 8, &Ks[nx][2048 + w * 512]);
      glds16(gvb + (size_t)srow * SEQ + (kt + 1) * 64 + gs * 8,       &Vs[nx][w * 512]);
      glds16(gvb + (size_t)(32 + srow) * SEQ + (kt + 1) * 64 + gs * 8,&Vs[nx][2048 + w * 512]);
    }
    f32x4 s[4] = {};
    __builtin_amdgcn_s_setprio(1);
#pragma unroll
    for (int nt = 0; nt < 4; ++nt) {
      int r = (nt * 16 + rl) * 64;
      bf16x8 b0 = *(const bf16x8*)&Ks[cur][r + ((0 + g) ^ sw) * 8];
      bf16x8 b1 = *(const bf16x8*)&Ks[cur][r + ((4 + g) ^ sw) * 8];
      s[nt] = __builtin_amdgcn_mfma_f32_16x16x32_bf16(aq0, b0, s[nt], 0, 0, 0);
      s[nt] = __builtin_amdgcn_mfma_f32_16x16x32_bf16(aq1, b1, s[nt], 0, 0, 0);
    }
    __builtin_amdgcn_s_setprio(0);
#pragma unroll
    for (int nt = 0; nt < 4; ++nt) s[nt] *= 0.125f;
    if (kt == ti) {
#pragma unroll
      for (int nt = 0; nt < 4; ++nt) {
        int col = nt * 16 + rl;
#pragma unroll
        for (int r2 = 0; r2 < 4; ++r2)
          if (col > qloc + r2) s[nt][r2] = -3.0e38f;
      }
    }
#pragma unroll
    for (int r2 = 0; r2 < 4; ++r2) {
      float pm = fmaxf(fmaxf(s[0][r2], s[1][r2]), fmaxf(s[2][r2], s[3][r2]));
#pragma unroll
      for (int o = 1; o < 16; o <<= 1) pm = fmaxf(pm, __shfl_xor(pm, o));
      float mn = fmaxf(m[r2], pm);
      float corr = __expf(m[r2] - mn);
      float p0 = __expf(s[0][r2] - mn);
      float p1 = __expf(s[1][r2] - mn);
      float p2 = __expf(s[2][r2] - mn);
      float p3 = __expf(s[3][r2] - mn);
      float ps = p0 + p1 + p2 + p3;
#pragma unroll
      for (int o = 1; o < 16; o <<= 1) ps += __shfl_xor(ps, o);
      lsum[r2] = lsum[r2] * corr + ps;
      m[r2] = mn;
      oacc[0][r2] *= corr; oacc[1][r2] *= corr;
      oacc[2][r2] *= corr; oacc[3][r2] *= corr;
      int prow = (qloc + r2) * 72;
      Ps[prow + rl]      = f2bf(p0);
      Ps[prow + 16 + rl] = f2bf(p1);
      Ps[prow + 32 + rl] = f2bf(p2);
      Ps[prow + 48 + rl] = f2bf(p3);
    }
    bf16x8 pa0 = *(const bf16x8*)&Ps[(w * 16 + rl) * 72 + g * 8];
    bf16x8 pa1 = *(const bf16x8*)&Ps[(w * 16 + rl) * 72 + 32 + g * 8];
    __builtin_amdgcn_s_setprio(1);
#pragma unroll
    for (int nt = 0; nt < 4; ++nt) {
      int r = (nt * 16 + rl) * 64;
      bf16x8 b0 = *(const bf16x8*)&Vs[cur][r + ((0 + g) ^ sw) * 8];
      bf16x8 b1 = *(const bf16x8*)&Vs[cur][r + ((4 + g) ^ sw) * 8];
      oacc[nt] = __builtin_amdgcn_mfma_f32_16x16x32_bf16(pa0, b0, oacc[nt], 0, 0, 0);
      oacc[nt] = __builtin_amdgcn_mfma_f32_16x16x32_bf16(pa1, b1, oacc[nt], 0, 0, 0);
    }
    __builtin_amdgcn_s_setprio(0);
    __syncthreads();
    cur ^= 1;
  }
  int b = bh / NH, h = bh % NH;
  float invl[4];
#pragma unroll
  for (int r2 = 0; r2 < 4; ++r2) invl[r2] = 1.f / lsum[r2];
#pragma unroll
  for (int nt = 0; nt < 4; ++nt) {
    int d = nt * 16 + rl;
#pragma unroll
    for (int r2 = 0; r2 < 4; ++r2) {
      int trow = ti * 64 + qloc + r2;
      yb[((size_t)(b * SEQ + trow)) * DM + h * HD2 + d] = f2bf(oacc[nt][r2] * invl[r2]);
    }
  }
}

// ------- 128x128 GEMM, BK=32, dbuf single-sync loop (round-7 proven) --------
// modes: 1 bf16 gelu out (+bias); 3 f32 nontemporal out;
//        4 fused qkv: bias + rope(q,k) -> qr/kr [bh][t][d]; v -> vT [bh][d][t]
__global__ void k_g128(const u16* __restrict__ A, const u16* __restrict__ Bt,
                       const float* __restrict__ bias, u16* __restrict__ outb,
                       float* __restrict__ outf, int M, int N, int K, int MT,
                       int mode, const float* __restrict__ ctab,
                       const float* __restrict__ stab, u16* __restrict__ qrp,
                       u16* __restrict__ krp, u16* __restrict__ vTp) {
  __shared__ u16 SM[16384];  // [As0|Bs0|As1|Bs1] 4096 u16 each; alias cw[32][132]
  float* cw = (float*)SM;
  int nwg = gridDim.x;
  int id = blockIdx.x;
  if ((nwg & 7) == 0) id = (id & 7) * (nwg >> 3) + (id >> 3);  // XCD swizzle
  int mt = id % MT, nt = id / MT;
  int m0 = mt * 128, n0 = nt * 128;
  int tid = threadIdx.x;
  int w = tid >> 6, l = tid & 63;
  int srow = w * 16 + (l >> 2);
  int gs = (l & 3) ^ ((l >> 3) & 3);    // pre-swizzled source chunk
  const u16* gA0 = A + (size_t)(m0 + srow) * K + gs * 8;
  const u16* gA1 = A + (size_t)(m0 + 64 + srow) * K + gs * 8;
  int rb0 = n0 + srow;      if (rb0 > N - 1) rb0 = N - 1;
  int rb1 = n0 + 64 + srow; if (rb1 > N - 1) rb1 = N - 1;
  const u16* gB0 = Bt + (size_t)rb0 * K + gs * 8;
  const u16* gB1 = Bt + (size_t)rb1 * K + gs * 8;
  int wm = (w >> 1) * 64, wn = (w & 1) * 64;
  int rl = l & 15, g = l >> 4;
  int sla = g ^ ((rl >> 1) & 3);  // read-side swizzle (lane-constant)
  f32x4 acc[4][4] = {};
  int nK = K >> 5;
  int cur = 0;
  {  // prologue: stage kt=0 into buf0
    u16* dA = SM + w * 512;
    glds16(gA0, dA); glds16(gA1, dA + 2048);
    u16* dB = SM + 4096 + w * 512;
    glds16(gB0, dB); glds16(gB1, dB + 2048);
  }
  __syncthreads();
  for (int kt = 0; kt < nK; ++kt) {
    if (kt + 1 < nK) {  // issue next-tile stage before compute
      u16* dA = SM + (cur ^ 1) * 8192 + w * 512;
      glds16(gA0 + (kt + 1) * 32, dA); glds16(gA1 + (kt + 1) * 32, dA + 2048);
      u16* dB = dA + 4096;
      glds16(gB0 + (kt + 1) * 32, dB); glds16(gB1 + (kt + 1) * 32, dB + 2048);
    }
    const u16* As = SM + cur * 8192;
    const u16* Bs = As + 4096;
    bf16x8 af[4], bfr[4];
    __builtin_amdgcn_s_setprio(1);
#pragma unroll
    for (int i = 0; i < 4; ++i)
      af[i] = *(const bf16x8*)&As[(wm + i * 16 + rl) * 32 + sla * 8];
#pragma unroll
    for (int j = 0; j < 4; ++j)
      bfr[j] = *(const bf16x8*)&Bs[(wn + j * 16 + rl) * 32 + sla * 8];
#pragma unroll
    for (int i = 0; i < 4; ++i)
#pragma unroll
      for (int j = 0; j < 4; ++j)
        acc[i][j] = __builtin_amdgcn_mfma_f32_16x16x32_bf16(af[i], bfr[j],
                                                            acc[i][j], 0, 0, 0);
    __builtin_amdgcn_s_setprio(0);
    __syncthreads();
    cur ^= 1;
  }
  // region/head decode for mode 4 (tiles never straddle q/k/v: DM%128==0)
  int reg = n0 / DM;
  int h0 = (n0 % DM) / 64;
  int bb = m0 >> 10;             // SEQ=1024, 1024%128==0 -> whole tile one batch
  int t0 = m0 & (SEQ - 1);
  size_t bhbase = (size_t)bb * NH;
  // epilogue: 32-row chunks through LDS
  for (int ch = 0; ch < 4; ++ch) {
    if ((w >> 1) == (ch >> 1)) {
      int ib = (ch & 1) * 2;
#pragma unroll
      for (int ii = 0; ii < 2; ++ii) {
#pragma unroll
        for (int j = 0; j < 4; ++j) {
          int col = wn + j * 16 + rl;
#pragma unroll
          for (int r2 = 0; r2 < 4; ++r2) {
            int rowc = ii * 16 + g * 4 + r2;
            float v = acc[ib + ii][j][r2];
            if (mode != 3) {
              v += bias[n0 + col];
              if (mode == 1) {
                float u = 0.7978845608028654f * (v + 0.044715f * v * v * v);
                v = 0.5f * v * (1.f + tanhf(u));
              }
            }
            cw[rowc * 132 + col] = v;
          }
        }
      }
    }
    __syncthreads();
    if (mode == 3) {
      for (int t = tid; t < 4096; t += 256) {
        int rowc = t >> 7, col = t & 127;
        int gc = n0 + col;
        if (gc < N)
          __builtin_nontemporal_store(cw[rowc * 132 + col],
                                      &outf[(size_t)(m0 + ch * 32 + rowc) * N + gc]);
      }
    } else if (mode == 1) {  // bf16 packed u32 writes (N multiple of 128)
      for (int t = tid; t < 2048; t += 256) {
        int rowc = t >> 6, cp = t & 63;
        u32 wv = (u32)f2bf(cw[rowc * 132 + 2 * cp]) |
                 ((u32)f2bf(cw[rowc * 132 + 2 * cp + 1]) << 16);
        *(u32*)&outb[(size_t)(m0 + ch * 32 + rowc) * N + n0 + 2 * cp] = wv;
      }
    } else if (reg < 2) {  // mode 4: q/k rope writes
      u16* dst = (reg == 0) ? qrp : krp;
      for (int t = tid; t < 2048; t += 256) {
        int rowc = t >> 6, cp = t & 63;
        int c = 2 * cp;               // col (even), 0..126
        int hh = c >> 6, d = c & 63;  // head sub-index, local dim (even)
        int tt = t0 + ch * 32 + rowc;
        float x0 = cw[rowc * 132 + c];
        float x1 = cw[rowc * 132 + c + 1];
        float o0, o1;
        if (d < 32) {
          float y0 = cw[rowc * 132 + c + 32];
          float y1 = cw[rowc * 132 + c + 33];
          float c0 = 1.f, s0 = 0.f, c1 = 1.f, s1 = 0.f;
          if (d < 16) {
            c0 = ctab[tt * 16 + d];     s0 = stab[tt * 16 + d];
            c1 = ctab[tt * 16 + d + 1]; s1 = stab[tt * 16 + d + 1];
          }
          o0 = x0 * c0 - y0 * s0;
          o1 = x1 * c1 - y1 * s1;
        } else {
          int j = d - 32;
          float y0 = cw[rowc * 132 + c - 32];
          float y1 = cw[rowc * 132 + c - 31];
          float c0 = 1.f, s0 = 0.f, c1 = 1.f, s1 = 0.f;
          if (j < 16) {
            c0 = ctab[tt * 16 + j];     s0 = stab[tt * 16 + j];
            c1 = ctab[tt * 16 + j + 1]; s1 = stab[tt * 16 + j + 1];
          }
          o0 = x0 * c0 + y0 * s0;
          o1 = x1 * c1 + y1 * s1;
        }
        u32 wv = (u32)f2bf(o0) | ((u32)f2bf(o1) << 16);
        *(u32*)&dst[((bhbase + h0 + hh) * SEQ + tt) * HD2 + d] = wv;
      }
    } else {  // mode 4: v transposed write vT[bh][d][t], 2 tokens per u32
      for (int t = tid; t < 2048; t += 256) {
        int dcol = t >> 4, p = t & 15;    // col 0..127, token-pair 0..15
        int hh = dcol >> 6, d = dcol & 63;
        int tt = t0 + ch * 32 + 2 * p;
        u32 wv = (u32)f2bf(cw[(2 * p) * 132 + dcol]) |
                 ((u32)f2bf(cw[(2 * p + 1) * 132 + dcol]) << 16);
        *(u32*)&vTp[((bhbase + h0 + hh) * HD2 + d) * SEQ + tt] = wv;
      }
    }
    __syncthreads();
  }
}

// ------- 64x64-tile GEMM, BK=64, dbuf, split-K (wo / wp residual adds) ------
// mode 2: f32 atomic residual add (+bias at sk0)
__global__ void k_gemm64(const u16* __restrict__ A, const u16* __restrict__ Bt,
                         const float* __restrict__ bias,
                         float* __restrict__ outf, int M, int N, int K, int MT) {
  __shared__ u16 As[8192];  // 2 x [64][64]
  __shared__ u16 Bs[8192];
  int nwg = gridDim.x;
  int id = blockIdx.x;
  if ((nwg & 7) == 0) id = (id & 7) * (nwg >> 3) + (id >> 3);  // XCD swizzle
  int mt = id % MT, nt = id / MT;
  int sk = blockIdx.y, nsk = gridDim.y;
  int Kc = K / nsk, k0 = sk * Kc;
  int m0 = mt * 64, n0 = nt * 64;
  int tid = threadIdx.x;
  int w = tid >> 6, l = tid & 63;
  int row0 = tid >> 3, slot0 = tid & 7;
  int gs0 = slot0 ^ (row0 & 7);
  const u16* gA0 = A + (size_t)(m0 + row0) * K + k0 + gs0 * 8;
  const u16* gA1 = gA0 + (size_t)32 * K;
  const u16* gB0 = Bt + (size_t)(n0 + row0) * K + k0 + gs0 * 8;
  const u16* gB1 = gB0 + (size_t)32 * K;
  int wm = (w >> 1) * 32, wn = (w & 1) * 32;
  int rl = l & 15, g = l >> 4;
  int sl0 = g ^ (rl & 7), sl1 = (4 + g) ^ (rl & 7);
  f32x4 acc[2][2] = {};
  int nK = Kc >> 6;
  int cur = 0;
  {  // prologue stage kt=0 -> buf0
    glds16(gA0, As + w * 512); glds16(gA1, As + 2048 + w * 512);
    glds16(gB0, Bs + w * 512); glds16(gB1, Bs + 2048 + w * 512);
  }
  __syncthreads();
  for (int kt = 0; kt < nK; ++kt) {
    if (kt + 1 < nK) {
      int nx = (cur ^ 1) * 4096;
      glds16(gA0 + (kt + 1) * 64, As + nx + w * 512);
      glds16(gA1 + (kt + 1) * 64, As + nx + 2048 + w * 512);
      glds16(gB0 + (kt + 1) * 64, Bs + nx + w * 512);
      glds16(gB1 + (kt + 1) * 64, Bs + nx + 2048 + w * 512);
    }
    const u16* Ac = As + cur * 4096;
    const u16* Bc = Bs + cur * 4096;
    bf16x8 a0[2], a1[2], b0[2], b1[2];
    __builtin_amdgcn_s_setprio(1);
#pragma unroll
    for (int i = 0; i < 2; ++i) {
      int r = (wm + i * 16 + rl) * 64;
      a0[i] = *(const bf16x8*)&Ac[r + sl0 * 8];
      a1[i] = *(const bf16x8*)&Ac[r + sl1 * 8];
    }
#pragma unroll
    for (int j = 0; j < 2; ++j) {
      int r = (wn + j * 16 + rl) * 64;
      b0[j] = *(const bf16x8*)&Bc[r + sl0 * 8];
      b1[j] = *(const bf16x8*)&Bc[r + sl1 * 8];
    }
#pragma unroll
    for (int i = 0; i < 2; ++i)
#pragma unroll
      for (int j = 0; j < 2; ++j) {
        acc[i][j] = __builtin_amdgcn_mfma_f32_16x16x32_bf16(a0[i], b0[j],
                                                            acc[i][j], 0, 0, 0);
        acc[i][j] = __builtin_amdgcn_mfma_f32_16x16x32_bf16(a1[i], b1[j],
                                                            acc[i][j], 0, 0, 0);
      }
    __builtin_amdgcn_s_setprio(0);
    __syncthreads();
    cur ^= 1;
  }
#pragma unroll
  for (int i = 0; i < 2; ++i) {
#pragma unroll
    for (int j = 0; j < 2; ++j) {
      int col = n0 + wn + j * 16 + rl;
      float bv = bias ? bias[col] : 0.f;
#pragma unroll
      for (int r2 = 0; r2 < 4; ++r2) {
        int row = m0 + wm + i * 16 + g * 4 + r2;
        float v = acc[i][j][r2];
        if (sk == 0) v += bv;
        atomicAdd(&outf[(size_t)row * N + col], v);
      }
    }
  }
}

// ---------------- fallback GEMM (f32 B, on-the-fly cvt) — logits only --------
__global__ void k_gemm_f32b(const u16* __restrict__ A, const float* __restrict__ B,
                            float* __restrict__ outf, int M, int N, int K) {
  __shared__ u16 As[128 * 40];
  __shared__ u16 Bs[4 * 128 * 12];
  int tid = threadIdx.x;
  int wid = tid >> 6, lane = tid & 63;
  int rl = lane & 15, g = lane >> 4;
  int m0 = blockIdx.x * 128, n0 = blockIdx.y * 128;
  int wm = (wid >> 1) * 64, wn = (wid & 1) * 64;
  int ar = tid >> 2, ac = tid & 3;
  int bn = tid & 127, bq = tid >> 7;
  f32x4 acc[4][4] = {};
  int nK = K / 32;
  for (int kt = 0; kt < nK; ++kt) {
    __syncthreads();
    {
      const u16* ga = A + (size_t)(m0 + ar) * K + kt * 32 + ac * 8;
      *(uint4*)&As[ar * 40 + ac * 8] = *(const uint4*)ga;
      *(uint4*)&As[(ar + 64) * 40 + ac * 8] = *(const uint4*)(ga + (size_t)64 * K);
    }
    int col = n0 + bn;
#pragma unroll
    for (int r = 0; r < 4; ++r) {
      int kq = bq + 2 * r;
      int kk = kt * 32 + kq * 4;
      float f0 = 0.f, f1 = 0.f, f2v = 0.f, f3 = 0.f;
      if (col < N) {
        const float* gb = B + (size_t)kk * N + col;
        f0 = gb[0]; f1 = gb[(size_t)N]; f2v = gb[(size_t)2 * N]; f3 = gb[(size_t)3 * N];
      }
      uint2 wv;
      wv.x = (u32)f2bf(f0) | ((u32)f2bf(f1) << 16);
      wv.y = (u32)f2bf(f2v) | ((u32)f2bf(f3) << 16);
      *(uint2*)&Bs[(kq >> 1) * 1536 + bn * 12 + (kq & 1) * 4] = wv;
    }
    __syncthreads();
    bf16x8 af[4], bfr[4];
#pragma unroll
    for (int mt = 0; mt < 4; ++mt)
      af[mt] = *(const bf16x8*)&As[(wm + mt * 16 + rl) * 40 + g * 8];
#pragma unroll
    for (int nt = 0; nt < 4; ++nt) {
      const u16* p = &Bs[g * 1536 + (wn + nt * 16 + rl) * 12];
      union { bf16x8 v; uint2 u2[2]; } tmp;
      tmp.u2[0] = *(const uint2*)p;
      tmp.u2[1] = *(const uint2*)(p + 4);
      bfr[nt] = tmp.v;
    }
#pragma unroll
    for (int mt = 0; mt < 4; ++mt)
#pragma unroll
      for (int nt = 0; nt < 4; ++nt)
        acc[mt][nt] = __builtin_amdgcn_mfma_f32_16x16x32_bf16(af[mt], bfr[nt],
                                                              acc[mt][nt], 0, 0, 0);
  }
#pragma unroll
  for (int mt = 0; mt < 4; ++mt)
#pragma unroll
    for (int nt = 0; nt < 4; ++nt) {
      int col = n0 + wn + nt * 16 + rl;
      if (col >= N) continue;
#pragma unroll
      for (int r2 = 0; r2 < 4; ++r2) {
        int row = m0 + wm + mt * 16 + g * 4 + r2;
        outf[(size_t)row * N + col] = acc[mt][nt][r2];
      }
    }
}

extern "C" void kernel_launch(void* const* d_in, const int* in_sizes, int n_in,
                              void* d_out, int out_size, void* d_ws, size_t ws_size,
                              hipStream_t stream) {
  (void)in_sizes; (void)n_in; (void)out_size;
  const int*   idx  = (const int*)  d_in[0];
  const float* wte  = (const float*)d_in[1];
  const float* ln1g = (const float*)d_in[2];
  const float* ln1b = (const float*)d_in[3];
  const float* Wqkv = (const float*)d_in[4];
  const float* bqkv = (const float*)d_in[5];
  const float* Wo   = (const float*)d_in[6];
  const float* bo   = (const float*)d_in[7];
  const float* ln2g = (const float*)d_in[8];
  const float* ln2b = (const float*)d_in[9];
  const float* Wfc  = (const float*)d_in[10];
  const float* bfc  = (const float*)d_in[11];
  const float* Wp   = (const float*)d_in[12];
  const float* bp   = (const float*)d_in[13];
  const float* lnfg = (const float*)d_in[14];
  const float* lnfb = (const float*)d_in[15];
  const float* Wlm  = (const float*)d_in[16];
  float* out = (float*)d_out;

  // Scratch packed into d_out (all dead before the logits GEMM rewrites d_out).
  char* sb = (char*)d_out;
  size_t off = 0;
  auto alloc = [&](size_t bytes) {
    char* p = sb + off;
    off += (bytes + 255) & ~(size_t)255;
    return (void*)p;
  };
  float* xf  = (float*)alloc((size_t)BT * DM * 4);
  u16* h1b   = (u16*)alloc((size_t)BT * DM * 2);
  u16* h2b   = (u16*)alloc((size_t)BT * DM * 2);
  u16* qr    = (u16*)alloc((size_t)BT * DM * 2);
  u16* kr    = (u16*)alloc((size_t)BT * DM * 2);
  u16* vT    = (u16*)alloc((size_t)BT * DM * 2);
  u16* yb    = (u16*)alloc((size_t)BT * DM * 2);
  u16* hgel  = (u16*)alloc((size_t)BT * 4 * DM * 2);
  float* ctab = (float*)alloc((size_t)SEQ * 16 * 4);
  float* stab = (float*)alloc((size_t)SEQ * 16 * 4);
  // transposed bf16 weights (also dead before logits GEMM)
  u16* wqkvT = (u16*)alloc((size_t)NLAYER * 3 * DM * DM * 2);
  u16* woT   = (u16*)alloc((size_t)NLAYER * DM * DM * 2);
  u16* wfcT  = (u16*)alloc((size_t)NLAYER * 4 * DM * DM * 2);
  u16* wpT   = (u16*)alloc((size_t)NLAYER * 4 * DM * DM * 2);

  // Wlm^T (77 MB) must survive the logits GEMM -> d_ws if it fits.
  size_t wlmT_bytes = (size_t)NVOCAB * DM * 2;
  size_t xlnf_bytes = (size_t)BT * DM * 2;
  bool fast_lm = ws_size >= wlmT_bytes + xlnf_bytes + 512;
  u16* wlmT = (u16*)d_ws;
  u16* xlnf = fast_lm ? (u16*)((char*)d_ws + ((wlmT_bytes + 255) & ~(size_t)255))
                      : (u16*)d_ws;

  // ---- weight conversion + trig tables ----
  k_trig<<<(SEQ * 16) / 256, 256, 0, stream>>>(ctab, stab);
  for (int l = 0; l < NLAYER; ++l) {
    k_cvtT<<<dim3((3 * DM + 63) / 64, DM / 64), 256, 0, stream>>>(
        Wqkv + (size_t)l * DM * 3 * DM, wqkvT + (size_t)l * 3 * DM * DM, DM, 3 * DM);
    k_cvtT<<<dim3(DM / 64, DM / 64), 256, 0, stream>>>(
        Wo + (size_t)l * DM * DM, woT + (size_t)l * DM * DM, DM, DM);
    k_cvtT<<<dim3((4 * DM) / 64, DM / 64), 256, 0, stream>>>(
        Wfc + (size_t)l * DM * 4 * DM, wfcT + (size_t)l * 4 * DM * DM, DM, 4 * DM);
    k_cvtT<<<dim3(DM / 64, (4 * DM) / 64), 256, 0, stream>>>(
        Wp + (size_t)l * 4 * DM * DM, wpT + (size_t)l * 4 * DM * DM, 4 * DM, DM);
  }
  if (fast_lm)
    k_cvtT<<<dim3((NVOCAB + 63) / 64, DM / 64), 256, 0, stream>>>(Wlm, wlmT, DM, NVOCAB);

  k_embed<<<BT, 256, 0, stream>>>(idx, wte, xf);
  for (int l = 0; l < NLAYER; ++l) {
    k_ln<<<BT, 256, 0, stream>>>(xf, ln1g + l * DM, ln1b + l * DM,
                                 ln2g + l * DM, ln2b + l * DM, h1b, h2b);
    // fused qkv GEMM + bias + rope + v-transpose (128^2 tile)
    k_g128<<<(BT / 128) * (3 * DM / 128), 256, 0, stream>>>(
        h1b, wqkvT + (size_t)l * 3 * DM * DM, bqkv + (size_t)l * 3 * DM,
        nullptr, nullptr, BT, 3 * DM, DM, BT / 128, 4, ctab, stab, qr, kr, vT);
    k_attn<<<dim3(SEQ / 64, 2 * NH), 256, 0, stream>>>(qr, kr, vT, yb);
    k_gemm64<<<dim3((BT / 64) * (DM / 64), 2), 256, 0, stream>>>(
        yb, woT + (size_t)l * DM * DM, bo + (size_t)l * DM, xf, BT, DM, DM, BT / 64);
    k_g128<<<(BT / 128) * (4 * DM / 128), 256, 0, stream>>>(
        h2b, wfcT + (size_t)l * 4 * DM * DM, bfc + (size_t)l * 4 * DM,
        hgel, nullptr, BT, 4 * DM, DM, BT / 128, 1,
        nullptr, nullptr, nullptr, nullptr, nullptr);
    k_gemm64<<<dim3((BT / 64) * (DM / 64), 4), 256, 0, stream>>>(
        hgel, wpT + (size_t)l * 4 * DM * DM, bp + (size_t)l * DM, xf, BT, DM, 4 * DM,
        BT / 64);
  }
  k_ln<<<BT, 256, 0, stream>>>(xf, lnfg, lnfb, nullptr, nullptr, xlnf, nullptr);
  if (fast_lm) {
    int nt = (NVOCAB + 127) / 128;
    k_g128<<<(BT / 128) * nt, 256, 0, stream>>>(
        xlnf, wlmT, nullptr, nullptr, out, BT, NVOCAB, DM, BT / 128, 3,
        nullptr, nullptr, nullptr, nullptr, nullptr);
  } else {
    k_gemm_f32b<<<dim3(BT / 128, (NVOCAB + 127) / 128), 256, 0, stream>>>(
        xlnf, Wlm, out, BT, NVOCAB, DM);
  }
}

// Round 10
// 1056.968 us; speedup vs baseline: 5.1795x; 5.1795x over previous
//
#include <hip/hip_runtime.h>

typedef unsigned short u16;
typedef unsigned int u32;
typedef __attribute__((ext_vector_type(8))) short bf16x8;
typedef __attribute__((ext_vector_type(4))) float f32x4;

#define SEQ 1024
#define DM 768
#define NH 12
#define HD2 64
#define NLAYER 4
#define NVOCAB 50257
#define BT 2048  // B*T

__device__ __forceinline__ u16 f2bf(float f) {
  union { float f; u32 u; } v; v.f = f;
  u32 r = v.u + 0x7FFFu + ((v.u >> 16) & 1u);
  return (u16)(r >> 16);
}
__device__ __forceinline__ float bf2f(u16 u) {
  union { u32 u; float f; } v; v.u = ((u32)u) << 16;
  return v.f;
}

__device__ __forceinline__ void glds16(const u16* g, u16* l) {
  __builtin_amdgcn_global_load_lds(
      (const __attribute__((address_space(1))) u32*)(const void*)g,
      (__attribute__((address_space(3))) u32*)(void*)l, 16, 0, 0);
}

// ---------------- embedding ----------------
__global__ void k_embed(const int* __restrict__ idx, const float* __restrict__ wte,
                        float* __restrict__ xf) {
  int r = blockIdx.x;
  int tok = idx[r];
  const float* s = wte + (size_t)tok * DM;
  float* d = xf + (size_t)r * DM;
  for (int c = threadIdx.x; c < DM; c += 256) d[c] = s[c];
}

// ---------------- rope trig tables: [SEQ][16] cos/sin ----------------
__global__ void k_trig(float* __restrict__ ctab, float* __restrict__ stab) {
  int gid = blockIdx.x * 256 + threadIdx.x;  // over SEQ*16
  int tt = gid >> 4, j = gid & 15;
  float inv = powf(10000.f, -(float)j * (1.f / 32.f));
  float ang = (float)tt * inv;
  ctab[gid] = cosf(ang);
  stab[gid] = sinf(ang);
}

// ------- transpose + f32->bf16: in[R,C] f32 -> out[C,R] bf16 (64x64 tile) ----
__global__ void k_cvtT(const float* __restrict__ in, u16* __restrict__ out,
                       int R, int C) {
  __shared__ u16 t[64][68];
  int c0 = blockIdx.x * 64, r0 = blockIdx.y * 64;  // R always multiple of 64
  int tx = threadIdx.x & 15, ty = threadIdx.x >> 4;
  int c = c0 + tx * 4;
#pragma unroll
  for (int i = 0; i < 4; ++i) {
    int r = r0 + ty + i * 16;
    float4 v = make_float4(0.f, 0.f, 0.f, 0.f);
    if (c + 3 < C) {
      v = *(const float4*)&in[(size_t)r * C + c];
    } else {
      if (c + 0 < C) v.x = in[(size_t)r * C + c];
      if (c + 1 < C) v.y = in[(size_t)r * C + c + 1];
      if (c + 2 < C) v.z = in[(size_t)r * C + c + 2];
      if (c + 3 < C) v.w = in[(size_t)r * C + c + 3];
    }
    t[ty + i * 16][tx * 4 + 0] = f2bf(v.x);
    t[ty + i * 16][tx * 4 + 1] = f2bf(v.y);
    t[ty + i * 16][tx * 4 + 2] = f2bf(v.z);
    t[ty + i * 16][tx * 4 + 3] = f2bf(v.w);
  }
  __syncthreads();
  int wl = threadIdx.x & 31, grp = threadIdx.x >> 5;
#pragma unroll
  for (int it = 0; it < 8; ++it) {
    int cc = it * 8 + grp;
    int gcol = c0 + cc;
    if (gcol < C) {
      u32 wv = (u32)t[2 * wl][cc] | ((u32)t[2 * wl + 1][cc] << 16);
      *(u32*)&out[(size_t)gcol * R + r0 + 2 * wl] = wv;
    }
  }
}

// ---------------- block reductions (256 thr = 4 waves) ----------------
__device__ __forceinline__ float bsum(float v, float* red) {
#pragma unroll
  for (int o = 32; o > 0; o >>= 1) v += __shfl_down(v, o);
  if ((threadIdx.x & 63) == 0) red[threadIdx.x >> 6] = v;
  __syncthreads();
  if (threadIdx.x == 0) red[4] = red[0] + red[1] + red[2] + red[3];
  __syncthreads();
  return red[4];
}

// ---------------- dual layernorm (both read same x) ----------------
__global__ void k_ln(const float* __restrict__ x, const float* __restrict__ g1,
                     const float* __restrict__ b1, const float* __restrict__ g2,
                     const float* __restrict__ b2, u16* __restrict__ o1,
                     u16* __restrict__ o2) {
  __shared__ float red[8];
  int r = blockIdx.x;
  int t = threadIdx.x;
  const float* xr = x + (size_t)r * DM;
  float v0 = xr[t], v1 = xr[t + 256], v2 = xr[t + 512];
  float mean = bsum(v0 + v1 + v2, red) * (1.f / DM);
  float d0 = v0 - mean, d1 = v1 - mean, d2 = v2 - mean;
  float var = bsum(d0 * d0 + d1 * d1 + d2 * d2, red) * (1.f / DM);
  float rstd = rsqrtf(var + 1e-5f);
  u16* p1 = o1 + (size_t)r * DM;
  p1[t]       = f2bf(d0 * rstd * g1[t]       + b1[t]);
  p1[t + 256] = f2bf(d1 * rstd * g1[t + 256] + b1[t + 256]);
  p1[t + 512] = f2bf(d2 * rstd * g1[t + 512] + b1[t + 512]);
  if (o2) {
    u16* p2 = o2 + (size_t)r * DM;
    p2[t]       = f2bf(d0 * rstd * g2[t]       + b2[t]);
    p2[t + 256] = f2bf(d1 * rstd * g2[t + 256] + b2[t + 256]);
    p2[t + 512] = f2bf(d2 * rstd * g2[t + 512] + b2[t + 512]);
  }
}

// ---------------- fused flash attention, glds-staged double-buffered K/V ----
__global__ void k_attn(const u16* __restrict__ qr, const u16* __restrict__ kr,
                       const u16* __restrict__ vT, u16* __restrict__ yb) {
  int ti = (int)gridDim.x - 1 - (int)blockIdx.x;  // big tiles first
  int bh = blockIdx.y;
  __shared__ u16 Ps[64 * 72];       // Q staging, then P tile (wave-private rows)
  __shared__ u16 Ks[2][4096];       // [64][64] XOR-swizzled
  __shared__ u16 Vs[2][4096];
  int tid = threadIdx.x;
  int rr = tid >> 2, cc = tid & 3;
  int w = tid >> 6, l = tid & 63;
  int rl = l & 15, g = l >> 4;
  {
    const u16* gq = qr + ((size_t)bh * SEQ + ti * 64 + rr) * HD2;
    *(uint4*)&Ps[rr * 72 + cc * 8]      = *(const uint4*)(gq + cc * 8);
    *(uint4*)&Ps[rr * 72 + cc * 8 + 32] = *(const uint4*)(gq + cc * 8 + 32);
  }
  int srow = w * 8 + (l >> 3);
  int gs = (l & 7) ^ (l >> 3);
  const u16* gkb = kr + (size_t)bh * SEQ * HD2;
  const u16* gvb = vT + (size_t)bh * HD2 * SEQ;
  glds16(gkb + (size_t)srow * 64 + gs * 8,        &Ks[0][w * 512]);
  glds16(gkb + (size_t)(32 + srow) * 64 + gs * 8, &Ks[0][2048 + w * 512]);
  glds16(gvb + (size_t)srow * SEQ + gs * 8,       &Vs[0][w * 512]);
  glds16(gvb + (size_t)(32 + srow) * SEQ + gs * 8,&Vs[0][2048 + w * 512]);
  __syncthreads();
  bf16x8 aq0 = *(const bf16x8*)&Ps[(w * 16 + rl) * 72 + g * 8];
  bf16x8 aq1 = *(const bf16x8*)&Ps[(w * 16 + rl) * 72 + 32 + g * 8];
  float m[4], lsum[4];
  f32x4 oacc[4] = {};
#pragma unroll
  for (int r2 = 0; r2 < 4; ++r2) { m[r2] = -3.0e38f; lsum[r2] = 0.f; }
  int qloc = w * 16 + g * 4;
  int sw = rl & 7;
  int cur = 0;
  for (int kt = 0; kt <= ti; ++kt) {
    if (kt < ti) {
      int nx = cur ^ 1;
      glds16(gkb + (size_t)((kt + 1) * 64 + srow) * 64 + gs * 8,      &Ks[nx][w * 512]);
      glds16(gkb + (size_t)((kt + 1) * 64 + 32 + srow) * 64 + gs * 8, &Ks[nx][2048 + w * 512]);
      glds16(gvb + (size_t)srow * SEQ + (kt + 1) * 64 + gs * 8,       &Vs[nx][w * 512]);
      glds16(gvb + (size_t)(32 + srow) * SEQ + (kt + 1) * 64 + gs * 8,&Vs[nx][2048 + w * 512]);
    }
    f32x4 s[4] = {};
    __builtin_amdgcn_s_setprio(1);
#pragma unroll
    for (int nt = 0; nt < 4; ++nt) {
      int r = (nt * 16 + rl) * 64;
      bf16x8 b0 = *(const bf16x8*)&Ks[cur][r + ((0 + g) ^ sw) * 8];
      bf16x8 b1 = *(const bf16x8*)&Ks[cur][r + ((4 + g) ^ sw) * 8];
      s[nt] = __builtin_amdgcn_mfma_f32_16x16x32_bf16(aq0, b0, s[nt], 0, 0, 0);
      s[nt] = __builtin_amdgcn_mfma_f32_16x16x32_bf16(aq1, b1, s[nt], 0, 0, 0);
    }
    __builtin_amdgcn_s_setprio(0);
#pragma unroll
    for (int nt = 0; nt < 4; ++nt) s[nt] *= 0.125f;
    if (kt == ti) {
#pragma unroll
      for (int nt = 0; nt < 4; ++nt) {
        int col = nt * 16 + rl;
#pragma unroll
        for (int r2 = 0; r2 < 4; ++r2)
          if (col > qloc + r2) s[nt][r2] = -3.0e38f;
      }
    }
#pragma unroll
    for (int r2 = 0; r2 < 4; ++r2) {
      float pm = fmaxf(fmaxf(s[0][r2], s[1][r2]), fmaxf(s[2][r2], s[3][r2]));
#pragma unroll
      for (int o = 1; o < 16; o <<= 1) pm = fmaxf(pm, __shfl_xor(pm, o));
      float mn = fmaxf(m[r2], pm);
      float corr = __expf(m[r2] - mn);
      float p0 = __expf(s[0][r2] - mn);
      float p1 = __expf(s[1][r2] - mn);
      float p2 = __expf(s[2][r2] - mn);
      float p3 = __expf(s[3][r2] - mn);
      float ps = p0 + p1 + p2 + p3;
#pragma unroll
      for (int o = 1; o < 16; o <<= 1) ps += __shfl_xor(ps, o);
      lsum[r2] = lsum[r2] * corr + ps;
      m[r2] = mn;
      oacc[0][r2] *= corr; oacc[1][r2] *= corr;
      oacc[2][r2] *= corr; oacc[3][r2] *= corr;
      int prow = (qloc + r2) * 72;
      Ps[prow + rl]      = f2bf(p0);
      Ps[prow + 16 + rl] = f2bf(p1);
      Ps[prow + 32 + rl] = f2bf(p2);
      Ps[prow + 48 + rl] = f2bf(p3);
    }
    bf16x8 pa0 = *(const bf16x8*)&Ps[(w * 16 + rl) * 72 + g * 8];
    bf16x8 pa1 = *(const bf16x8*)&Ps[(w * 16 + rl) * 72 + 32 + g * 8];
    __builtin_amdgcn_s_setprio(1);
#pragma unroll
    for (int nt = 0; nt < 4; ++nt) {
      int r = (nt * 16 + rl) * 64;
      bf16x8 b0 = *(const bf16x8*)&Vs[cur][r + ((0 + g) ^ sw) * 8];
      bf16x8 b1 = *(const bf16x8*)&Vs[cur][r + ((4 + g) ^ sw) * 8];
      oacc[nt] = __builtin_amdgcn_mfma_f32_16x16x32_bf16(pa0, b0, oacc[nt], 0, 0, 0);
      oacc[nt] = __builtin_amdgcn_mfma_f32_16x16x32_bf16(pa1, b1, oacc[nt], 0, 0, 0);
    }
    __builtin_amdgcn_s_setprio(0);
    __syncthreads();
    cur ^= 1;
  }
  int b = bh / NH, h = bh % NH;
  float invl[4];
#pragma unroll
  for (int r2 = 0; r2 < 4; ++r2) invl[r2] = 1.f / lsum[r2];
#pragma unroll
  for (int nt = 0; nt < 4; ++nt) {
    int d = nt * 16 + rl;
#pragma unroll
    for (int r2 = 0; r2 < 4; ++r2) {
      int trow = ti * 64 + qloc + r2;
      yb[((size_t)(b * SEQ + trow)) * DM + h * HD2 + d] = f2bf(oacc[nt][r2] * invl[r2]);
    }
  }
}

// ------- 128x128 GEMM, BK=32, dbuf single-sync loop; MODE is COMPILE-TIME ----
// MODE 1: bf16 gelu out (+bias); MODE 3: f32 nontemporal out;
// MODE 4: fused qkv: bias + rope(q,k) -> qr/kr [bh][t][d]; v -> vT [bh][d][t]
// (template MODE + fully-unrolled epilogue keeps acc statically indexed in
//  registers — round 9's runtime-mode variant spilled acc to scratch: 16 GB
//  of HBM traffic per logits dispatch, 12x slowdown)
template <int MODE>
__global__ void k_g128(const u16* __restrict__ A, const u16* __restrict__ Bt,
                       const float* __restrict__ bias, u16* __restrict__ outb,
                       float* __restrict__ outf, int M, int N, int K, int MT,
                       const float* __restrict__ ctab,
                       const float* __restrict__ stab, u16* __restrict__ qrp,
                       u16* __restrict__ krp, u16* __restrict__ vTp) {
  __shared__ u16 SM[16384];  // [As0|Bs0|As1|Bs1] 4096 u16 each; alias cw[32][132]
  float* cw = (float*)SM;
  int nwg = gridDim.x;
  int id = blockIdx.x;
  if ((nwg & 7) == 0) id = (id & 7) * (nwg >> 3) + (id >> 3);  // XCD swizzle
  int mt = id % MT, nt = id / MT;
  int m0 = mt * 128, n0 = nt * 128;
  int tid = threadIdx.x;
  int w = tid >> 6, l = tid & 63;
  int srow = w * 16 + (l >> 2);
  int gs = (l & 3) ^ ((l >> 3) & 3);    // pre-swizzled source chunk
  const u16* gA0 = A + (size_t)(m0 + srow) * K + gs * 8;
  const u16* gA1 = A + (size_t)(m0 + 64 + srow) * K + gs * 8;
  int rb0 = n0 + srow;      if (rb0 > N - 1) rb0 = N - 1;
  int rb1 = n0 + 64 + srow; if (rb1 > N - 1) rb1 = N - 1;
  const u16* gB0 = Bt + (size_t)rb0 * K + gs * 8;
  const u16* gB1 = Bt + (size_t)rb1 * K + gs * 8;
  int wm = (w >> 1) * 64, wn = (w & 1) * 64;
  int rl = l & 15, g = l >> 4;
  int sla = g ^ ((rl >> 1) & 3);  // read-side swizzle (lane-constant)
  f32x4 acc[4][4] = {};
  int nK = K >> 5;
  int cur = 0;
  {  // prologue: stage kt=0 into buf0
    u16* dA = SM + w * 512;
    glds16(gA0, dA); glds16(gA1, dA + 2048);
    u16* dB = SM + 4096 + w * 512;
    glds16(gB0, dB); glds16(gB1, dB + 2048);
  }
  __syncthreads();
  for (int kt = 0; kt < nK; ++kt) {
    if (kt + 1 < nK) {  // issue next-tile stage before compute
      u16* dA = SM + (cur ^ 1) * 8192 + w * 512;
      glds16(gA0 + (kt + 1) * 32, dA); glds16(gA1 + (kt + 1) * 32, dA + 2048);
      u16* dB = dA + 4096;
      glds16(gB0 + (kt + 1) * 32, dB); glds16(gB1 + (kt + 1) * 32, dB + 2048);
    }
    const u16* As = SM + cur * 8192;
    const u16* Bs = As + 4096;
    bf16x8 af[4], bfr[4];
    __builtin_amdgcn_s_setprio(1);
#pragma unroll
    for (int i = 0; i < 4; ++i)
      af[i] = *(const bf16x8*)&As[(wm + i * 16 + rl) * 32 + sla * 8];
#pragma unroll
    for (int j = 0; j < 4; ++j)
      bfr[j] = *(const bf16x8*)&Bs[(wn + j * 16 + rl) * 32 + sla * 8];
#pragma unroll
    for (int i = 0; i < 4; ++i)
#pragma unroll
      for (int j = 0; j < 4; ++j)
        acc[i][j] = __builtin_amdgcn_mfma_f32_16x16x32_bf16(af[i], bfr[j],
                                                            acc[i][j], 0, 0, 0);
    __builtin_amdgcn_s_setprio(0);
    __syncthreads();
    cur ^= 1;
  }
  // region/head decode for MODE 4 (tiles never straddle q/k/v: DM%128==0)
  int reg = n0 / DM;
  int h0 = (n0 % DM) / 64;
  int bb = m0 >> 10;             // SEQ=1024, 1024%128==0 -> whole tile one batch
  int t0 = m0 & (SEQ - 1);
  size_t bhbase = (size_t)bb * NH;
  // epilogue: 32-row chunks through LDS (ch fully unrolled -> static acc idx)
#pragma unroll
  for (int ch = 0; ch < 4; ++ch) {
    if ((w >> 1) == (ch >> 1)) {
      int ib = (ch & 1) * 2;
#pragma unroll
      for (int ii = 0; ii < 2; ++ii) {
#pragma unroll
        for (int j = 0; j < 4; ++j) {
          int col = wn + j * 16 + rl;
#pragma unroll
          for (int r2 = 0; r2 < 4; ++r2) {
            int rowc = ii * 16 + g * 4 + r2;
            float v = acc[ib + ii][j][r2];
            if (MODE != 3) {
              v += bias[n0 + col];
              if (MODE == 1) {
                float u = 0.7978845608028654f * (v + 0.044715f * v * v * v);
                v = 0.5f * v * (1.f + tanhf(u));
              }
            }
            cw[rowc * 132 + col] = v;
          }
        }
      }
    }
    __syncthreads();
    if (MODE == 3) {
      for (int t = tid; t < 4096; t += 256) {
        int rowc = t >> 7, col = t & 127;
        int gc = n0 + col;
        if (gc < N)
          __builtin_nontemporal_store(cw[rowc * 132 + col],
                                      &outf[(size_t)(m0 + ch * 32 + rowc) * N + gc]);
      }
    } else if (MODE == 1) {  // bf16 packed u32 writes (N multiple of 128)
      for (int t = tid; t < 2048; t += 256) {
        int rowc = t >> 6, cp = t & 63;
        u32 wv = (u32)f2bf(cw[rowc * 132 + 2 * cp]) |
                 ((u32)f2bf(cw[rowc * 132 + 2 * cp + 1]) << 16);
        *(u32*)&outb[(size_t)(m0 + ch * 32 + rowc) * N + n0 + 2 * cp] = wv;
      }
    } else {  // MODE 4
      if (reg < 2) {  // q/k rope writes
        u16* dst = (reg == 0) ? qrp : krp;
        for (int t = tid; t < 2048; t += 256) {
          int rowc = t >> 6, cp = t & 63;
          int c = 2 * cp;               // col (even), 0..126
          int hh = c >> 6, d = c & 63;  // head sub-index, local dim (even)
          int tt = t0 + ch * 32 + rowc;
          float x0 = cw[rowc * 132 + c];
          float x1 = cw[rowc * 132 + c + 1];
          float o0, o1;
          if (d < 32) {
            float y0 = cw[rowc * 132 + c + 32];
            float y1 = cw[rowc * 132 + c + 33];
            float c0 = 1.f, s0 = 0.f, c1 = 1.f, s1 = 0.f;
            if (d < 16) {
              c0 = ctab[tt * 16 + d];     s0 = stab[tt * 16 + d];
              c1 = ctab[tt * 16 + d + 1]; s1 = stab[tt * 16 + d + 1];
            }
            o0 = x0 * c0 - y0 * s0;
            o1 = x1 * c1 - y1 * s1;
          } else {
            int j = d - 32;
            float y0 = cw[rowc * 132 + c - 32];
            float y1 = cw[rowc * 132 + c - 31];
            float c0 = 1.f, s0 = 0.f, c1 = 1.f, s1 = 0.f;
            if (j < 16) {
              c0 = ctab[tt * 16 + j];     s0 = stab[tt * 16 + j];
              c1 = ctab[tt * 16 + j + 1]; s1 = stab[tt * 16 + j + 1];
            }
            o0 = x0 * c0 + y0 * s0;
            o1 = x1 * c1 + y1 * s1;
          }
          u32 wv = (u32)f2bf(o0) | ((u32)f2bf(o1) << 16);
          *(u32*)&dst[((bhbase + h0 + hh) * SEQ + tt) * HD2 + d] = wv;
        }
      } else {  // v transposed write vT[bh][d][t], 2 tokens per u32
        for (int t = tid; t < 2048; t += 256) {
          int dcol = t >> 4, p = t & 15;    // col 0..127, token-pair 0..15
          int hh = dcol >> 6, d = dcol & 63;
          int tt = t0 + ch * 32 + 2 * p;
          u32 wv = (u32)f2bf(cw[(2 * p) * 132 + dcol]) |
                   ((u32)f2bf(cw[(2 * p + 1) * 132 + dcol]) << 16);
          *(u32*)&vTp[((bhbase + h0 + hh) * HD2 + d) * SEQ + tt] = wv;
        }
      }
    }
    __syncthreads();
  }
}

// ------- 64x64-tile GEMM, BK=64, dbuf, split-K (wo / wp residual adds) ------
// f32 atomic residual add (+bias at sk0)
__global__ void k_gemm64(const u16* __restrict__ A, const u16* __restrict__ Bt,
                         const float* __restrict__ bias,
                         float* __restrict__ outf, int M, int N, int K, int MT) {
  __shared__ u16 As[8192];  // 2 x [64][64]
  __shared__ u16 Bs[8192];
  int nwg = gridDim.x;
  int id = blockIdx.x;
  if ((nwg & 7) == 0) id = (id & 7) * (nwg >> 3) + (id >> 3);  // XCD swizzle
  int mt = id % MT, nt = id / MT;
  int sk = blockIdx.y, nsk = gridDim.y;
  int Kc = K / nsk, k0 = sk * Kc;
  int m0 = mt * 64, n0 = nt * 64;
  int tid = threadIdx.x;
  int w = tid >> 6, l = tid & 63;
  int row0 = tid >> 3, slot0 = tid & 7;
  int gs0 = slot0 ^ (row0 & 7);
  const u16* gA0 = A + (size_t)(m0 + row0) * K + k0 + gs0 * 8;
  const u16* gA1 = gA0 + (size_t)32 * K;
  const u16* gB0 = Bt + (size_t)(n0 + row0) * K + k0 + gs0 * 8;
  const u16* gB1 = gB0 + (size_t)32 * K;
  int wm = (w >> 1) * 32, wn = (w & 1) * 32;
  int rl = l & 15, g = l >> 4;
  int sl0 = g ^ (rl & 7), sl1 = (4 + g) ^ (rl & 7);
  f32x4 acc[2][2] = {};
  int nK = Kc >> 6;
  int cur = 0;
  {  // prologue stage kt=0 -> buf0
    glds16(gA0, As + w * 512); glds16(gA1, As + 2048 + w * 512);
    glds16(gB0, Bs + w * 512); glds16(gB1, Bs + 2048 + w * 512);
  }
  __syncthreads();
  for (int kt = 0; kt < nK; ++kt) {
    if (kt + 1 < nK) {
      int nx = (cur ^ 1) * 4096;
      glds16(gA0 + (kt + 1) * 64, As + nx + w * 512);
      glds16(gA1 + (kt + 1) * 64, As + nx + 2048 + w * 512);
      glds16(gB0 + (kt + 1) * 64, Bs + nx + w * 512);
      glds16(gB1 + (kt + 1) * 64, Bs + nx + 2048 + w * 512);
    }
    const u16* Ac = As + cur * 4096;
    const u16* Bc = Bs + cur * 4096;
    bf16x8 a0[2], a1[2], b0[2], b1[2];
    __builtin_amdgcn_s_setprio(1);
#pragma unroll
    for (int i = 0; i < 2; ++i) {
      int r = (wm + i * 16 + rl) * 64;
      a0[i] = *(const bf16x8*)&Ac[r + sl0 * 8];
      a1[i] = *(const bf16x8*)&Ac[r + sl1 * 8];
    }
#pragma unroll
    for (int j = 0; j < 2; ++j) {
      int r = (wn + j * 16 + rl) * 64;
      b0[j] = *(const bf16x8*)&Bc[r + sl0 * 8];
      b1[j] = *(const bf16x8*)&Bc[r + sl1 * 8];
    }
#pragma unroll
    for (int i = 0; i < 2; ++i)
#pragma unroll
      for (int j = 0; j < 2; ++j) {
        acc[i][j] = __builtin_amdgcn_mfma_f32_16x16x32_bf16(a0[i], b0[j],
                                                            acc[i][j], 0, 0, 0);
        acc[i][j] = __builtin_amdgcn_mfma_f32_16x16x32_bf16(a1[i], b1[j],
                                                            acc[i][j], 0, 0, 0);
      }
    __builtin_amdgcn_s_setprio(0);
    __syncthreads();
    cur ^= 1;
  }
#pragma unroll
  for (int i = 0; i < 2; ++i) {
#pragma unroll
    for (int j = 0; j < 2; ++j) {
      int col = n0 + wn + j * 16 + rl;
      float bv = bias ? bias[col] : 0.f;
#pragma unroll
      for (int r2 = 0; r2 < 4; ++r2) {
        int row = m0 + wm + i * 16 + g * 4 + r2;
        float v = acc[i][j][r2];
        if (sk == 0) v += bv;
        atomicAdd(&outf[(size_t)row * N + col], v);
      }
    }
  }
}

// ---------------- fallback GEMM (f32 B, on-the-fly cvt) — logits only --------
__global__ void k_gemm_f32b(const u16* __restrict__ A, const float* __restrict__ B,
                            float* __restrict__ outf, int M, int N, int K) {
  __shared__ u16 As[128 * 40];
  __shared__ u16 Bs[4 * 128 * 12];
  int tid = threadIdx.x;
  int wid = tid >> 6, lane = tid & 63;
  int rl = lane & 15, g = lane >> 4;
  int m0 = blockIdx.x * 128, n0 = blockIdx.y * 128;
  int wm = (wid >> 1) * 64, wn = (wid & 1) * 64;
  int ar = tid >> 2, ac = tid & 3;
  int bn = tid & 127, bq = tid >> 7;
  f32x4 acc[4][4] = {};
  int nK = K / 32;
  for (int kt = 0; kt < nK; ++kt) {
    __syncthreads();
    {
      const u16* ga = A + (size_t)(m0 + ar) * K + kt * 32 + ac * 8;
      *(uint4*)&As[ar * 40 + ac * 8] = *(const uint4*)ga;
      *(uint4*)&As[(ar + 64) * 40 + ac * 8] = *(const uint4*)(ga + (size_t)64 * K);
    }
    int col = n0 + bn;
#pragma unroll
    for (int r = 0; r < 4; ++r) {
      int kq = bq + 2 * r;
      int kk = kt * 32 + kq * 4;
      float f0 = 0.f, f1 = 0.f, f2v = 0.f, f3 = 0.f;
      if (col < N) {
        const float* gb = B + (size_t)kk * N + col;
        f0 = gb[0]; f1 = gb[(size_t)N]; f2v = gb[(size_t)2 * N]; f3 = gb[(size_t)3 * N];
      }
      uint2 wv;
      wv.x = (u32)f2bf(f0) | ((u32)f2bf(f1) << 16);
      wv.y = (u32)f2bf(f2v) | ((u32)f2bf(f3) << 16);
      *(uint2*)&Bs[(kq >> 1) * 1536 + bn * 12 + (kq & 1) * 4] = wv;
    }
    __syncthreads();
    bf16x8 af[4], bfr[4];
#pragma unroll
    for (int mt = 0; mt < 4; ++mt)
      af[mt] = *(const bf16x8*)&As[(wm + mt * 16 + rl) * 40 + g * 8];
#pragma unroll
    for (int nt = 0; nt < 4; ++nt) {
      const u16* p = &Bs[g * 1536 + (wn + nt * 16 + rl) * 12];
      union { bf16x8 v; uint2 u2[2]; } tmp;
      tmp.u2[0] = *(const uint2*)p;
      tmp.u2[1] = *(const uint2*)(p + 4);
      bfr[nt] = tmp.v;
    }
#pragma unroll
    for (int mt = 0; mt < 4; ++mt)
#pragma unroll
      for (int nt = 0; nt < 4; ++nt)
        acc[mt][nt] = __builtin_amdgcn_mfma_f32_16x16x32_bf16(af[mt], bfr[nt],
                                                              acc[mt][nt], 0, 0, 0);
  }
#pragma unroll
  for (int mt = 0; mt < 4; ++mt)
#pragma unroll
    for (int nt = 0; nt < 4; ++nt) {
      int col = n0 + wn + nt * 16 + rl;
      if (col >= N) continue;
#pragma unroll
      for (int r2 = 0; r2 < 4; ++r2) {
        int row = m0 + wm + mt * 16 + g * 4 + r2;
        outf[(size_t)row * N + col] = acc[mt][nt][r2];
      }
    }
}

extern "C" void kernel_launch(void* const* d_in, const int* in_sizes, int n_in,
                              void* d_out, int out_size, void* d_ws, size_t ws_size,
                              hipStream_t stream) {
  (void)in_sizes; (void)n_in; (void)out_size;
  const int*   idx  = (const int*)  d_in[0];
  const float* wte  = (const float*)d_in[1];
  const float* ln1g = (const float*)d_in[2];
  const float* ln1b = (const float*)d_in[3];
  const float* Wqkv = (const float*)d_in[4];
  const float* bqkv = (const float*)d_in[5];
  const float* Wo   = (const float*)d_in[6];
  const float* bo   = (const float*)d_in[7];
  const float* ln2g = (const float*)d_in[8];
  const float* ln2b = (const float*)d_in[9];
  const float* Wfc  = (const float*)d_in[10];
  const float* bfc  = (const float*)d_in[11];
  const float* Wp   = (const float*)d_in[12];
  const float* bp   = (const float*)d_in[13];
  const float* lnfg = (const float*)d_in[14];
  const float* lnfb = (const float*)d_in[15];
  const float* Wlm  = (const float*)d_in[16];
  float* out = (float*)d_out;

  // Scratch packed into d_out (all dead before the logits GEMM rewrites d_out).
  char* sb = (char*)d_out;
  size_t off = 0;
  auto alloc = [&](size_t bytes) {
    char* p = sb + off;
    off += (bytes + 255) & ~(size_t)255;
    return (void*)p;
  };
  float* xf  = (float*)alloc((size_t)BT * DM * 4);
  u16* h1b   = (u16*)alloc((size_t)BT * DM * 2);
  u16* h2b   = (u16*)alloc((size_t)BT * DM * 2);
  u16* qr    = (u16*)alloc((size_t)BT * DM * 2);
  u16* kr    = (u16*)alloc((size_t)BT * DM * 2);
  u16* vT    = (u16*)alloc((size_t)BT * DM * 2);
  u16* yb    = (u16*)alloc((size_t)BT * DM * 2);
  u16* hgel  = (u16*)alloc((size_t)BT * 4 * DM * 2);
  float* ctab = (float*)alloc((size_t)SEQ * 16 * 4);
  float* stab = (float*)alloc((size_t)SEQ * 16 * 4);
  // transposed bf16 weights (also dead before logits GEMM)
  u16* wqkvT = (u16*)alloc((size_t)NLAYER * 3 * DM * DM * 2);
  u16* woT   = (u16*)alloc((size_t)NLAYER * DM * DM * 2);
  u16* wfcT  = (u16*)alloc((size_t)NLAYER * 4 * DM * DM * 2);
  u16* wpT   = (u16*)alloc((size_t)NLAYER * 4 * DM * DM * 2);

  // Wlm^T (77 MB) must survive the logits GEMM -> d_ws if it fits.
  size_t wlmT_bytes = (size_t)NVOCAB * DM * 2;
  size_t xlnf_bytes = (size_t)BT * DM * 2;
  bool fast_lm = ws_size >= wlmT_bytes + xlnf_bytes + 512;
  u16* wlmT = (u16*)d_ws;
  u16* xlnf = fast_lm ? (u16*)((char*)d_ws + ((wlmT_bytes + 255) & ~(size_t)255))
                      : (u16*)d_ws;

  // ---- weight conversion + trig tables ----
  k_trig<<<(SEQ * 16) / 256, 256, 0, stream>>>(ctab, stab);
  for (int l = 0; l < NLAYER; ++l) {
    k_cvtT<<<dim3((3 * DM + 63) / 64, DM / 64), 256, 0, stream>>>(
        Wqkv + (size_t)l * DM * 3 * DM, wqkvT + (size_t)l * 3 * DM * DM, DM, 3 * DM);
    k_cvtT<<<dim3(DM / 64, DM / 64), 256, 0, stream>>>(
        Wo + (size_t)l * DM * DM, woT + (size_t)l * DM * DM, DM, DM);
    k_cvtT<<<dim3((4 * DM) / 64, DM / 64), 256, 0, stream>>>(
        Wfc + (size_t)l * DM * 4 * DM, wfcT + (size_t)l * 4 * DM * DM, DM, 4 * DM);
    k_cvtT<<<dim3(DM / 64, (4 * DM) / 64), 256, 0, stream>>>(
        Wp + (size_t)l * 4 * DM * DM, wpT + (size_t)l * 4 * DM * DM, 4 * DM, DM);
  }
  if (fast_lm)
    k_cvtT<<<dim3((NVOCAB + 63) / 64, DM / 64), 256, 0, stream>>>(Wlm, wlmT, DM, NVOCAB);

  k_embed<<<BT, 256, 0, stream>>>(idx, wte, xf);
  for (int l = 0; l < NLAYER; ++l) {
    k_ln<<<BT, 256, 0, stream>>>(xf, ln1g + l * DM, ln1b + l * DM,
                                 ln2g + l * DM, ln2b + l * DM, h1b, h2b);
    // fused qkv GEMM + bias + rope + v-transpose (128^2 tile)
    k_g128<4><<<(BT / 128) * (3 * DM / 128), 256, 0, stream>>>(
        h1b, wqkvT + (size_t)l * 3 * DM * DM, bqkv + (size_t)l * 3 * DM,
        nullptr, nullptr, BT, 3 * DM, DM, BT / 128, ctab, stab, qr, kr, vT);
    k_attn<<<dim3(SEQ / 64, 2 * NH), 256, 0, stream>>>(qr, kr, vT, yb);
    k_gemm64<<<dim3((BT / 64) * (DM / 64), 2), 256, 0, stream>>>(
        yb, woT + (size_t)l * DM * DM, bo + (size_t)l * DM, xf, BT, DM, DM, BT / 64);
    k_g128<1><<<(BT / 128) * (4 * DM / 128), 256, 0, stream>>>(
        h2b, wfcT + (size_t)l * 4 * DM * DM, bfc + (size_t)l * 4 * DM,
        hgel, nullptr, BT, 4 * DM, DM, BT / 128,
        nullptr, nullptr, nullptr, nullptr, nullptr);
    k_gemm64<<<dim3((BT / 64) * (DM / 64), 4), 256, 0, stream>>>(
        hgel, wpT + (size_t)l * 4 * DM * DM, bp + (size_t)l * DM, xf, BT, DM, 4 * DM,
        BT / 64);
  }
  k_ln<<<BT, 256, 0, stream>>>(xf, lnfg, lnfb, nullptr, nullptr, xlnf, nullptr);
  if (fast_lm) {
    int nt = (NVOCAB + 127) / 128;
    k_g128<3><<<(BT / 128) * nt, 256, 0, stream>>>(
        xlnf, wlmT, nullptr, nullptr, out, BT, NVOCAB, DM, BT / 128,
        nullptr, nullptr, nullptr, nullptr, nullptr);
  } else {
    k_gemm_f32b<<<dim3(BT / 128, (NVOCAB + 127) / 128), 256, 0, stream>>>(
        xlnf, Wlm, out, BT, NVOCAB, DM);
  }
}

// Round 11
// 965.946 us; speedup vs baseline: 5.6675x; 1.0942x over previous
//
#include <hip/hip_runtime.h>

typedef unsigned short u16;
typedef unsigned int u32;
typedef __attribute__((ext_vector_type(8))) short bf16x8;
typedef __attribute__((ext_vector_type(4))) float f32x4;

#define SEQ 1024
#define DM 768
#define NH 12
#define HD2 64
#define NLAYER 4
#define NVOCAB 50257
#define BT 2048  // B*T

__device__ __forceinline__ u16 f2bf(float f) {
  union { float f; u32 u; } v; v.f = f;
  u32 r = v.u + 0x7FFFu + ((v.u >> 16) & 1u);
  return (u16)(r >> 16);
}
__device__ __forceinline__ float bf2f(u16 u) {
  union { u32 u; float f; } v; v.u = ((u32)u) << 16;
  return v.f;
}

__device__ __forceinline__ void glds16(const u16* g, u16* l) {
  __builtin_amdgcn_global_load_lds(
      (const __attribute__((address_space(1))) u32*)(const void*)g,
      (__attribute__((address_space(3))) u32*)(void*)l, 16, 0, 0);
}

// ---------------- embedding ----------------
__global__ void k_embed(const int* __restrict__ idx, const float* __restrict__ wte,
                        float* __restrict__ xf) {
  int r = blockIdx.x;
  int tok = idx[r];
  const float* s = wte + (size_t)tok * DM;
  float* d = xf + (size_t)r * DM;
  for (int c = threadIdx.x; c < DM; c += 256) d[c] = s[c];
}

// ---------------- rope trig tables: [SEQ][16] cos/sin ----------------
__global__ void k_trig(float* __restrict__ ctab, float* __restrict__ stab) {
  int gid = blockIdx.x * 256 + threadIdx.x;  // over SEQ*16
  int tt = gid >> 4, j = gid & 15;
  float inv = powf(10000.f, -(float)j * (1.f / 32.f));
  float ang = (float)tt * inv;
  ctab[gid] = cosf(ang);
  stab[gid] = sinf(ang);
}

// ------- transpose + f32->bf16: in[R,C] f32 -> out[C,R] bf16 (64x64 tile) ----
__global__ void k_cvtT(const float* __restrict__ in, u16* __restrict__ out,
                       int R, int C) {
  __shared__ u16 t[64][68];
  int c0 = blockIdx.x * 64, r0 = blockIdx.y * 64;  // R always multiple of 64
  int tx = threadIdx.x & 15, ty = threadIdx.x >> 4;
  int c = c0 + tx * 4;
#pragma unroll
  for (int i = 0; i < 4; ++i) {
    int r = r0 + ty + i * 16;
    float4 v = make_float4(0.f, 0.f, 0.f, 0.f);
    if (c + 3 < C) {
      v = *(const float4*)&in[(size_t)r * C + c];
    } else {
      if (c + 0 < C) v.x = in[(size_t)r * C + c];
      if (c + 1 < C) v.y = in[(size_t)r * C + c + 1];
      if (c + 2 < C) v.z = in[(size_t)r * C + c + 2];
      if (c + 3 < C) v.w = in[(size_t)r * C + c + 3];
    }
    t[ty + i * 16][tx * 4 + 0] = f2bf(v.x);
    t[ty + i * 16][tx * 4 + 1] = f2bf(v.y);
    t[ty + i * 16][tx * 4 + 2] = f2bf(v.z);
    t[ty + i * 16][tx * 4 + 3] = f2bf(v.w);
  }
  __syncthreads();
  int wl = threadIdx.x & 31, grp = threadIdx.x >> 5;
#pragma unroll
  for (int it = 0; it < 8; ++it) {
    int cc = it * 8 + grp;
    int gcol = c0 + cc;
    if (gcol < C) {
      u32 wv = (u32)t[2 * wl][cc] | ((u32)t[2 * wl + 1][cc] << 16);
      *(u32*)&out[(size_t)gcol * R + r0 + 2 * wl] = wv;
    }
  }
}

// ---------------- block reductions (256 thr = 4 waves) ----------------
__device__ __forceinline__ float bsum(float v, float* red) {
#pragma unroll
  for (int o = 32; o > 0; o >>= 1) v += __shfl_down(v, o);
  if ((threadIdx.x & 63) == 0) red[threadIdx.x >> 6] = v;
  __syncthreads();
  if (threadIdx.x == 0) red[4] = red[0] + red[1] + red[2] + red[3];
  __syncthreads();
  return red[4];
}

// ---------------- dual layernorm (both read same x) ----------------
__global__ void k_ln(const float* __restrict__ x, const float* __restrict__ g1,
                     const float* __restrict__ b1, const float* __restrict__ g2,
                     const float* __restrict__ b2, u16* __restrict__ o1,
                     u16* __restrict__ o2) {
  __shared__ float red[8];
  int r = blockIdx.x;
  int t = threadIdx.x;
  const float* xr = x + (size_t)r * DM;
  float v0 = xr[t], v1 = xr[t + 256], v2 = xr[t + 512];
  float mean = bsum(v0 + v1 + v2, red) * (1.f / DM);
  float d0 = v0 - mean, d1 = v1 - mean, d2 = v2 - mean;
  float var = bsum(d0 * d0 + d1 * d1 + d2 * d2, red) * (1.f / DM);
  float rstd = rsqrtf(var + 1e-5f);
  u16* p1 = o1 + (size_t)r * DM;
  p1[t]       = f2bf(d0 * rstd * g1[t]       + b1[t]);
  p1[t + 256] = f2bf(d1 * rstd * g1[t + 256] + b1[t + 256]);
  p1[t + 512] = f2bf(d2 * rstd * g1[t + 512] + b1[t + 512]);
  if (o2) {
    u16* p2 = o2 + (size_t)r * DM;
    p2[t]       = f2bf(d0 * rstd * g2[t]       + b2[t]);
    p2[t + 256] = f2bf(d1 * rstd * g2[t + 256] + b2[t + 256]);
    p2[t + 512] = f2bf(d2 * rstd * g2[t + 512] + b2[t + 512]);
  }
}

// ---------------- fused flash attention, glds-staged double-buffered K/V ----
// q is pre-scaled by 1/8 in the qkv epilogue (exact in bf16) -> no scale here.
__global__ void k_attn(const u16* __restrict__ qr, const u16* __restrict__ kr,
                       const u16* __restrict__ vT, u16* __restrict__ yb) {
  int ti = (int)gridDim.x - 1 - (int)blockIdx.x;  // big tiles first
  int bh = blockIdx.y;
  __shared__ u16 Ps[64 * 72];       // Q staging, then P tile (wave-private rows)
  __shared__ u16 Ks[2][4096];       // [64][64] XOR-swizzled
  __shared__ u16 Vs[2][4096];
  int tid = threadIdx.x;
  int rr = tid >> 2, cc = tid & 3;
  int w = tid >> 6, l = tid & 63;
  int rl = l & 15, g = l >> 4;
  {
    const u16* gq = qr + ((size_t)bh * SEQ + ti * 64 + rr) * HD2;
    *(uint4*)&Ps[rr * 72 + cc * 8]      = *(const uint4*)(gq + cc * 8);
    *(uint4*)&Ps[rr * 72 + cc * 8 + 32] = *(const uint4*)(gq + cc * 8 + 32);
  }
  int srow = w * 8 + (l >> 3);
  int gs = (l & 7) ^ (l >> 3);
  const u16* gkb = kr + (size_t)bh * SEQ * HD2;
  const u16* gvb = vT + (size_t)bh * HD2 * SEQ;
  glds16(gkb + (size_t)srow * 64 + gs * 8,        &Ks[0][w * 512]);
  glds16(gkb + (size_t)(32 + srow) * 64 + gs * 8, &Ks[0][2048 + w * 512]);
  glds16(gvb + (size_t)srow * SEQ + gs * 8,       &Vs[0][w * 512]);
  glds16(gvb + (size_t)(32 + srow) * SEQ + gs * 8,&Vs[0][2048 + w * 512]);
  __syncthreads();
  bf16x8 aq0 = *(const bf16x8*)&Ps[(w * 16 + rl) * 72 + g * 8];
  bf16x8 aq1 = *(const bf16x8*)&Ps[(w * 16 + rl) * 72 + 32 + g * 8];
  float m[4], lsum[4];
  f32x4 oacc[4] = {};
#pragma unroll
  for (int r2 = 0; r2 < 4; ++r2) { m[r2] = -3.0e38f; lsum[r2] = 0.f; }
  int qloc = w * 16 + g * 4;
  int sw = rl & 7;
  int cur = 0;
  for (int kt = 0; kt <= ti; ++kt) {
    if (kt < ti) {
      int nx = cur ^ 1;
      glds16(gkb + (size_t)((kt + 1) * 64 + srow) * 64 + gs * 8,      &Ks[nx][w * 512]);
      glds16(gkb + (size_t)((kt + 1) * 64 + 32 + srow) * 64 + gs * 8, &Ks[nx][2048 + w * 512]);
      glds16(gvb + (size_t)srow * SEQ + (kt + 1) * 64 + gs * 8,       &Vs[nx][w * 512]);
      glds16(gvb + (size_t)(32 + srow) * SEQ + (kt + 1) * 64 + gs * 8,&Vs[nx][2048 + w * 512]);
    }
    f32x4 s[4] = {};
    __builtin_amdgcn_s_setprio(1);
#pragma unroll
    for (int nt = 0; nt < 4; ++nt) {
      int r = (nt * 16 + rl) * 64;
      bf16x8 b0 = *(const bf16x8*)&Ks[cur][r + ((0 + g) ^ sw) * 8];
      bf16x8 b1 = *(const bf16x8*)&Ks[cur][r + ((4 + g) ^ sw) * 8];
      s[nt] = __builtin_amdgcn_mfma_f32_16x16x32_bf16(aq0, b0, s[nt], 0, 0, 0);
      s[nt] = __builtin_amdgcn_mfma_f32_16x16x32_bf16(aq1, b1, s[nt], 0, 0, 0);
    }
    __builtin_amdgcn_s_setprio(0);
    if (kt == ti) {
#pragma unroll
      for (int nt = 0; nt < 4; ++nt) {
        int col = nt * 16 + rl;
#pragma unroll
        for (int r2 = 0; r2 < 4; ++r2)
          if (col > qloc + r2) s[nt][r2] = -3.0e38f;
      }
    }
#pragma unroll
    for (int r2 = 0; r2 < 4; ++r2) {
      float pm = fmaxf(fmaxf(s[0][r2], s[1][r2]), fmaxf(s[2][r2], s[3][r2]));
#pragma unroll
      for (int o = 1; o < 16; o <<= 1) pm = fmaxf(pm, __shfl_xor(pm, o));
      float mn = fmaxf(m[r2], pm);
      float corr = __expf(m[r2] - mn);
      float p0 = __expf(s[0][r2] - mn);
      float p1 = __expf(s[1][r2] - mn);
      float p2 = __expf(s[2][r2] - mn);
      float p3 = __expf(s[3][r2] - mn);
      float ps = p0 + p1 + p2 + p3;
#pragma unroll
      for (int o = 1; o < 16; o <<= 1) ps += __shfl_xor(ps, o);
      lsum[r2] = lsum[r2] * corr + ps;
      m[r2] = mn;
      oacc[0][r2] *= corr; oacc[1][r2] *= corr;
      oacc[2][r2] *= corr; oacc[3][r2] *= corr;
      int prow = (qloc + r2) * 72;
      Ps[prow + rl]      = f2bf(p0);
      Ps[prow + 16 + rl] = f2bf(p1);
      Ps[prow + 32 + rl] = f2bf(p2);
      Ps[prow + 48 + rl] = f2bf(p3);
    }
    bf16x8 pa0 = *(const bf16x8*)&Ps[(w * 16 + rl) * 72 + g * 8];
    bf16x8 pa1 = *(const bf16x8*)&Ps[(w * 16 + rl) * 72 + 32 + g * 8];
    __builtin_amdgcn_s_setprio(1);
#pragma unroll
    for (int nt = 0; nt < 4; ++nt) {
      int r = (nt * 16 + rl) * 64;
      bf16x8 b0 = *(const bf16x8*)&Vs[cur][r + ((0 + g) ^ sw) * 8];
      bf16x8 b1 = *(const bf16x8*)&Vs[cur][r + ((4 + g) ^ sw) * 8];
      oacc[nt] = __builtin_amdgcn_mfma_f32_16x16x32_bf16(pa0, b0, oacc[nt], 0, 0, 0);
      oacc[nt] = __builtin_amdgcn_mfma_f32_16x16x32_bf16(pa1, b1, oacc[nt], 0, 0, 0);
    }
    __builtin_amdgcn_s_setprio(0);
    __syncthreads();
    cur ^= 1;
  }
  int b = bh / NH, h = bh % NH;
  float invl[4];
#pragma unroll
  for (int r2 = 0; r2 < 4; ++r2) invl[r2] = 1.f / lsum[r2];
#pragma unroll
  for (int nt = 0; nt < 4; ++nt) {
    int d = nt * 16 + rl;
#pragma unroll
    for (int r2 = 0; r2 < 4; ++r2) {
      int trow = ti * 64 + qloc + r2;
      yb[((size_t)(b * SEQ + trow)) * DM + h * HD2 + d] = f2bf(oacc[nt][r2] * invl[r2]);
    }
  }
}

// ------- 128x128 GEMM, BK=32, dbuf single-sync loop; MODE compile-time ------
// MODE 3: f32 nontemporal out (logits). Only <3> is instantiated; grid must be
// large (logits: 6288 blocks = 24/CU). 128^2 at layer shapes starves occupancy.
template <int MODE>
__global__ void k_g128(const u16* __restrict__ A, const u16* __restrict__ Bt,
                       float* __restrict__ outf, int M, int N, int K, int MT) {
  __shared__ u16 SM[16384];  // [As0|Bs0|As1|Bs1] 4096 u16 each; alias cw[32][132]
  float* cw = (float*)SM;
  int nwg = gridDim.x;
  int id = blockIdx.x;
  if ((nwg & 7) == 0) id = (id & 7) * (nwg >> 3) + (id >> 3);  // XCD swizzle
  int mt = id % MT, nt = id / MT;
  int m0 = mt * 128, n0 = nt * 128;
  int tid = threadIdx.x;
  int w = tid >> 6, l = tid & 63;
  int srow = w * 16 + (l >> 2);
  int gs = (l & 3) ^ ((l >> 3) & 3);    // pre-swizzled source chunk
  const u16* gA0 = A + (size_t)(m0 + srow) * K + gs * 8;
  const u16* gA1 = A + (size_t)(m0 + 64 + srow) * K + gs * 8;
  int rb0 = n0 + srow;      if (rb0 > N - 1) rb0 = N - 1;
  int rb1 = n0 + 64 + srow; if (rb1 > N - 1) rb1 = N - 1;
  const u16* gB0 = Bt + (size_t)rb0 * K + gs * 8;
  const u16* gB1 = Bt + (size_t)rb1 * K + gs * 8;
  int wm = (w >> 1) * 64, wn = (w & 1) * 64;
  int rl = l & 15, g = l >> 4;
  int sla = g ^ ((rl >> 1) & 3);  // read-side swizzle (lane-constant)
  f32x4 acc[4][4] = {};
  int nK = K >> 5;
  int cur = 0;
  {  // prologue: stage kt=0 into buf0
    u16* dA = SM + w * 512;
    glds16(gA0, dA); glds16(gA1, dA + 2048);
    u16* dB = SM + 4096 + w * 512;
    glds16(gB0, dB); glds16(gB1, dB + 2048);
  }
  __syncthreads();
  for (int kt = 0; kt < nK; ++kt) {
    if (kt + 1 < nK) {  // issue next-tile stage before compute
      u16* dA = SM + (cur ^ 1) * 8192 + w * 512;
      glds16(gA0 + (kt + 1) * 32, dA); glds16(gA1 + (kt + 1) * 32, dA + 2048);
      u16* dB = dA + 4096;
      glds16(gB0 + (kt + 1) * 32, dB); glds16(gB1 + (kt + 1) * 32, dB + 2048);
    }
    const u16* As = SM + cur * 8192;
    const u16* Bs = As + 4096;
    bf16x8 af[4], bfr[4];
    __builtin_amdgcn_s_setprio(1);
#pragma unroll
    for (int i = 0; i < 4; ++i)
      af[i] = *(const bf16x8*)&As[(wm + i * 16 + rl) * 32 + sla * 8];
#pragma unroll
    for (int j = 0; j < 4; ++j)
      bfr[j] = *(const bf16x8*)&Bs[(wn + j * 16 + rl) * 32 + sla * 8];
#pragma unroll
    for (int i = 0; i < 4; ++i)
#pragma unroll
      for (int j = 0; j < 4; ++j)
        acc[i][j] = __builtin_amdgcn_mfma_f32_16x16x32_bf16(af[i], bfr[j],
                                                            acc[i][j], 0, 0, 0);
    __builtin_amdgcn_s_setprio(0);
    __syncthreads();
    cur ^= 1;
  }
  // epilogue: 32-row chunks through LDS, coalesced nontemporal f32 row writes
#pragma unroll
  for (int ch = 0; ch < 4; ++ch) {
    if ((w >> 1) == (ch >> 1)) {
      int ib = (ch & 1) * 2;
#pragma unroll
      for (int ii = 0; ii < 2; ++ii) {
#pragma unroll
        for (int j = 0; j < 4; ++j) {
          int col = wn + j * 16 + rl;
#pragma unroll
          for (int r2 = 0; r2 < 4; ++r2) {
            int rowc = ii * 16 + g * 4 + r2;
            cw[rowc * 132 + col] = acc[ib + ii][j][r2];
          }
        }
      }
    }
    __syncthreads();
    for (int t = tid; t < 4096; t += 256) {
      int rowc = t >> 7, col = t & 127;
      int gc = n0 + col;
      if (gc < N)
        __builtin_nontemporal_store(cw[rowc * 132 + col],
                                    &outf[(size_t)(m0 + ch * 32 + rowc) * N + gc]);
    }
    __syncthreads();
  }
}

// ------- 64x64-tile GEMM, BK=64, dbuf, split-K; MODE compile-time -----------
// MODE 0: bf16 out; 1: bf16 gelu out; 2: f32 atomic residual add (+bias sk0);
// MODE 4: fused qkv: bias + rope(q,k)*[q pre-scaled 1/8] -> qr/kr; v -> vT
template <int MODE>
__global__ void k_gemm64(const u16* __restrict__ A, const u16* __restrict__ Bt,
                         const float* __restrict__ bias, u16* __restrict__ outb,
                         float* __restrict__ outf, int M, int N, int K, int MT,
                         const float* __restrict__ ctab,
                         const float* __restrict__ stab, u16* __restrict__ qrp,
                         u16* __restrict__ krp, u16* __restrict__ vTp) {
  __shared__ u16 SM2[16384];  // As | Bs (2x dbuf); alias f32 cw[64][68] (MODE 4)
  u16* As = SM2;
  u16* Bs = SM2 + 8192;
  float* cw = (float*)SM2;
  int nwg = gridDim.x;
  int id = blockIdx.x;
  if ((nwg & 7) == 0) id = (id & 7) * (nwg >> 3) + (id >> 3);  // XCD swizzle
  int mt = id % MT, nt = id / MT;
  int sk = blockIdx.y, nsk = gridDim.y;
  int Kc = K / nsk, k0 = sk * Kc;
  int m0 = mt * 64, n0 = nt * 64;
  int tid = threadIdx.x;
  int w = tid >> 6, l = tid & 63;
  int row0 = tid >> 3, slot0 = tid & 7;
  int gs0 = slot0 ^ (row0 & 7);
  const u16* gA0 = A + (size_t)(m0 + row0) * K + k0 + gs0 * 8;
  const u16* gA1 = gA0 + (size_t)32 * K;
  const u16* gB0 = Bt + (size_t)(n0 + row0) * K + k0 + gs0 * 8;
  const u16* gB1 = gB0 + (size_t)32 * K;
  int wm = (w >> 1) * 32, wn = (w & 1) * 32;
  int rl = l & 15, g = l >> 4;
  int sl0 = g ^ (rl & 7), sl1 = (4 + g) ^ (rl & 7);
  f32x4 acc[2][2] = {};
  int nK = Kc >> 6;
  int cur = 0;
  {  // prologue stage kt=0 -> buf0
    glds16(gA0, As + w * 512); glds16(gA1, As + 2048 + w * 512);
    glds16(gB0, Bs + w * 512); glds16(gB1, Bs + 2048 + w * 512);
  }
  __syncthreads();
  for (int kt = 0; kt < nK; ++kt) {
    if (kt + 1 < nK) {
      int nx = (cur ^ 1) * 4096;
      glds16(gA0 + (kt + 1) * 64, As + nx + w * 512);
      glds16(gA1 + (kt + 1) * 64, As + nx + 2048 + w * 512);
      glds16(gB0 + (kt + 1) * 64, Bs + nx + w * 512);
      glds16(gB1 + (kt + 1) * 64, Bs + nx + 2048 + w * 512);
    }
    const u16* Ac = As + cur * 4096;
    const u16* Bc = Bs + cur * 4096;
    bf16x8 a0[2], a1[2], b0[2], b1[2];
    __builtin_amdgcn_s_setprio(1);
#pragma unroll
    for (int i = 0; i < 2; ++i) {
      int r = (wm + i * 16 + rl) * 64;
      a0[i] = *(const bf16x8*)&Ac[r + sl0 * 8];
      a1[i] = *(const bf16x8*)&Ac[r + sl1 * 8];
    }
#pragma unroll
    for (int j = 0; j < 2; ++j) {
      int r = (wn + j * 16 + rl) * 64;
      b0[j] = *(const bf16x8*)&Bc[r + sl0 * 8];
      b1[j] = *(const bf16x8*)&Bc[r + sl1 * 8];
    }
#pragma unroll
    for (int i = 0; i < 2; ++i)
#pragma unroll
      for (int j = 0; j < 2; ++j) {
        acc[i][j] = __builtin_amdgcn_mfma_f32_16x16x32_bf16(a0[i], b0[j],
                                                            acc[i][j], 0, 0, 0);
        acc[i][j] = __builtin_amdgcn_mfma_f32_16x16x32_bf16(a1[i], b1[j],
                                                            acc[i][j], 0, 0, 0);
      }
    __builtin_amdgcn_s_setprio(0);
    __syncthreads();
    cur ^= 1;
  }
  if constexpr (MODE != 4) {
#pragma unroll
    for (int i = 0; i < 2; ++i) {
#pragma unroll
      for (int j = 0; j < 2; ++j) {
        int col = n0 + wn + j * 16 + rl;
        float bv = bias ? bias[col] : 0.f;
#pragma unroll
        for (int r2 = 0; r2 < 4; ++r2) {
          int row = m0 + wm + i * 16 + g * 4 + r2;
          size_t oi = (size_t)row * N + col;
          float v = acc[i][j][r2];
          if constexpr (MODE == 0) {
            outb[oi] = f2bf(v + bv);
          } else if constexpr (MODE == 1) {
            v += bv;
            float u = 0.7978845608028654f * (v + 0.044715f * v * v * v);
            outb[oi] = f2bf(0.5f * v * (1.f + tanhf(u)));
          } else {
            if (sk == 0) v += bv;
            atomicAdd(&outf[oi], v);
          }
        }
      }
    }
    return;
  } else {
    // ---- MODE 4: fused qkv epilogue (tile = 64 tokens x 1 head dim-block) --
#pragma unroll
    for (int i = 0; i < 2; ++i) {
#pragma unroll
      for (int j = 0; j < 2; ++j) {
        int col = wn + j * 16 + rl;
        float bv = bias[n0 + col];
#pragma unroll
        for (int r2 = 0; r2 < 4; ++r2)
          cw[(wm + i * 16 + g * 4 + r2) * 68 + col] = acc[i][j][r2] + bv;
      }
    }
    __syncthreads();
    int reg = n0 / DM;            // 0=q, 1=k, 2=v (tiles never straddle)
    int h = (n0 % DM) / 64;       // head (tile = exactly one head)
    int b = m0 >> 10;             // SEQ=1024; whole tile same batch
    int t0 = m0 & (SEQ - 1);
    size_t bh = (size_t)(b * NH + h);
    if (reg < 2) {
      u16* dst = (reg == 0) ? qrp : krp;
      float qs = (reg == 0) ? 0.125f : 1.f;  // fold 1/sqrt(HD) into q (exact)
      for (int t = tid; t < 2048; t += 256) {
        int rowc = t >> 5, cp = t & 31;   // row 0..63, u32-pair 0..31
        int d = 2 * cp;                   // even; pair (d, d+1) same rope class
        int tt = t0 + rowc;
        float x0 = cw[rowc * 68 + d];
        float x1 = cw[rowc * 68 + d + 1];
        float o0, o1;
        if (d < 32) {
          float y0 = cw[rowc * 68 + d + 32];
          float y1 = cw[rowc * 68 + d + 33];
          float c0 = 1.f, s0 = 0.f, c1 = 1.f, s1 = 0.f;
          if (d < 16) {
            c0 = ctab[tt * 16 + d];     s0 = stab[tt * 16 + d];
            c1 = ctab[tt * 16 + d + 1]; s1 = stab[tt * 16 + d + 1];
          }
          o0 = x0 * c0 - y0 * s0;
          o1 = x1 * c1 - y1 * s1;
        } else {
          int j = d - 32;
          float y0 = cw[rowc * 68 + j];
          float y1 = cw[rowc * 68 + j + 1];
          float c0 = 1.f, s0 = 0.f, c1 = 1.f, s1 = 0.f;
          if (j < 16) {
            c0 = ctab[tt * 16 + j];     s0 = stab[tt * 16 + j];
            c1 = ctab[tt * 16 + j + 1]; s1 = stab[tt * 16 + j + 1];
          }
          o0 = x0 * c0 + y0 * s0;
          o1 = x1 * c1 + y1 * s1;
        }
        u32 wv = (u32)f2bf(o0 * qs) | ((u32)f2bf(o1 * qs) << 16);
        *(u32*)&dst[(bh * SEQ + tt) * HD2 + d] = wv;
      }
    } else {
      // v: transposed write vT[bh][d][t], 2 tokens packed per u32
      for (int t = tid; t < 2048; t += 256) {
        int d = t >> 5, p = t & 31;       // d 0..63, token-pair 0..31
        int tt = t0 + 2 * p;
        u32 wv = (u32)f2bf(cw[(2 * p) * 68 + d]) |
                 ((u32)f2bf(cw[(2 * p + 1) * 68 + d]) << 16);
        *(u32*)&vTp[(bh * HD2 + d) * SEQ + tt] = wv;
      }
    }
  }
}

// ---------------- fallback GEMM (f32 B, on-the-fly cvt) — logits only --------
__global__ void k_gemm_f32b(const u16* __restrict__ A, const float* __restrict__ B,
                            float* __restrict__ outf, int M, int N, int K) {
  __shared__ u16 As[128 * 40];
  __shared__ u16 Bs[4 * 128 * 12];
  int tid = threadIdx.x;
  int wid = tid >> 6, lane = tid & 63;
  int rl = lane & 15, g = lane >> 4;
  int m0 = blockIdx.x * 128, n0 = blockIdx.y * 128;
  int wm = (wid >> 1) * 64, wn = (wid & 1) * 64;
  int ar = tid >> 2, ac = tid & 3;
  int bn = tid & 127, bq = tid >> 7;
  f32x4 acc[4][4] = {};
  int nK = K / 32;
  for (int kt = 0; kt < nK; ++kt) {
    __syncthreads();
    {
      const u16* ga = A + (size_t)(m0 + ar) * K + kt * 32 + ac * 8;
      *(uint4*)&As[ar * 40 + ac * 8] = *(const uint4*)ga;
      *(uint4*)&As[(ar + 64) * 40 + ac * 8] = *(const uint4*)(ga + (size_t)64 * K);
    }
    int col = n0 + bn;
#pragma unroll
    for (int r = 0; r < 4; ++r) {
      int kq = bq + 2 * r;
      int kk = kt * 32 + kq * 4;
      float f0 = 0.f, f1 = 0.f, f2v = 0.f, f3 = 0.f;
      if (col < N) {
        const float* gb = B + (size_t)kk * N + col;
        f0 = gb[0]; f1 = gb[(size_t)N]; f2v = gb[(size_t)2 * N]; f3 = gb[(size_t)3 * N];
      }
      uint2 wv;
      wv.x = (u32)f2bf(f0) | ((u32)f2bf(f1) << 16);
      wv.y = (u32)f2bf(f2v) | ((u32)f2bf(f3) << 16);
      *(uint2*)&Bs[(kq >> 1) * 1536 + bn * 12 + (kq & 1) * 4] = wv;
    }
    __syncthreads();
    bf16x8 af[4], bfr[4];
#pragma unroll
    for (int mt = 0; mt < 4; ++mt)
      af[mt] = *(const bf16x8*)&As[(wm + mt * 16 + rl) * 40 + g * 8];
#pragma unroll
    for (int nt = 0; nt < 4; ++nt) {
      const u16* p = &Bs[g * 1536 + (wn + nt * 16 + rl) * 12];
      union { bf16x8 v; uint2 u2[2]; } tmp;
      tmp.u2[0] = *(const uint2*)p;
      tmp.u2[1] = *(const uint2*)(p + 4);
      bfr[nt] = tmp.v;
    }
#pragma unroll
    for (int mt = 0; mt < 4; ++mt)
#pragma unroll
      for (int nt = 0; nt < 4; ++nt)
        acc[mt][nt] = __builtin_amdgcn_mfma_f32_16x16x32_bf16(af[mt], bfr[nt],
                                                              acc[mt][nt], 0, 0, 0);
  }
#pragma unroll
  for (int mt = 0; mt < 4; ++mt)
#pragma unroll
    for (int nt = 0; nt < 4; ++nt) {
      int col = n0 + wn + nt * 16 + rl;
      if (col >= N) continue;
#pragma unroll
      for (int r2 = 0; r2 < 4; ++r2) {
        int row = m0 + wm + mt * 16 + g * 4 + r2;
        outf[(size_t)row * N + col] = acc[mt][nt][r2];
      }
    }
}

extern "C" void kernel_launch(void* const* d_in, const int* in_sizes, int n_in,
                              void* d_out, int out_size, void* d_ws, size_t ws_size,
                              hipStream_t stream) {
  (void)in_sizes; (void)n_in; (void)out_size;
  const int*   idx  = (const int*)  d_in[0];
  const float* wte  = (const float*)d_in[1];
  const float* ln1g = (const float*)d_in[2];
  const float* ln1b = (const float*)d_in[3];
  const float* Wqkv = (const float*)d_in[4];
  const float* bqkv = (const float*)d_in[5];
  const float* Wo   = (const float*)d_in[6];
  const float* bo   = (const float*)d_in[7];
  const float* ln2g = (const float*)d_in[8];
  const float* ln2b = (const float*)d_in[9];
  const float* Wfc  = (const float*)d_in[10];
  const float* bfc  = (const float*)d_in[11];
  const float* Wp   = (const float*)d_in[12];
  const float* bp   = (const float*)d_in[13];
  const float* lnfg = (const float*)d_in[14];
  const float* lnfb = (const float*)d_in[15];
  const float* Wlm  = (const float*)d_in[16];
  float* out = (float*)d_out;

  // Scratch packed into d_out (all dead before the logits GEMM rewrites d_out).
  char* sb = (char*)d_out;
  size_t off = 0;
  auto alloc = [&](size_t bytes) {
    char* p = sb + off;
    off += (bytes + 255) & ~(size_t)255;
    return (void*)p;
  };
  float* xf  = (float*)alloc((size_t)BT * DM * 4);
  u16* h1b   = (u16*)alloc((size_t)BT * DM * 2);
  u16* h2b   = (u16*)alloc((size_t)BT * DM * 2);
  u16* qr    = (u16*)alloc((size_t)BT * DM * 2);
  u16* kr    = (u16*)alloc((size_t)BT * DM * 2);
  u16* vT    = (u16*)alloc((size_t)BT * DM * 2);
  u16* yb    = (u16*)alloc((size_t)BT * DM * 2);
  u16* hgel  = (u16*)alloc((size_t)BT * 4 * DM * 2);
  float* ctab = (float*)alloc((size_t)SEQ * 16 * 4);
  float* stab = (float*)alloc((size_t)SEQ * 16 * 4);
  // transposed bf16 weights (also dead before logits GEMM)
  u16* wqkvT = (u16*)alloc((size_t)NLAYER * 3 * DM * DM * 2);
  u16* woT   = (u16*)alloc((size_t)NLAYER * DM * DM * 2);
  u16* wfcT  = (u16*)alloc((size_t)NLAYER * 4 * DM * DM * 2);
  u16* wpT   = (u16*)alloc((size_t)NLAYER * 4 * DM * DM * 2);

  // Wlm^T (77 MB) must survive the logits GEMM -> d_ws if it fits.
  size_t wlmT_bytes = (size_t)NVOCAB * DM * 2;
  size_t xlnf_bytes = (size_t)BT * DM * 2;
  bool fast_lm = ws_size >= wlmT_bytes + xlnf_bytes + 512;
  u16* wlmT = (u16*)d_ws;
  u16* xlnf = fast_lm ? (u16*)((char*)d_ws + ((wlmT_bytes + 255) & ~(size_t)255))
                      : (u16*)d_ws;

  // ---- weight conversion + trig tables ----
  k_trig<<<(SEQ * 16) / 256, 256, 0, stream>>>(ctab, stab);
  for (int l = 0; l < NLAYER; ++l) {
    k_cvtT<<<dim3((3 * DM + 63) / 64, DM / 64), 256, 0, stream>>>(
        Wqkv + (size_t)l * DM * 3 * DM, wqkvT + (size_t)l * 3 * DM * DM, DM, 3 * DM);
    k_cvtT<<<dim3(DM / 64, DM / 64), 256, 0, stream>>>(
        Wo + (size_t)l * DM * DM, woT + (size_t)l * DM * DM, DM, DM);
    k_cvtT<<<dim3((4 * DM) / 64, DM / 64), 256, 0, stream>>>(
        Wfc + (size_t)l * DM * 4 * DM, wfcT + (size_t)l * 4 * DM * DM, DM, 4 * DM);
    k_cvtT<<<dim3(DM / 64, (4 * DM) / 64), 256, 0, stream>>>(
        Wp + (size_t)l * 4 * DM * DM, wpT + (size_t)l * 4 * DM * DM, 4 * DM, DM);
  }
  if (fast_lm)
    k_cvtT<<<dim3((NVOCAB + 63) / 64, DM / 64), 256, 0, stream>>>(Wlm, wlmT, DM, NVOCAB);

  k_embed<<<BT, 256, 0, stream>>>(idx, wte, xf);
  for (int l = 0; l < NLAYER; ++l) {
    k_ln<<<BT, 256, 0, stream>>>(xf, ln1g + l * DM, ln1b + l * DM,
                                 ln2g + l * DM, ln2b + l * DM, h1b, h2b);
    // fused qkv GEMM + bias + rope (+q/8) + v-transpose (64^2, 1152 blocks)
    k_gemm64<4><<<dim3((BT / 64) * (3 * DM / 64), 1), 256, 0, stream>>>(
        h1b, wqkvT + (size_t)l * 3 * DM * DM, bqkv + (size_t)l * 3 * DM,
        nullptr, nullptr, BT, 3 * DM, DM, BT / 64, ctab, stab, qr, kr, vT);
    k_attn<<<dim3(SEQ / 64, 2 * NH), 256, 0, stream>>>(qr, kr, vT, yb);
    k_gemm64<2><<<dim3((BT / 64) * (DM / 64), 2), 256, 0, stream>>>(
        yb, woT + (size_t)l * DM * DM, bo + (size_t)l * DM,
        nullptr, xf, BT, DM, DM, BT / 64,
        nullptr, nullptr, nullptr, nullptr, nullptr);
    k_gemm64<1><<<dim3((BT / 64) * (4 * DM / 64), 1), 256, 0, stream>>>(
        h2b, wfcT + (size_t)l * 4 * DM * DM, bfc + (size_t)l * 4 * DM,
        hgel, nullptr, BT, 4 * DM, DM, BT / 64,
        nullptr, nullptr, nullptr, nullptr, nullptr);
    k_gemm64<2><<<dim3((BT / 64) * (DM / 64), 4), 256, 0, stream>>>(
        hgel, wpT + (size_t)l * 4 * DM * DM, bp + (size_t)l * DM,
        nullptr, xf, BT, DM, 4 * DM, BT / 64,
        nullptr, nullptr, nullptr, nullptr, nullptr);
  }
  k_ln<<<BT, 256, 0, stream>>>(xf, lnfg, lnfb, nullptr, nullptr, xlnf, nullptr);
  if (fast_lm) {
    int nt = (NVOCAB + 127) / 128;
    k_g128<3><<<(BT / 128) * nt, 256, 0, stream>>>(
        xlnf, wlmT, out, BT, NVOCAB, DM, BT / 128);
  } else {
    k_gemm_f32b<<<dim3(BT / 128, (NVOCAB + 127) / 128), 256, 0, stream>>>(
        xlnf, Wlm, out, BT, NVOCAB, DM);
  }
}

// Round 12
// 963.814 us; speedup vs baseline: 5.6801x; 1.0022x over previous
//
#include <hip/hip_runtime.h>

typedef unsigned short u16;
typedef unsigned int u32;
typedef __attribute__((ext_vector_type(8))) short bf16x8;
typedef __attribute__((ext_vector_type(4))) float f32x4;

#define SEQ 1024
#define DM 768
#define NH 12
#define HD2 64
#define NLAYER 4
#define NVOCAB 50257
#define BT 2048  // B*T

__device__ __forceinline__ u16 f2bf(float f) {
  union { float f; u32 u; } v; v.f = f;
  u32 r = v.u + 0x7FFFu + ((v.u >> 16) & 1u);
  return (u16)(r >> 16);
}
__device__ __forceinline__ float bf2f(u16 u) {
  union { u32 u; float f; } v; v.u = ((u32)u) << 16;
  return v.f;
}

__device__ __forceinline__ void glds16(const u16* g, u16* l) {
  __builtin_amdgcn_global_load_lds(
      (const __attribute__((address_space(1))) u32*)(const void*)g,
      (__attribute__((address_space(3))) u32*)(void*)l, 16, 0, 0);
}

// ---------------- embedding ----------------
__global__ void k_embed(const int* __restrict__ idx, const float* __restrict__ wte,
                        float* __restrict__ xf) {
  int r = blockIdx.x;
  int tok = idx[r];
  const float* s = wte + (size_t)tok * DM;
  float* d = xf + (size_t)r * DM;
  for (int c = threadIdx.x; c < DM; c += 256) d[c] = s[c];
}

// ---------------- rope trig tables: [SEQ][16] cos/sin ----------------
__global__ void k_trig(float* __restrict__ ctab, float* __restrict__ stab) {
  int gid = blockIdx.x * 256 + threadIdx.x;  // over SEQ*16
  int tt = gid >> 4, j = gid & 15;
  float inv = powf(10000.f, -(float)j * (1.f / 32.f));
  float ang = (float)tt * inv;
  ctab[gid] = cosf(ang);
  stab[gid] = sinf(ang);
}

// ------- transpose + f32->bf16: in[R,C] f32 -> out[C,R] bf16 (64x64 tile) ----
__global__ void k_cvtT(const float* __restrict__ in, u16* __restrict__ out,
                       int R, int C) {
  __shared__ u16 t[64][68];
  int c0 = blockIdx.x * 64, r0 = blockIdx.y * 64;  // R always multiple of 64
  int tx = threadIdx.x & 15, ty = threadIdx.x >> 4;
  int c = c0 + tx * 4;
#pragma unroll
  for (int i = 0; i < 4; ++i) {
    int r = r0 + ty + i * 16;
    float4 v = make_float4(0.f, 0.f, 0.f, 0.f);
    if (c + 3 < C) {
      v = *(const float4*)&in[(size_t)r * C + c];
    } else {
      if (c + 0 < C) v.x = in[(size_t)r * C + c];
      if (c + 1 < C) v.y = in[(size_t)r * C + c + 1];
      if (c + 2 < C) v.z = in[(size_t)r * C + c + 2];
      if (c + 3 < C) v.w = in[(size_t)r * C + c + 3];
    }
    t[ty + i * 16][tx * 4 + 0] = f2bf(v.x);
    t[ty + i * 16][tx * 4 + 1] = f2bf(v.y);
    t[ty + i * 16][tx * 4 + 2] = f2bf(v.z);
    t[ty + i * 16][tx * 4 + 3] = f2bf(v.w);
  }
  __syncthreads();
  int wl = threadIdx.x & 31, grp = threadIdx.x >> 5;
#pragma unroll
  for (int it = 0; it < 8; ++it) {
    int cc = it * 8 + grp;
    int gcol = c0 + cc;
    if (gcol < C) {
      u32 wv = (u32)t[2 * wl][cc] | ((u32)t[2 * wl + 1][cc] << 16);
      *(u32*)&out[(size_t)gcol * R + r0 + 2 * wl] = wv;
    }
  }
}

// ---------------- block reductions (256 thr = 4 waves) ----------------
__device__ __forceinline__ float bsum(float v, float* red) {
#pragma unroll
  for (int o = 32; o > 0; o >>= 1) v += __shfl_down(v, o);
  if ((threadIdx.x & 63) == 0) red[threadIdx.x >> 6] = v;
  __syncthreads();
  if (threadIdx.x == 0) red[4] = red[0] + red[1] + red[2] + red[3];
  __syncthreads();
  return red[4];
}

// ---------------- dual layernorm (both read same x) ----------------
__global__ void k_ln(const float* __restrict__ x, const float* __restrict__ g1,
                     const float* __restrict__ b1, const float* __restrict__ g2,
                     const float* __restrict__ b2, u16* __restrict__ o1,
                     u16* __restrict__ o2) {
  __shared__ float red[8];
  int r = blockIdx.x;
  int t = threadIdx.x;
  const float* xr = x + (size_t)r * DM;
  float v0 = xr[t], v1 = xr[t + 256], v2 = xr[t + 512];
  float mean = bsum(v0 + v1 + v2, red) * (1.f / DM);
  float d0 = v0 - mean, d1 = v1 - mean, d2 = v2 - mean;
  float var = bsum(d0 * d0 + d1 * d1 + d2 * d2, red) * (1.f / DM);
  float rstd = rsqrtf(var + 1e-5f);
  u16* p1 = o1 + (size_t)r * DM;
  p1[t]       = f2bf(d0 * rstd * g1[t]       + b1[t]);
  p1[t + 256] = f2bf(d1 * rstd * g1[t + 256] + b1[t + 256]);
  p1[t + 512] = f2bf(d2 * rstd * g1[t + 512] + b1[t + 512]);
  if (o2) {
    u16* p2 = o2 + (size_t)r * DM;
    p2[t]       = f2bf(d0 * rstd * g2[t]       + b2[t]);
    p2[t + 256] = f2bf(d1 * rstd * g2[t + 256] + b2[t + 256]);
    p2[t + 512] = f2bf(d2 * rstd * g2[t + 512] + b2[t + 512]);
  }
}

// ---------------- fused flash attention, glds-staged double-buffered K/V ----
// q pre-scaled by 1/8 in the qkv epilogue; defer-max rescale (T13, THR=8).
__global__ void k_attn(const u16* __restrict__ qr, const u16* __restrict__ kr,
                       const u16* __restrict__ vT, u16* __restrict__ yb) {
  int ti = (int)gridDim.x - 1 - (int)blockIdx.x;  // big tiles first
  int bh = blockIdx.y;
  __shared__ u16 Ps[64 * 72];       // Q staging, then P tile (wave-private rows)
  __shared__ u16 Ks[2][4096];       // [64][64] XOR-swizzled
  __shared__ u16 Vs[2][4096];
  int tid = threadIdx.x;
  int rr = tid >> 2, cc = tid & 3;
  int w = tid >> 6, l = tid & 63;
  int rl = l & 15, g = l >> 4;
  {
    const u16* gq = qr + ((size_t)bh * SEQ + ti * 64 + rr) * HD2;
    *(uint4*)&Ps[rr * 72 + cc * 8]      = *(const uint4*)(gq + cc * 8);
    *(uint4*)&Ps[rr * 72 + cc * 8 + 32] = *(const uint4*)(gq + cc * 8 + 32);
  }
  int srow = w * 8 + (l >> 3);
  int gs = (l & 7) ^ (l >> 3);
  const u16* gkb = kr + (size_t)bh * SEQ * HD2;
  const u16* gvb = vT + (size_t)bh * HD2 * SEQ;
  glds16(gkb + (size_t)srow * 64 + gs * 8,        &Ks[0][w * 512]);
  glds16(gkb + (size_t)(32 + srow) * 64 + gs * 8, &Ks[0][2048 + w * 512]);
  glds16(gvb + (size_t)srow * SEQ + gs * 8,       &Vs[0][w * 512]);
  glds16(gvb + (size_t)(32 + srow) * SEQ + gs * 8,&Vs[0][2048 + w * 512]);
  __syncthreads();
  bf16x8 aq0 = *(const bf16x8*)&Ps[(w * 16 + rl) * 72 + g * 8];
  bf16x8 aq1 = *(const bf16x8*)&Ps[(w * 16 + rl) * 72 + 32 + g * 8];
  float m[4], lsum[4];
  f32x4 oacc[4] = {};
#pragma unroll
  for (int r2 = 0; r2 < 4; ++r2) { m[r2] = -3.0e38f; lsum[r2] = 0.f; }
  int qloc = w * 16 + g * 4;
  int sw = rl & 7;
  int cur = 0;
  for (int kt = 0; kt <= ti; ++kt) {
    if (kt < ti) {
      int nx = cur ^ 1;
      glds16(gkb + (size_t)((kt + 1) * 64 + srow) * 64 + gs * 8,      &Ks[nx][w * 512]);
      glds16(gkb + (size_t)((kt + 1) * 64 + 32 + srow) * 64 + gs * 8, &Ks[nx][2048 + w * 512]);
      glds16(gvb + (size_t)srow * SEQ + (kt + 1) * 64 + gs * 8,       &Vs[nx][w * 512]);
      glds16(gvb + (size_t)(32 + srow) * SEQ + (kt + 1) * 64 + gs * 8,&Vs[nx][2048 + w * 512]);
    }
    f32x4 s[4] = {};
    __builtin_amdgcn_s_setprio(1);
#pragma unroll
    for (int nt = 0; nt < 4; ++nt) {
      int r = (nt * 16 + rl) * 64;
      bf16x8 b0 = *(const bf16x8*)&Ks[cur][r + ((0 + g) ^ sw) * 8];
      bf16x8 b1 = *(const bf16x8*)&Ks[cur][r + ((4 + g) ^ sw) * 8];
      s[nt] = __builtin_amdgcn_mfma_f32_16x16x32_bf16(aq0, b0, s[nt], 0, 0, 0);
      s[nt] = __builtin_amdgcn_mfma_f32_16x16x32_bf16(aq1, b1, s[nt], 0, 0, 0);
    }
    __builtin_amdgcn_s_setprio(0);
    if (kt == ti) {
#pragma unroll
      for (int nt = 0; nt < 4; ++nt) {
        int col = nt * 16 + rl;
#pragma unroll
        for (int r2 = 0; r2 < 4; ++r2)
          if (col > qloc + r2) s[nt][r2] = -3.0e38f;
      }
    }
#pragma unroll
    for (int r2 = 0; r2 < 4; ++r2) {
      float pm = fmaxf(fmaxf(s[0][r2], s[1][r2]), fmaxf(s[2][r2], s[3][r2]));
#pragma unroll
      for (int o = 1; o < 16; o <<= 1) pm = fmaxf(pm, __shfl_xor(pm, o));
      if (pm > m[r2] + 8.f) {   // defer-max: only rescale on large growth
        float corr = __expf(m[r2] - pm);
        m[r2] = pm;
        lsum[r2] *= corr;
        oacc[0][r2] *= corr; oacc[1][r2] *= corr;
        oacc[2][r2] *= corr; oacc[3][r2] *= corr;
      }
      float p0 = __expf(s[0][r2] - m[r2]);
      float p1 = __expf(s[1][r2] - m[r2]);
      float p2 = __expf(s[2][r2] - m[r2]);
      float p3 = __expf(s[3][r2] - m[r2]);
      float ps = p0 + p1 + p2 + p3;
#pragma unroll
      for (int o = 1; o < 16; o <<= 1) ps += __shfl_xor(ps, o);
      lsum[r2] += ps;
      int prow = (qloc + r2) * 72;
      Ps[prow + rl]      = f2bf(p0);
      Ps[prow + 16 + rl] = f2bf(p1);
      Ps[prow + 32 + rl] = f2bf(p2);
      Ps[prow + 48 + rl] = f2bf(p3);
    }
    bf16x8 pa0 = *(const bf16x8*)&Ps[(w * 16 + rl) * 72 + g * 8];
    bf16x8 pa1 = *(const bf16x8*)&Ps[(w * 16 + rl) * 72 + 32 + g * 8];
    __builtin_amdgcn_s_setprio(1);
#pragma unroll
    for (int nt = 0; nt < 4; ++nt) {
      int r = (nt * 16 + rl) * 64;
      bf16x8 b0 = *(const bf16x8*)&Vs[cur][r + ((0 + g) ^ sw) * 8];
      bf16x8 b1 = *(const bf16x8*)&Vs[cur][r + ((4 + g) ^ sw) * 8];
      oacc[nt] = __builtin_amdgcn_mfma_f32_16x16x32_bf16(pa0, b0, oacc[nt], 0, 0, 0);
      oacc[nt] = __builtin_amdgcn_mfma_f32_16x16x32_bf16(pa1, b1, oacc[nt], 0, 0, 0);
    }
    __builtin_amdgcn_s_setprio(0);
    __syncthreads();
    cur ^= 1;
  }
  int b = bh / NH, h = bh % NH;
  float invl[4];
#pragma unroll
  for (int r2 = 0; r2 < 4; ++r2) invl[r2] = 1.f / lsum[r2];
#pragma unroll
  for (int nt = 0; nt < 4; ++nt) {
    int d = nt * 16 + rl;
#pragma unroll
    for (int r2 = 0; r2 < 4; ++r2) {
      int trow = ti * 64 + qloc + r2;
      yb[((size_t)(b * SEQ + trow)) * DM + h * HD2 + d] = f2bf(oacc[nt][r2] * invl[r2]);
    }
  }
}

// ------- 128x128 GEMM, BK=32, dbuf single-sync loop — logits (f32 NT out) ---
template <int MODE>
__global__ void k_g128(const u16* __restrict__ A, const u16* __restrict__ Bt,
                       float* __restrict__ outf, int M, int N, int K, int MT) {
  __shared__ u16 SM[16384];  // [As0|Bs0|As1|Bs1] 4096 u16 each; alias cw[32][132]
  float* cw = (float*)SM;
  int nwg = gridDim.x;
  int id = blockIdx.x;
  if ((nwg & 7) == 0) id = (id & 7) * (nwg >> 3) + (id >> 3);  // XCD swizzle
  int mt = id % MT, nt = id / MT;
  int m0 = mt * 128, n0 = nt * 128;
  int tid = threadIdx.x;
  int w = tid >> 6, l = tid & 63;
  int srow = w * 16 + (l >> 2);
  int gs = (l & 3) ^ ((l >> 3) & 3);    // pre-swizzled source chunk
  const u16* gA0 = A + (size_t)(m0 + srow) * K + gs * 8;
  const u16* gA1 = A + (size_t)(m0 + 64 + srow) * K + gs * 8;
  int rb0 = n0 + srow;      if (rb0 > N - 1) rb0 = N - 1;
  int rb1 = n0 + 64 + srow; if (rb1 > N - 1) rb1 = N - 1;
  const u16* gB0 = Bt + (size_t)rb0 * K + gs * 8;
  const u16* gB1 = Bt + (size_t)rb1 * K + gs * 8;
  int wm = (w >> 1) * 64, wn = (w & 1) * 64;
  int rl = l & 15, g = l >> 4;
  int sla = g ^ ((rl >> 1) & 3);  // read-side swizzle (lane-constant)
  f32x4 acc[4][4] = {};
  int nK = K >> 5;
  int cur = 0;
  {  // prologue: stage kt=0 into buf0
    u16* dA = SM + w * 512;
    glds16(gA0, dA); glds16(gA1, dA + 2048);
    u16* dB = SM + 4096 + w * 512;
    glds16(gB0, dB); glds16(gB1, dB + 2048);
  }
  __syncthreads();
  for (int kt = 0; kt < nK; ++kt) {
    if (kt + 1 < nK) {  // issue next-tile stage before compute
      u16* dA = SM + (cur ^ 1) * 8192 + w * 512;
      glds16(gA0 + (kt + 1) * 32, dA); glds16(gA1 + (kt + 1) * 32, dA + 2048);
      u16* dB = dA + 4096;
      glds16(gB0 + (kt + 1) * 32, dB); glds16(gB1 + (kt + 1) * 32, dB + 2048);
    }
    const u16* As = SM + cur * 8192;
    const u16* Bs = As + 4096;
    bf16x8 af[4], bfr[4];
    __builtin_amdgcn_s_setprio(1);
#pragma unroll
    for (int i = 0; i < 4; ++i)
      af[i] = *(const bf16x8*)&As[(wm + i * 16 + rl) * 32 + sla * 8];
#pragma unroll
    for (int j = 0; j < 4; ++j)
      bfr[j] = *(const bf16x8*)&Bs[(wn + j * 16 + rl) * 32 + sla * 8];
#pragma unroll
    for (int i = 0; i < 4; ++i)
#pragma unroll
      for (int j = 0; j < 4; ++j)
        acc[i][j] = __builtin_amdgcn_mfma_f32_16x16x32_bf16(af[i], bfr[j],
                                                            acc[i][j], 0, 0, 0);
    __builtin_amdgcn_s_setprio(0);
    __syncthreads();
    cur ^= 1;
  }
  // epilogue: 32-row chunks through LDS, coalesced nontemporal f32 row writes
#pragma unroll
  for (int ch = 0; ch < 4; ++ch) {
    if ((w >> 1) == (ch >> 1)) {
      int ib = (ch & 1) * 2;
#pragma unroll
      for (int ii = 0; ii < 2; ++ii) {
#pragma unroll
        for (int j = 0; j < 4; ++j) {
          int col = wn + j * 16 + rl;
#pragma unroll
          for (int r2 = 0; r2 < 4; ++r2) {
            int rowc = ii * 16 + g * 4 + r2;
            cw[rowc * 132 + col] = acc[ib + ii][j][r2];
          }
        }
      }
    }
    __syncthreads();
    for (int t = tid; t < 4096; t += 256) {
      int rowc = t >> 7, col = t & 127;
      int gc = n0 + col;
      if (gc < N)
        __builtin_nontemporal_store(cw[rowc * 132 + col],
                                    &outf[(size_t)(m0 + ch * 32 + rowc) * N + gc]);
    }
    __syncthreads();
  }
}

// ------- 64x128 block-tile GEMM, BK=64, dbuf; wave = 32x64 (16 MFMA/iter) ---
// MODE 1: bf16 gelu out (+bias), packed u32 stores via LDS staging
// MODE 4: fused qkv: bias + rope(q,k)[q*1/8] -> qr/kr; v -> vT  (2 heads/tile)
// N must be a multiple of 128.
template <int MODE>
__global__ void k_gw(const u16* __restrict__ A, const u16* __restrict__ Bt,
                     const float* __restrict__ bias, u16* __restrict__ outb,
                     int M, int N, int K, int MT,
                     const float* __restrict__ ctab,
                     const float* __restrict__ stab, u16* __restrict__ qrp,
                     u16* __restrict__ krp, u16* __restrict__ vTp) {
  __shared__ u16 SM2[24576];  // A0|A1 (4096 u16 each) | B0|B1 (8192 u16 each)
  float* cw = (float*)SM2;    // [64][133] f32 epilogue staging (34 KB < 48 KB)
  int nwg = gridDim.x;
  int id = blockIdx.x;
  if ((nwg & 7) == 0) id = (id & 7) * (nwg >> 3) + (id >> 3);  // XCD swizzle
  int mt = id % MT, nt = id / MT;
  int m0 = mt * 64, n0 = nt * 128;
  int tid = threadIdx.x;
  int w = tid >> 6, l = tid & 63;
  int row0 = tid >> 3, slot0 = tid & 7;
  int gs0 = slot0 ^ (row0 & 7);
  const u16* gA0 = A + (size_t)(m0 + row0) * K + gs0 * 8;
  const u16* gA1 = gA0 + (size_t)32 * K;
  const u16* gB0 = Bt + (size_t)(n0 + row0) * K + gs0 * 8;
  const u16* gB1 = gB0 + (size_t)32 * K;
  const u16* gB2 = gB0 + (size_t)64 * K;
  const u16* gB3 = gB0 + (size_t)96 * K;
  int wm = (w >> 1) * 32, wn = (w & 1) * 64;
  int rl = l & 15, g = l >> 4;
  int sl0 = g ^ (rl & 7), sl1 = (4 + g) ^ (rl & 7);
  f32x4 acc[2][4] = {};
  int nK = K >> 6;
  int cur = 0;
  {  // prologue stage kt=0 -> buf0
    u16* dA = SM2;
    glds16(gA0, dA + w * 512); glds16(gA1, dA + 2048 + w * 512);
    u16* dB = SM2 + 8192;
    glds16(gB0, dB + w * 512);        glds16(gB1, dB + 2048 + w * 512);
    glds16(gB2, dB + 4096 + w * 512); glds16(gB3, dB + 6144 + w * 512);
  }
  __syncthreads();
  for (int kt = 0; kt < nK; ++kt) {
    if (kt + 1 < nK) {
      int ka = (kt + 1) * 64;
      u16* dA = SM2 + (cur ^ 1) * 4096;
      glds16(gA0 + ka, dA + w * 512); glds16(gA1 + ka, dA + 2048 + w * 512);
      u16* dB = SM2 + 8192 + (cur ^ 1) * 8192;
      glds16(gB0 + ka, dB + w * 512);        glds16(gB1 + ka, dB + 2048 + w * 512);
      glds16(gB2 + ka, dB + 4096 + w * 512); glds16(gB3 + ka, dB + 6144 + w * 512);
    }
    const u16* Ac = SM2 + cur * 4096;
    const u16* Bc = SM2 + 8192 + cur * 8192;
    bf16x8 a0[2], a1[2], b0[4], b1[4];
    __builtin_amdgcn_s_setprio(1);
#pragma unroll
    for (int i = 0; i < 2; ++i) {
      int r = (wm + i * 16 + rl) * 64;
      a0[i] = *(const bf16x8*)&Ac[r + sl0 * 8];
      a1[i] = *(const bf16x8*)&Ac[r + sl1 * 8];
    }
#pragma unroll
    for (int j = 0; j < 4; ++j) {
      int r = (wn + j * 16 + rl) * 64;
      b0[j] = *(const bf16x8*)&Bc[r + sl0 * 8];
      b1[j] = *(const bf16x8*)&Bc[r + sl1 * 8];
    }
#pragma unroll
    for (int i = 0; i < 2; ++i)
#pragma unroll
      for (int j = 0; j < 4; ++j) {
        acc[i][j] = __builtin_amdgcn_mfma_f32_16x16x32_bf16(a0[i], b0[j],
                                                            acc[i][j], 0, 0, 0);
        acc[i][j] = __builtin_amdgcn_mfma_f32_16x16x32_bf16(a1[i], b1[j],
                                                            acc[i][j], 0, 0, 0);
      }
    __builtin_amdgcn_s_setprio(0);
    __syncthreads();
    cur ^= 1;
  }
  // ---- epilogue: stage acc (+bias [,gelu]) to cw[64][133] ----
#pragma unroll
  for (int i = 0; i < 2; ++i) {
#pragma unroll
    for (int j = 0; j < 4; ++j) {
      int col = wn + j * 16 + rl;
      float bv = bias[n0 + col];
#pragma unroll
      for (int r2 = 0; r2 < 4; ++r2) {
        float v = acc[i][j][r2] + bv;
        if (MODE == 1) {
          float u = 0.7978845608028654f * (v + 0.044715f * v * v * v);
          v = 0.5f * v * (1.f + tanhf(u));
        }
        cw[(wm + i * 16 + g * 4 + r2) * 133 + col] = v;
      }
    }
  }
  __syncthreads();
  if (MODE == 1) {  // packed u32 bf16 row writes
    for (int t = tid; t < 4096; t += 256) {
      int rowc = t >> 6, cp = t & 63;
      u32 wv = (u32)f2bf(cw[rowc * 133 + 2 * cp]) |
               ((u32)f2bf(cw[rowc * 133 + 2 * cp + 1]) << 16);
      *(u32*)&outb[(size_t)(m0 + rowc) * N + n0 + 2 * cp] = wv;
    }
  } else {  // MODE 4: tile = 64 tokens x 2 heads (never straddles q/k/v)
    int reg = n0 / DM;
    int h0 = (n0 % DM) / 64;
    int bb = m0 >> 10;           // 64 | 1024 -> single batch per tile
    int t0 = m0 & (SEQ - 1);
    size_t bhb = (size_t)bb * NH + h0;
    if (reg < 2) {
      u16* dst = (reg == 0) ? qrp : krp;
      float qs = (reg == 0) ? 0.125f : 1.f;  // fold 1/sqrt(HD) into q (exact)
      for (int t = tid; t < 4096; t += 256) {
        int rowc = t >> 6, cp = t & 63;
        int c = 2 * cp;               // col (even), 0..126
        int hh = c >> 6, d = c & 63;  // head sub-index, local dim (even)
        int tt = t0 + rowc;
        float x0 = cw[rowc * 133 + c];
        float x1 = cw[rowc * 133 + c + 1];
        float o0, o1;
        if (d < 32) {
          float y0 = cw[rowc * 133 + c + 32];
          float y1 = cw[rowc * 133 + c + 33];
          float c0 = 1.f, s0 = 0.f, c1 = 1.f, s1 = 0.f;
          if (d < 16) {
            c0 = ctab[tt * 16 + d];     s0 = stab[tt * 16 + d];
            c1 = ctab[tt * 16 + d + 1]; s1 = stab[tt * 16 + d + 1];
          }
          o0 = x0 * c0 - y0 * s0;
          o1 = x1 * c1 - y1 * s1;
        } else {
          int j = d - 32;
          float y0 = cw[rowc * 133 + c - 32];
          float y1 = cw[rowc * 133 + c - 31];
          float c0 = 1.f, s0 = 0.f, c1 = 1.f, s1 = 0.f;
          if (j < 16) {
            c0 = ctab[tt * 16 + j];     s0 = stab[tt * 16 + j];
            c1 = ctab[tt * 16 + j + 1]; s1 = stab[tt * 16 + j + 1];
          }
          o0 = x0 * c0 + y0 * s0;
          o1 = x1 * c1 + y1 * s1;
        }
        u32 wv = (u32)f2bf(o0 * qs) | ((u32)f2bf(o1 * qs) << 16);
        *(u32*)&dst[((bhb + hh) * SEQ + tt) * HD2 + d] = wv;
      }
    } else {  // v transposed write vT[bh][d][t], 2 tokens per u32
      for (int t = tid; t < 4096; t += 256) {
        int dcol = t >> 5, p = t & 31;    // col 0..127, token-pair 0..31
        int hh = dcol >> 6, d = dcol & 63;
        int tt = t0 + 2 * p;
        u32 wv = (u32)f2bf(cw[(2 * p) * 133 + dcol]) |
                 ((u32)f2bf(cw[(2 * p + 1) * 133 + dcol]) << 16);
        *(u32*)&vTp[((bhb + hh) * HD2 + d) * SEQ + tt] = wv;
      }
    }
  }
}

// ------- 64x64-tile GEMM, BK=64, dbuf, split-K residual add (wo / wp) -------
__global__ void k_g64r(const u16* __restrict__ A, const u16* __restrict__ Bt,
                       const float* __restrict__ bias,
                       float* __restrict__ outf, int M, int N, int K, int MT) {
  __shared__ u16 As[8192];  // 2 x [64][64]
  __shared__ u16 Bs[8192];
  int nwg = gridDim.x;
  int id = blockIdx.x;
  if ((nwg & 7) == 0) id = (id & 7) * (nwg >> 3) + (id >> 3);  // XCD swizzle
  int mt = id % MT, nt = id / MT;
  int sk = blockIdx.y, nsk = gridDim.y;
  int Kc = K / nsk, k0 = sk * Kc;
  int m0 = mt * 64, n0 = nt * 64;
  int tid = threadIdx.x;
  int w = tid >> 6, l = tid & 63;
  int row0 = tid >> 3, slot0 = tid & 7;
  int gs0 = slot0 ^ (row0 & 7);
  const u16* gA0 = A + (size_t)(m0 + row0) * K + k0 + gs0 * 8;
  const u16* gA1 = gA0 + (size_t)32 * K;
  const u16* gB0 = Bt + (size_t)(n0 + row0) * K + k0 + gs0 * 8;
  const u16* gB1 = gB0 + (size_t)32 * K;
  int wm = (w >> 1) * 32, wn = (w & 1) * 32;
  int rl = l & 15, g = l >> 4;
  int sl0 = g ^ (rl & 7), sl1 = (4 + g) ^ (rl & 7);
  f32x4 acc[2][2] = {};
  int nK = Kc >> 6;
  int cur = 0;
  {  // prologue stage kt=0 -> buf0
    glds16(gA0, As + w * 512); glds16(gA1, As + 2048 + w * 512);
    glds16(gB0, Bs + w * 512); glds16(gB1, Bs + 2048 + w * 512);
  }
  __syncthreads();
  for (int kt = 0; kt < nK; ++kt) {
    if (kt + 1 < nK) {
      int nx = (cur ^ 1) * 4096;
      glds16(gA0 + (kt + 1) * 64, As + nx + w * 512);
      glds16(gA1 + (kt + 1) * 64, As + nx + 2048 + w * 512);
      glds16(gB0 + (kt + 1) * 64, Bs + nx + w * 512);
      glds16(gB1 + (kt + 1) * 64, Bs + nx + 2048 + w * 512);
    }
    const u16* Ac = As + cur * 4096;
    const u16* Bc = Bs + cur * 4096;
    bf16x8 a0[2], a1[2], b0[2], b1[2];
    __builtin_amdgcn_s_setprio(1);
#pragma unroll
    for (int i = 0; i < 2; ++i) {
      int r = (wm + i * 16 + rl) * 64;
      a0[i] = *(const bf16x8*)&Ac[r + sl0 * 8];
      a1[i] = *(const bf16x8*)&Ac[r + sl1 * 8];
    }
#pragma unroll
    for (int j = 0; j < 2; ++j) {
      int r = (wn + j * 16 + rl) * 64;
      b0[j] = *(const bf16x8*)&Bc[r + sl0 * 8];
      b1[j] = *(const bf16x8*)&Bc[r + sl1 * 8];
    }
#pragma unroll
    for (int i = 0; i < 2; ++i)
#pragma unroll
      for (int j = 0; j < 2; ++j) {
        acc[i][j] = __builtin_amdgcn_mfma_f32_16x16x32_bf16(a0[i], b0[j],
                                                            acc[i][j], 0, 0, 0);
        acc[i][j] = __builtin_amdgcn_mfma_f32_16x16x32_bf16(a1[i], b1[j],
                                                            acc[i][j], 0, 0, 0);
      }
    __builtin_amdgcn_s_setprio(0);
    __syncthreads();
    cur ^= 1;
  }
#pragma unroll
  for (int i = 0; i < 2; ++i) {
#pragma unroll
    for (int j = 0; j < 2; ++j) {
      int col = n0 + wn + j * 16 + rl;
      float bv = bias ? bias[col] : 0.f;
#pragma unroll
      for (int r2 = 0; r2 < 4; ++r2) {
        int row = m0 + wm + i * 16 + g * 4 + r2;
        float v = acc[i][j][r2];
        if (sk == 0) v += bv;
        atomicAdd(&outf[(size_t)row * N + col], v);
      }
    }
  }
}

// ---------------- fallback GEMM (f32 B, on-the-fly cvt) — logits only --------
__global__ void k_gemm_f32b(const u16* __restrict__ A, const float* __restrict__ B,
                            float* __restrict__ outf, int M, int N, int K) {
  __shared__ u16 As[128 * 40];
  __shared__ u16 Bs[4 * 128 * 12];
  int tid = threadIdx.x;
  int wid = tid >> 6, lane = tid & 63;
  int rl = lane & 15, g = lane >> 4;
  int m0 = blockIdx.x * 128, n0 = blockIdx.y * 128;
  int wm = (wid >> 1) * 64, wn = (wid & 1) * 64;
  int ar = tid >> 2, ac = tid & 3;
  int bn = tid & 127, bq = tid >> 7;
  f32x4 acc[4][4] = {};
  int nK = K / 32;
  for (int kt = 0; kt < nK; ++kt) {
    __syncthreads();
    {
      const u16* ga = A + (size_t)(m0 + ar) * K + kt * 32 + ac * 8;
      *(uint4*)&As[ar * 40 + ac * 8] = *(const uint4*)ga;
      *(uint4*)&As[(ar + 64) * 40 + ac * 8] = *(const uint4*)(ga + (size_t)64 * K);
    }
    int col = n0 + bn;
#pragma unroll
    for (int r = 0; r < 4; ++r) {
      int kq = bq + 2 * r;
      int kk = kt * 32 + kq * 4;
      float f0 = 0.f, f1 = 0.f, f2v = 0.f, f3 = 0.f;
      if (col < N) {
        const float* gb = B + (size_t)kk * N + col;
        f0 = gb[0]; f1 = gb[(size_t)N]; f2v = gb[(size_t)2 * N]; f3 = gb[(size_t)3 * N];
      }
      uint2 wv;
      wv.x = (u32)f2bf(f0) | ((u32)f2bf(f1) << 16);
      wv.y = (u32)f2bf(f2v) | ((u32)f2bf(f3) << 16);
      *(uint2*)&Bs[(kq >> 1) * 1536 + bn * 12 + (kq & 1) * 4] = wv;
    }
    __syncthreads();
    bf16x8 af[4], bfr[4];
#pragma unroll
    for (int mt = 0; mt < 4; ++mt)
      af[mt] = *(const bf16x8*)&As[(wm + mt * 16 + rl) * 40 + g * 8];
#pragma unroll
    for (int nt = 0; nt < 4; ++nt) {
      const u16* p = &Bs[g * 1536 + (wn + nt * 16 + rl) * 12];
      union { bf16x8 v; uint2 u2[2]; } tmp;
      tmp.u2[0] = *(const uint2*)p;
      tmp.u2[1] = *(const uint2*)(p + 4);
      bfr[nt] = tmp.v;
    }
#pragma unroll
    for (int mt = 0; mt < 4; ++mt)
#pragma unroll
      for (int nt = 0; nt < 4; ++nt)
        acc[mt][nt] = __builtin_amdgcn_mfma_f32_16x16x32_bf16(af[mt], bfr[nt],
                                                              acc[mt][nt], 0, 0, 0);
  }
#pragma unroll
  for (int mt = 0; mt < 4; ++mt)
#pragma unroll
    for (int nt = 0; nt < 4; ++nt) {
      int col = n0 + wn + nt * 16 + rl;
      if (col >= N) continue;
#pragma unroll
      for (int r2 = 0; r2 < 4; ++r2) {
        int row = m0 + wm + mt * 16 + g * 4 + r2;
        outf[(size_t)row * N + col] = acc[mt][nt][r2];
      }
    }
}

extern "C" void kernel_launch(void* const* d_in, const int* in_sizes, int n_in,
                              void* d_out, int out_size, void* d_ws, size_t ws_size,
                              hipStream_t stream) {
  (void)in_sizes; (void)n_in; (void)out_size;
  const int*   idx  = (const int*)  d_in[0];
  const float* wte  = (const float*)d_in[1];
  const float* ln1g = (const float*)d_in[2];
  const float* ln1b = (const float*)d_in[3];
  const float* Wqkv = (const float*)d_in[4];
  const float* bqkv = (const float*)d_in[5];
  const float* Wo   = (const float*)d_in[6];
  const float* bo   = (const float*)d_in[7];
  const float* ln2g = (const float*)d_in[8];
  const float* ln2b = (const float*)d_in[9];
  const float* Wfc  = (const float*)d_in[10];
  const float* bfc  = (const float*)d_in[11];
  const float* Wp   = (const float*)d_in[12];
  const float* bp   = (const float*)d_in[13];
  const float* lnfg = (const float*)d_in[14];
  const float* lnfb = (const float*)d_in[15];
  const float* Wlm  = (const float*)d_in[16];
  float* out = (float*)d_out;

  // Scratch packed into d_out (all dead before the logits GEMM rewrites d_out).
  char* sb = (char*)d_out;
  size_t off = 0;
  auto alloc = [&](size_t bytes) {
    char* p = sb + off;
    off += (bytes + 255) & ~(size_t)255;
    return (void*)p;
  };
  float* xf  = (float*)alloc((size_t)BT * DM * 4);
  u16* h1b   = (u16*)alloc((size_t)BT * DM * 2);
  u16* h2b   = (u16*)alloc((size_t)BT * DM * 2);
  u16* qr    = (u16*)alloc((size_t)BT * DM * 2);
  u16* kr    = (u16*)alloc((size_t)BT * DM * 2);
  u16* vT    = (u16*)alloc((size_t)BT * DM * 2);
  u16* yb    = (u16*)alloc((size_t)BT * DM * 2);
  u16* hgel  = (u16*)alloc((size_t)BT * 4 * DM * 2);
  float* ctab = (float*)alloc((size_t)SEQ * 16 * 4);
  float* stab = (float*)alloc((size_t)SEQ * 16 * 4);
  // transposed bf16 weights (also dead before logits GEMM)
  u16* wqkvT = (u16*)alloc((size_t)NLAYER * 3 * DM * DM * 2);
  u16* woT   = (u16*)alloc((size_t)NLAYER * DM * DM * 2);
  u16* wfcT  = (u16*)alloc((size_t)NLAYER * 4 * DM * DM * 2);
  u16* wpT   = (u16*)alloc((size_t)NLAYER * 4 * DM * DM * 2);

  // Wlm^T (77 MB) must survive the logits GEMM -> d_ws if it fits.
  size_t wlmT_bytes = (size_t)NVOCAB * DM * 2;
  size_t xlnf_bytes = (size_t)BT * DM * 2;
  bool fast_lm = ws_size >= wlmT_bytes + xlnf_bytes + 512;
  u16* wlmT = (u16*)d_ws;
  u16* xlnf = fast_lm ? (u16*)((char*)d_ws + ((wlmT_bytes + 255) & ~(size_t)255))
                      : (u16*)d_ws;

  // ---- weight conversion + trig tables ----
  k_trig<<<(SEQ * 16) / 256, 256, 0, stream>>>(ctab, stab);
  for (int l = 0; l < NLAYER; ++l) {
    k_cvtT<<<dim3((3 * DM + 63) / 64, DM / 64), 256, 0, stream>>>(
        Wqkv + (size_t)l * DM * 3 * DM, wqkvT + (size_t)l * 3 * DM * DM, DM, 3 * DM);
    k_cvtT<<<dim3(DM / 64, DM / 64), 256, 0, stream>>>(
        Wo + (size_t)l * DM * DM, woT + (size_t)l * DM * DM, DM, DM);
    k_cvtT<<<dim3((4 * DM) / 64, DM / 64), 256, 0, stream>>>(
        Wfc + (size_t)l * DM * 4 * DM, wfcT + (size_t)l * 4 * DM * DM, DM, 4 * DM);
    k_cvtT<<<dim3(DM / 64, (4 * DM) / 64), 256, 0, stream>>>(
        Wp + (size_t)l * 4 * DM * DM, wpT + (size_t)l * 4 * DM * DM, 4 * DM, DM);
  }
  if (fast_lm)
    k_cvtT<<<dim3((NVOCAB + 63) / 64, DM / 64), 256, 0, stream>>>(Wlm, wlmT, DM, NVOCAB);

  k_embed<<<BT, 256, 0, stream>>>(idx, wte, xf);
  for (int l = 0; l < NLAYER; ++l) {
    k_ln<<<BT, 256, 0, stream>>>(xf, ln1g + l * DM, ln1b + l * DM,
                                 ln2g + l * DM, ln2b + l * DM, h1b, h2b);
    // fused qkv GEMM + bias + rope (+q/8) + v-transpose (64x128 tile, 576 blk)
    k_gw<4><<<(BT / 64) * (3 * DM / 128), 256, 0, stream>>>(
        h1b, wqkvT + (size_t)l * 3 * DM * DM, bqkv + (size_t)l * 3 * DM,
        nullptr, BT, 3 * DM, DM, BT / 64, ctab, stab, qr, kr, vT);
    k_attn<<<dim3(SEQ / 64, 2 * NH), 256, 0, stream>>>(qr, kr, vT, yb);
    k_g64r<<<dim3((BT / 64) * (DM / 64), 2), 256, 0, stream>>>(
        yb, woT + (size_t)l * DM * DM, bo + (size_t)l * DM, xf, BT, DM, DM, BT / 64);
    // fc GEMM + bias + gelu (64x128 tile, 768 blocks)
    k_gw<1><<<(BT / 64) * (4 * DM / 128), 256, 0, stream>>>(
        h2b, wfcT + (size_t)l * 4 * DM * DM, bfc + (size_t)l * 4 * DM,
        hgel, BT, 4 * DM, DM, BT / 64, nullptr, nullptr, nullptr, nullptr, nullptr);
    k_g64r<<<dim3((BT / 64) * (DM / 64), 4), 256, 0, stream>>>(
        hgel, wpT + (size_t)l * 4 * DM * DM, bp + (size_t)l * DM, xf, BT, DM, 4 * DM,
        BT / 64);
  }
  k_ln<<<BT, 256, 0, stream>>>(xf, lnfg, lnfb, nullptr, nullptr, xlnf, nullptr);
  if (fast_lm) {
    int nt = (NVOCAB + 127) / 128;
    k_g128<3><<<(BT / 128) * nt, 256, 0, stream>>>(
        xlnf, wlmT, out, BT, NVOCAB, DM, BT / 128);
  } else {
    k_gemm_f32b<<<dim3(BT / 128, (NVOCAB + 127) / 128), 256, 0, stream>>>(
        xlnf, Wlm, out, BT, NVOCAB, DM);
  }
}

// Round 13
// 898.045 us; speedup vs baseline: 6.0961x; 1.0732x over previous
//
#include <hip/hip_runtime.h>

typedef unsigned short u16;
typedef unsigned int u32;
typedef __attribute__((ext_vector_type(8))) short bf16x8;
typedef __attribute__((ext_vector_type(4))) float f32x4;

#define SEQ 1024
#define DM 768
#define NH 12
#define HD2 64
#define NLAYER 4
#define NVOCAB 50257
#define BT 2048  // B*T

__device__ __forceinline__ u16 f2bf(float f) {
  union { float f; u32 u; } v; v.f = f;
  u32 r = v.u + 0x7FFFu + ((v.u >> 16) & 1u);
  return (u16)(r >> 16);
}
__device__ __forceinline__ float bf2f(u16 u) {
  union { u32 u; float f; } v; v.u = ((u32)u) << 16;
  return v.f;
}

__device__ __forceinline__ void glds16(const u16* g, u16* l) {
  __builtin_amdgcn_global_load_lds(
      (const __attribute__((address_space(1))) u32*)(const void*)g,
      (__attribute__((address_space(3))) u32*)(void*)l, 16, 0, 0);
}

// ---- transpose+cvt one 64x64 tile: in[R,C] f32 -> out[C,R] bf16 ------------
__device__ __forceinline__ void cvt_tile(const float* __restrict__ in,
                                         u16* __restrict__ out, int R, int C,
                                         int cx, int ry, u16 (*t)[68]) {
  int c0 = cx * 64, r0 = ry * 64;  // R always multiple of 64
  int tx = threadIdx.x & 15, ty = threadIdx.x >> 4;
  int c = c0 + tx * 4;
#pragma unroll
  for (int i = 0; i < 4; ++i) {
    int r = r0 + ty + i * 16;
    float4 v = make_float4(0.f, 0.f, 0.f, 0.f);
    if (c + 3 < C) {
      v = *(const float4*)&in[(size_t)r * C + c];
    } else {
      if (c + 0 < C) v.x = in[(size_t)r * C + c];
      if (c + 1 < C) v.y = in[(size_t)r * C + c + 1];
      if (c + 2 < C) v.z = in[(size_t)r * C + c + 2];
      if (c + 3 < C) v.w = in[(size_t)r * C + c + 3];
    }
    t[ty + i * 16][tx * 4 + 0] = f2bf(v.x);
    t[ty + i * 16][tx * 4 + 1] = f2bf(v.y);
    t[ty + i * 16][tx * 4 + 2] = f2bf(v.z);
    t[ty + i * 16][tx * 4 + 3] = f2bf(v.w);
  }
  __syncthreads();
  int wl = threadIdx.x & 31, grp = threadIdx.x >> 5;
#pragma unroll
  for (int it = 0; it < 8; ++it) {
    int cc = it * 8 + grp;
    int gcol = c0 + cc;
    if (gcol < C) {
      u32 wv = (u32)t[2 * wl][cc] | ((u32)t[2 * wl + 1][cc] << 16);
      *(u32*)&out[(size_t)gcol * R + r0 + 2 * wl] = wv;
    }
  }
}

// ---- mega prologue: embed | rope trig | all weight cvt+transpose -----------
// block decode: [0,BT) embed rows; [BT,BT+64) trig; then per-layer weight
// tiles (1728/layer: qkv 432, wo 144, wfc 576, wp 576); then Wlm tiles.
__global__ void k_prep(const int* __restrict__ idx, const float* __restrict__ wte,
                       float* __restrict__ xf, float* __restrict__ ctab,
                       float* __restrict__ stab, const float* __restrict__ Wqkv,
                       const float* __restrict__ Wo, const float* __restrict__ Wfc,
                       const float* __restrict__ Wp, const float* __restrict__ Wlm,
                       u16* __restrict__ wqkvT, u16* __restrict__ woT,
                       u16* __restrict__ wfcT, u16* __restrict__ wpT,
                       u16* __restrict__ wlmT) {
  __shared__ u16 t[64][68];
  int bid = blockIdx.x;
  if (bid < BT) {  // embedding
    int tok = idx[bid];
    const float* s = wte + (size_t)tok * DM;
    float* d = xf + (size_t)bid * DM;
    for (int c = threadIdx.x; c < DM; c += 256) d[c] = s[c];
    return;
  }
  bid -= BT;
  if (bid < 64) {  // trig tables [SEQ][16]
    int gid = bid * 256 + threadIdx.x;
    int tt = gid >> 4, j = gid & 15;
    float inv = powf(10000.f, -(float)j * (1.f / 32.f));
    float ang = (float)tt * inv;
    ctab[gid] = cosf(ang);
    stab[gid] = sinf(ang);
    return;
  }
  bid -= 64;
  if (bid < NLAYER * 1728) {
    int layer = bid / 1728, r = bid % 1728;
    if (r < 432) {  // Wqkv [DM, 3DM]: 36 x-tiles, 12 y-tiles
      cvt_tile(Wqkv + (size_t)layer * DM * 3 * DM,
               wqkvT + (size_t)layer * 3 * DM * DM, DM, 3 * DM, r % 36, r / 36, t);
      return;
    }
    r -= 432;
    if (r < 144) {  // Wo [DM, DM]
      cvt_tile(Wo + (size_t)layer * DM * DM, woT + (size_t)layer * DM * DM,
               DM, DM, r % 12, r / 12, t);
      return;
    }
    r -= 144;
    if (r < 576) {  // Wfc [DM, 4DM]: 48 x, 12 y
      cvt_tile(Wfc + (size_t)layer * DM * 4 * DM,
               wfcT + (size_t)layer * 4 * DM * DM, DM, 4 * DM, r % 48, r / 48, t);
      return;
    }
    r -= 576;       // Wp [4DM, DM]: 12 x, 48 y
    cvt_tile(Wp + (size_t)layer * 4 * DM * DM, wpT + (size_t)layer * 4 * DM * DM,
             4 * DM, DM, r % 12, r / 12, t);
    return;
  }
  bid -= NLAYER * 1728;  // Wlm [DM, NVOCAB]: 786 x, 12 y
  cvt_tile(Wlm, wlmT, DM, NVOCAB, bid % 786, bid / 786, t);
}

// ---------------- layernorm: wave-per-row, shuffle-only reductions ----------
__global__ void k_ln(const float* __restrict__ x, const float* __restrict__ g1,
                     const float* __restrict__ b1, const float* __restrict__ g2,
                     const float* __restrict__ b2, u16* __restrict__ o1,
                     u16* __restrict__ o2) {
  int w = threadIdx.x >> 6, l = threadIdx.x & 63;
  int r = blockIdx.x * 4 + w;
  const float* xr = x + (size_t)r * DM;
  float2 v[6];
  float s = 0.f;
#pragma unroll
  for (int i = 0; i < 6; ++i) {
    v[i] = *(const float2*)&xr[2 * l + i * 128];
    s += v[i].x + v[i].y;
  }
#pragma unroll
  for (int o = 1; o < 64; o <<= 1) s += __shfl_xor(s, o);
  float mean = s * (1.f / DM);
  float vs = 0.f;
#pragma unroll
  for (int i = 0; i < 6; ++i) {
    float dx = v[i].x - mean, dy = v[i].y - mean;
    vs += dx * dx + dy * dy;
  }
#pragma unroll
  for (int o = 1; o < 64; o <<= 1) vs += __shfl_xor(vs, o);
  float rstd = rsqrtf(vs * (1.f / DM) + 1e-5f);
  u16* p1 = o1 + (size_t)r * DM;
#pragma unroll
  for (int i = 0; i < 6; ++i) {
    int c = 2 * l + i * 128;
    float2 gg = *(const float2*)&g1[c];
    float2 bb = *(const float2*)&b1[c];
    u32 wv = (u32)f2bf((v[i].x - mean) * rstd * gg.x + bb.x) |
             ((u32)f2bf((v[i].y - mean) * rstd * gg.y + bb.y) << 16);
    *(u32*)&p1[c] = wv;
  }
  if (o2) {
    u16* p2 = o2 + (size_t)r * DM;
#pragma unroll
    for (int i = 0; i < 6; ++i) {
      int c = 2 * l + i * 128;
      float2 gg = *(const float2*)&g2[c];
      float2 bb = *(const float2*)&b2[c];
      u32 wv = (u32)f2bf((v[i].x - mean) * rstd * gg.x + bb.x) |
               ((u32)f2bf((v[i].y - mean) * rstd * gg.y + bb.y) << 16);
      *(u32*)&p2[c] = wv;
    }
  }
}

// ---------------- fused flash attention, glds-staged double-buffered K/V ----
// q pre-scaled by 1/8 in the qkv epilogue; defer-max rescale (T13, THR=8).
__global__ void k_attn(const u16* __restrict__ qr, const u16* __restrict__ kr,
                       const u16* __restrict__ vT, u16* __restrict__ yb) {
  int ti = (int)gridDim.x - 1 - (int)blockIdx.x;  // big tiles first
  int bh = blockIdx.y;
  __shared__ u16 Ps[64 * 72];       // Q staging, then P tile (wave-private rows)
  __shared__ u16 Ks[2][4096];       // [64][64] XOR-swizzled
  __shared__ u16 Vs[2][4096];
  int tid = threadIdx.x;
  int rr = tid >> 2, cc = tid & 3;
  int w = tid >> 6, l = tid & 63;
  int rl = l & 15, g = l >> 4;
  {
    const u16* gq = qr + ((size_t)bh * SEQ + ti * 64 + rr) * HD2;
    *(uint4*)&Ps[rr * 72 + cc * 8]      = *(const uint4*)(gq + cc * 8);
    *(uint4*)&Ps[rr * 72 + cc * 8 + 32] = *(const uint4*)(gq + cc * 8 + 32);
  }
  int srow = w * 8 + (l >> 3);
  int gs = (l & 7) ^ (l >> 3);
  const u16* gkb = kr + (size_t)bh * SEQ * HD2;
  const u16* gvb = vT + (size_t)bh * HD2 * SEQ;
  glds16(gkb + (size_t)srow * 64 + gs * 8,        &Ks[0][w * 512]);
  glds16(gkb + (size_t)(32 + srow) * 64 + gs * 8, &Ks[0][2048 + w * 512]);
  glds16(gvb + (size_t)srow * SEQ + gs * 8,       &Vs[0][w * 512]);
  glds16(gvb + (size_t)(32 + srow) * SEQ + gs * 8,&Vs[0][2048 + w * 512]);
  __syncthreads();
  bf16x8 aq0 = *(const bf16x8*)&Ps[(w * 16 + rl) * 72 + g * 8];
  bf16x8 aq1 = *(const bf16x8*)&Ps[(w * 16 + rl) * 72 + 32 + g * 8];
  float m[4], lsum[4];
  f32x4 oacc[4] = {};
#pragma unroll
  for (int r2 = 0; r2 < 4; ++r2) { m[r2] = -3.0e38f; lsum[r2] = 0.f; }
  int qloc = w * 16 + g * 4;
  int sw = rl & 7;
  int cur = 0;
  for (int kt = 0; kt <= ti; ++kt) {
    if (kt < ti) {
      int nx = cur ^ 1;
      glds16(gkb + (size_t)((kt + 1) * 64 + srow) * 64 + gs * 8,      &Ks[nx][w * 512]);
      glds16(gkb + (size_t)((kt + 1) * 64 + 32 + srow) * 64 + gs * 8, &Ks[nx][2048 + w * 512]);
      glds16(gvb + (size_t)srow * SEQ + (kt + 1) * 64 + gs * 8,       &Vs[nx][w * 512]);
      glds16(gvb + (size_t)(32 + srow) * SEQ + (kt + 1) * 64 + gs * 8,&Vs[nx][2048 + w * 512]);
    }
    f32x4 s[4] = {};
    __builtin_amdgcn_s_setprio(1);
#pragma unroll
    for (int nt = 0; nt < 4; ++nt) {
      int r = (nt * 16 + rl) * 64;
      bf16x8 b0 = *(const bf16x8*)&Ks[cur][r + ((0 + g) ^ sw) * 8];
      bf16x8 b1 = *(const bf16x8*)&Ks[cur][r + ((4 + g) ^ sw) * 8];
      s[nt] = __builtin_amdgcn_mfma_f32_16x16x32_bf16(aq0, b0, s[nt], 0, 0, 0);
      s[nt] = __builtin_amdgcn_mfma_f32_16x16x32_bf16(aq1, b1, s[nt], 0, 0, 0);
    }
    __builtin_amdgcn_s_setprio(0);
    if (kt == ti) {
#pragma unroll
      for (int nt = 0; nt < 4; ++nt) {
        int col = nt * 16 + rl;
#pragma unroll
        for (int r2 = 0; r2 < 4; ++r2)
          if (col > qloc + r2) s[nt][r2] = -3.0e38f;
      }
    }
#pragma unroll
    for (int r2 = 0; r2 < 4; ++r2) {
      float pm = fmaxf(fmaxf(s[0][r2], s[1][r2]), fmaxf(s[2][r2], s[3][r2]));
#pragma unroll
      for (int o = 1; o < 16; o <<= 1) pm = fmaxf(pm, __shfl_xor(pm, o));
      if (pm > m[r2] + 8.f) {   // defer-max: only rescale on large growth
        float corr = __expf(m[r2] - pm);
        m[r2] = pm;
        lsum[r2] *= corr;
        oacc[0][r2] *= corr; oacc[1][r2] *= corr;
        oacc[2][r2] *= corr; oacc[3][r2] *= corr;
      }
      float p0 = __expf(s[0][r2] - m[r2]);
      float p1 = __expf(s[1][r2] - m[r2]);
      float p2 = __expf(s[2][r2] - m[r2]);
      float p3 = __expf(s[3][r2] - m[r2]);
      float ps = p0 + p1 + p2 + p3;
#pragma unroll
      for (int o = 1; o < 16; o <<= 1) ps += __shfl_xor(ps, o);
      lsum[r2] += ps;
      int prow = (qloc + r2) * 72;
      Ps[prow + rl]      = f2bf(p0);
      Ps[prow + 16 + rl] = f2bf(p1);
      Ps[prow + 32 + rl] = f2bf(p2);
      Ps[prow + 48 + rl] = f2bf(p3);
    }
    bf16x8 pa0 = *(const bf16x8*)&Ps[(w * 16 + rl) * 72 + g * 8];
    bf16x8 pa1 = *(const bf16x8*)&Ps[(w * 16 + rl) * 72 + 32 + g * 8];
    __builtin_amdgcn_s_setprio(1);
#pragma unroll
    for (int nt = 0; nt < 4; ++nt) {
      int r = (nt * 16 + rl) * 64;
      bf16x8 b0 = *(const bf16x8*)&Vs[cur][r + ((0 + g) ^ sw) * 8];
      bf16x8 b1 = *(const bf16x8*)&Vs[cur][r + ((4 + g) ^ sw) * 8];
      oacc[nt] = __builtin_amdgcn_mfma_f32_16x16x32_bf16(pa0, b0, oacc[nt], 0, 0, 0);
      oacc[nt] = __builtin_amdgcn_mfma_f32_16x16x32_bf16(pa1, b1, oacc[nt], 0, 0, 0);
    }
    __builtin_amdgcn_s_setprio(0);
    __syncthreads();
    cur ^= 1;
  }
  int b = bh / NH, h = bh % NH;
  float invl[4];
#pragma unroll
  for (int r2 = 0; r2 < 4; ++r2) invl[r2] = 1.f / lsum[r2];
#pragma unroll
  for (int nt = 0; nt < 4; ++nt) {
    int d = nt * 16 + rl;
#pragma unroll
    for (int r2 = 0; r2 < 4; ++r2) {
      int trow = ti * 64 + qloc + r2;
      yb[((size_t)(b * SEQ + trow)) * DM + h * HD2 + d] = f2bf(oacc[nt][r2] * invl[r2]);
    }
  }
}

// ------- 128x128 GEMM, BK=32, dbuf single-sync loop — logits (f32 NT out) ---
template <int MODE>
__global__ void k_g128(const u16* __restrict__ A, const u16* __restrict__ Bt,
                       float* __restrict__ outf, int M, int N, int K, int MT) {
  __shared__ u16 SM[16384];  // [As0|Bs0|As1|Bs1] 4096 u16 each; alias cw[32][132]
  float* cw = (float*)SM;
  int nwg = gridDim.x;
  int id = blockIdx.x;
  if ((nwg & 7) == 0) id = (id & 7) * (nwg >> 3) + (id >> 3);  // XCD swizzle
  int mt = id % MT, nt = id / MT;
  int m0 = mt * 128, n0 = nt * 128;
  int tid = threadIdx.x;
  int w = tid >> 6, l = tid & 63;
  int srow = w * 16 + (l >> 2);
  int gs = (l & 3) ^ ((l >> 3) & 3);    // pre-swizzled source chunk
  const u16* gA0 = A + (size_t)(m0 + srow) * K + gs * 8;
  const u16* gA1 = A + (size_t)(m0 + 64 + srow) * K + gs * 8;
  int rb0 = n0 + srow;      if (rb0 > N - 1) rb0 = N - 1;
  int rb1 = n0 + 64 + srow; if (rb1 > N - 1) rb1 = N - 1;
  const u16* gB0 = Bt + (size_t)rb0 * K + gs * 8;
  const u16* gB1 = Bt + (size_t)rb1 * K + gs * 8;
  int wm = (w >> 1) * 64, wn = (w & 1) * 64;
  int rl = l & 15, g = l >> 4;
  int sla = g ^ ((rl >> 1) & 3);  // read-side swizzle (lane-constant)
  f32x4 acc[4][4] = {};
  int nK = K >> 5;
  int cur = 0;
  {  // prologue: stage kt=0 into buf0
    u16* dA = SM + w * 512;
    glds16(gA0, dA); glds16(gA1, dA + 2048);
    u16* dB = SM + 4096 + w * 512;
    glds16(gB0, dB); glds16(gB1, dB + 2048);
  }
  __syncthreads();
  for (int kt = 0; kt < nK; ++kt) {
    if (kt + 1 < nK) {  // issue next-tile stage before compute
      u16* dA = SM + (cur ^ 1) * 8192 + w * 512;
      glds16(gA0 + (kt + 1) * 32, dA); glds16(gA1 + (kt + 1) * 32, dA + 2048);
      u16* dB = dA + 4096;
      glds16(gB0 + (kt + 1) * 32, dB); glds16(gB1 + (kt + 1) * 32, dB + 2048);
    }
    const u16* As = SM + cur * 8192;
    const u16* Bs = As + 4096;
    bf16x8 af[4], bfr[4];
    __builtin_amdgcn_s_setprio(1);
#pragma unroll
    for (int i = 0; i < 4; ++i)
      af[i] = *(const bf16x8*)&As[(wm + i * 16 + rl) * 32 + sla * 8];
#pragma unroll
    for (int j = 0; j < 4; ++j)
      bfr[j] = *(const bf16x8*)&Bs[(wn + j * 16 + rl) * 32 + sla * 8];
#pragma unroll
    for (int i = 0; i < 4; ++i)
#pragma unroll
      for (int j = 0; j < 4; ++j)
        acc[i][j] = __builtin_amdgcn_mfma_f32_16x16x32_bf16(af[i], bfr[j],
                                                            acc[i][j], 0, 0, 0);
    __builtin_amdgcn_s_setprio(0);
    __syncthreads();
    cur ^= 1;
  }
  // epilogue: 32-row chunks through LDS, coalesced nontemporal f32 row writes
#pragma unroll
  for (int ch = 0; ch < 4; ++ch) {
    if ((w >> 1) == (ch >> 1)) {
      int ib = (ch & 1) * 2;
#pragma unroll
      for (int ii = 0; ii < 2; ++ii) {
#pragma unroll
        for (int j = 0; j < 4; ++j) {
          int col = wn + j * 16 + rl;
#pragma unroll
          for (int r2 = 0; r2 < 4; ++r2) {
            int rowc = ii * 16 + g * 4 + r2;
            cw[rowc * 132 + col] = acc[ib + ii][j][r2];
          }
        }
      }
    }
    __syncthreads();
    for (int t = tid; t < 4096; t += 256) {
      int rowc = t >> 7, col = t & 127;
      int gc = n0 + col;
      if (gc < N)
        __builtin_nontemporal_store(cw[rowc * 132 + col],
                                    &outf[(size_t)(m0 + ch * 32 + rowc) * N + gc]);
    }
    __syncthreads();
  }
}

// ------- 64x128 block-tile GEMM, BK=64, dbuf; wave = 32x64 (16 MFMA/iter) ---
// MODE 1: bf16 gelu out (+bias); MODE 4: fused qkv (rope q*1/8, k; v -> vT)
template <int MODE>
__global__ void k_gw(const u16* __restrict__ A, const u16* __restrict__ Bt,
                     const float* __restrict__ bias, u16* __restrict__ outb,
                     int M, int N, int K, int MT,
                     const float* __restrict__ ctab,
                     const float* __restrict__ stab, u16* __restrict__ qrp,
                     u16* __restrict__ krp, u16* __restrict__ vTp) {
  __shared__ u16 SM2[24576];  // A0|A1 (4096 u16 each) | B0|B1 (8192 u16 each)
  float* cw = (float*)SM2;    // [64][133] f32 epilogue staging
  int nwg = gridDim.x;
  int id = blockIdx.x;
  if ((nwg & 7) == 0) id = (id & 7) * (nwg >> 3) + (id >> 3);  // XCD swizzle
  int mt = id % MT, nt = id / MT;
  int m0 = mt * 64, n0 = nt * 128;
  int tid = threadIdx.x;
  int w = tid >> 6, l = tid & 63;
  int row0 = tid >> 3, slot0 = tid & 7;
  int gs0 = slot0 ^ (row0 & 7);
  const u16* gA0 = A + (size_t)(m0 + row0) * K + gs0 * 8;
  const u16* gA1 = gA0 + (size_t)32 * K;
  const u16* gB0 = Bt + (size_t)(n0 + row0) * K + gs0 * 8;
  const u16* gB1 = gB0 + (size_t)32 * K;
  const u16* gB2 = gB0 + (size_t)64 * K;
  const u16* gB3 = gB0 + (size_t)96 * K;
  int wm = (w >> 1) * 32, wn = (w & 1) * 64;
  int rl = l & 15, g = l >> 4;
  int sl0 = g ^ (rl & 7), sl1 = (4 + g) ^ (rl & 7);
  f32x4 acc[2][4] = {};
  int nK = K >> 6;
  int cur = 0;
  {  // prologue stage kt=0 -> buf0
    u16* dA = SM2;
    glds16(gA0, dA + w * 512); glds16(gA1, dA + 2048 + w * 512);
    u16* dB = SM2 + 8192;
    glds16(gB0, dB + w * 512);        glds16(gB1, dB + 2048 + w * 512);
    glds16(gB2, dB + 4096 + w * 512); glds16(gB3, dB + 6144 + w * 512);
  }
  __syncthreads();
  for (int kt = 0; kt < nK; ++kt) {
    if (kt + 1 < nK) {
      int ka = (kt + 1) * 64;
      u16* dA = SM2 + (cur ^ 1) * 4096;
      glds16(gA0 + ka, dA + w * 512); glds16(gA1 + ka, dA + 2048 + w * 512);
      u16* dB = SM2 + 8192 + (cur ^ 1) * 8192;
      glds16(gB0 + ka, dB + w * 512);        glds16(gB1 + ka, dB + 2048 + w * 512);
      glds16(gB2 + ka, dB + 4096 + w * 512); glds16(gB3 + ka, dB + 6144 + w * 512);
    }
    const u16* Ac = SM2 + cur * 4096;
    const u16* Bc = SM2 + 8192 + cur * 8192;
    bf16x8 a0[2], a1[2], b0[4], b1[4];
    __builtin_amdgcn_s_setprio(1);
#pragma unroll
    for (int i = 0; i < 2; ++i) {
      int r = (wm + i * 16 + rl) * 64;
      a0[i] = *(const bf16x8*)&Ac[r + sl0 * 8];
      a1[i] = *(const bf16x8*)&Ac[r + sl1 * 8];
    }
#pragma unroll
    for (int j = 0; j < 4; ++j) {
      int r = (wn + j * 16 + rl) * 64;
      b0[j] = *(const bf16x8*)&Bc[r + sl0 * 8];
      b1[j] = *(const bf16x8*)&Bc[r + sl1 * 8];
    }
#pragma unroll
    for (int i = 0; i < 2; ++i)
#pragma unroll
      for (int j = 0; j < 4; ++j) {
        acc[i][j] = __builtin_amdgcn_mfma_f32_16x16x32_bf16(a0[i], b0[j],
                                                            acc[i][j], 0, 0, 0);
        acc[i][j] = __builtin_amdgcn_mfma_f32_16x16x32_bf16(a1[i], b1[j],
                                                            acc[i][j], 0, 0, 0);
      }
    __builtin_amdgcn_s_setprio(0);
    __syncthreads();
    cur ^= 1;
  }
  // ---- epilogue: stage acc (+bias [,gelu]) to cw[64][133] ----
#pragma unroll
  for (int i = 0; i < 2; ++i) {
#pragma unroll
    for (int j = 0; j < 4; ++j) {
      int col = wn + j * 16 + rl;
      float bv = bias[n0 + col];
#pragma unroll
      for (int r2 = 0; r2 < 4; ++r2) {
        float v = acc[i][j][r2] + bv;
        if (MODE == 1) {
          float u = 0.7978845608028654f * (v + 0.044715f * v * v * v);
          v = 0.5f * v * (1.f + tanhf(u));
        }
        cw[(wm + i * 16 + g * 4 + r2) * 133 + col] = v;
      }
    }
  }
  __syncthreads();
  if (MODE == 1) {  // packed u32 bf16 row writes
    for (int t = tid; t < 4096; t += 256) {
      int rowc = t >> 6, cp = t & 63;
      u32 wv = (u32)f2bf(cw[rowc * 133 + 2 * cp]) |
               ((u32)f2bf(cw[rowc * 133 + 2 * cp + 1]) << 16);
      *(u32*)&outb[(size_t)(m0 + rowc) * N + n0 + 2 * cp] = wv;
    }
  } else {  // MODE 4: tile = 64 tokens x 2 heads (never straddles q/k/v)
    int reg = n0 / DM;
    int h0 = (n0 % DM) / 64;
    int bb = m0 >> 10;
    int t0 = m0 & (SEQ - 1);
    size_t bhb = (size_t)bb * NH + h0;
    if (reg < 2) {
      u16* dst = (reg == 0) ? qrp : krp;
      float qs = (reg == 0) ? 0.125f : 1.f;  // fold 1/sqrt(HD) into q (exact)
      for (int t = tid; t < 4096; t += 256) {
        int rowc = t >> 6, cp = t & 63;
        int c = 2 * cp;
        int hh = c >> 6, d = c & 63;
        int tt = t0 + rowc;
        float x0 = cw[rowc * 133 + c];
        float x1 = cw[rowc * 133 + c + 1];
        float o0, o1;
        if (d < 32) {
          float y0 = cw[rowc * 133 + c + 32];
          float y1 = cw[rowc * 133 + c + 33];
          float c0 = 1.f, s0 = 0.f, c1 = 1.f, s1 = 0.f;
          if (d < 16) {
            c0 = ctab[tt * 16 + d];     s0 = stab[tt * 16 + d];
            c1 = ctab[tt * 16 + d + 1]; s1 = stab[tt * 16 + d + 1];
          }
          o0 = x0 * c0 - y0 * s0;
          o1 = x1 * c1 - y1 * s1;
        } else {
          int j = d - 32;
          float y0 = cw[rowc * 133 + c - 32];
          float y1 = cw[rowc * 133 + c - 31];
          float c0 = 1.f, s0 = 0.f, c1 = 1.f, s1 = 0.f;
          if (j < 16) {
            c0 = ctab[tt * 16 + j];     s0 = stab[tt * 16 + j];
            c1 = ctab[tt * 16 + j + 1]; s1 = stab[tt * 16 + j + 1];
          }
          o0 = x0 * c0 + y0 * s0;
          o1 = x1 * c1 + y1 * s1;
        }
        u32 wv = (u32)f2bf(o0 * qs) | ((u32)f2bf(o1 * qs) << 16);
        *(u32*)&dst[((bhb + hh) * SEQ + tt) * HD2 + d] = wv;
      }
    } else {  // v transposed write vT[bh][d][t], 2 tokens per u32
      for (int t = tid; t < 4096; t += 256) {
        int dcol = t >> 5, p = t & 31;
        int hh = dcol >> 6, d = dcol & 63;
        int tt = t0 + 2 * p;
        u32 wv = (u32)f2bf(cw[(2 * p) * 133 + dcol]) |
                 ((u32)f2bf(cw[(2 * p + 1) * 133 + dcol]) << 16);
        *(u32*)&vTp[((bhb + hh) * HD2 + d) * SEQ + tt] = wv;
      }
    }
  }
}

// ------- 64x64-tile GEMM, BK=64, dbuf, split-K residual add (wo / wp) -------
__global__ void k_g64r(const u16* __restrict__ A, const u16* __restrict__ Bt,
                       const float* __restrict__ bias,
                       float* __restrict__ outf, int M, int N, int K, int MT) {
  __shared__ u16 As[8192];  // 2 x [64][64]
  __shared__ u16 Bs[8192];
  int nwg = gridDim.x;
  int id = blockIdx.x;
  if ((nwg & 7) == 0) id = (id & 7) * (nwg >> 3) + (id >> 3);  // XCD swizzle
  int mt = id % MT, nt = id / MT;
  int sk = blockIdx.y, nsk = gridDim.y;
  int Kc = K / nsk, k0 = sk * Kc;
  int m0 = mt * 64, n0 = nt * 64;
  int tid = threadIdx.x;
  int w = tid >> 6, l = tid & 63;
  int row0 = tid >> 3, slot0 = tid & 7;
  int gs0 = slot0 ^ (row0 & 7);
  const u16* gA0 = A + (size_t)(m0 + row0) * K + k0 + gs0 * 8;
  const u16* gA1 = gA0 + (size_t)32 * K;
  const u16* gB0 = Bt + (size_t)(n0 + row0) * K + k0 + gs0 * 8;
  const u16* gB1 = gB0 + (size_t)32 * K;
  int wm = (w >> 1) * 32, wn = (w & 1) * 32;
  int rl = l & 15, g = l >> 4;
  int sl0 = g ^ (rl & 7), sl1 = (4 + g) ^ (rl & 7);
  f32x4 acc[2][2] = {};
  int nK = Kc >> 6;
  int cur = 0;
  {  // prologue stage kt=0 -> buf0
    glds16(gA0, As + w * 512); glds16(gA1, As + 2048 + w * 512);
    glds16(gB0, Bs + w * 512); glds16(gB1, Bs + 2048 + w * 512);
  }
  __syncthreads();
  for (int kt = 0; kt < nK; ++kt) {
    if (kt + 1 < nK) {
      int nx = (cur ^ 1) * 4096;
      glds16(gA0 + (kt + 1) * 64, As + nx + w * 512);
      glds16(gA1 + (kt + 1) * 64, As + nx + 2048 + w * 512);
      glds16(gB0 + (kt + 1) * 64, Bs + nx + w * 512);
      glds16(gB1 + (kt + 1) * 64, Bs + nx + 2048 + w * 512);
    }
    const u16* Ac = As + cur * 4096;
    const u16* Bc = Bs + cur * 4096;
    bf16x8 a0[2], a1[2], b0[2], b1[2];
    __builtin_amdgcn_s_setprio(1);
#pragma unroll
    for (int i = 0; i < 2; ++i) {
      int r = (wm + i * 16 + rl) * 64;
      a0[i] = *(const bf16x8*)&Ac[r + sl0 * 8];
      a1[i] = *(const bf16x8*)&Ac[r + sl1 * 8];
    }
#pragma unroll
    for (int j = 0; j < 2; ++j) {
      int r = (wn + j * 16 + rl) * 64;
      b0[j] = *(const bf16x8*)&Bc[r + sl0 * 8];
      b1[j] = *(const bf16x8*)&Bc[r + sl1 * 8];
    }
#pragma unroll
    for (int i = 0; i < 2; ++i)
#pragma unroll
      for (int j = 0; j < 2; ++j) {
        acc[i][j] = __builtin_amdgcn_mfma_f32_16x16x32_bf16(a0[i], b0[j],
                                                            acc[i][j], 0, 0, 0);
        acc[i][j] = __builtin_amdgcn_mfma_f32_16x16x32_bf16(a1[i], b1[j],
                                                            acc[i][j], 0, 0, 0);
      }
    __builtin_amdgcn_s_setprio(0);
    __syncthreads();
    cur ^= 1;
  }
#pragma unroll
  for (int i = 0; i < 2; ++i) {
#pragma unroll
    for (int j = 0; j < 2; ++j) {
      int col = n0 + wn + j * 16 + rl;
      float bv = bias ? bias[col] : 0.f;
#pragma unroll
      for (int r2 = 0; r2 < 4; ++r2) {
        int row = m0 + wm + i * 16 + g * 4 + r2;
        float v = acc[i][j][r2];
        if (sk == 0) v += bv;
        atomicAdd(&outf[(size_t)row * N + col], v);
      }
    }
  }
}

// ---------------- fallback GEMM (f32 B, on-the-fly cvt) — logits only --------
__global__ void k_gemm_f32b(const u16* __restrict__ A, const float* __restrict__ B,
                            float* __restrict__ outf, int M, int N, int K) {
  __shared__ u16 As[128 * 40];
  __shared__ u16 Bs[4 * 128 * 12];
  int tid = threadIdx.x;
  int wid = tid >> 6, lane = tid & 63;
  int rl = lane & 15, g = lane >> 4;
  int m0 = blockIdx.x * 128, n0 = blockIdx.y * 128;
  int wm = (wid >> 1) * 64, wn = (wid & 1) * 64;
  int ar = tid >> 2, ac = tid & 3;
  int bn = tid & 127, bq = tid >> 7;
  f32x4 acc[4][4] = {};
  int nK = K / 32;
  for (int kt = 0; kt < nK; ++kt) {
    __syncthreads();
    {
      const u16* ga = A + (size_t)(m0 + ar) * K + kt * 32 + ac * 8;
      *(uint4*)&As[ar * 40 + ac * 8] = *(const uint4*)ga;
      *(uint4*)&As[(ar + 64) * 40 + ac * 8] = *(const uint4*)(ga + (size_t)64 * K);
    }
    int col = n0 + bn;
#pragma unroll
    for (int r = 0; r < 4; ++r) {
      int kq = bq + 2 * r;
      int kk = kt * 32 + kq * 4;
      float f0 = 0.f, f1 = 0.f, f2v = 0.f, f3 = 0.f;
      if (col < N) {
        const float* gb = B + (size_t)kk * N + col;
        f0 = gb[0]; f1 = gb[(size_t)N]; f2v = gb[(size_t)2 * N]; f3 = gb[(size_t)3 * N];
      }
      uint2 wv;
      wv.x = (u32)f2bf(f0) | ((u32)f2bf(f1) << 16);
      wv.y = (u32)f2bf(f2v) | ((u32)f2bf(f3) << 16);
      *(uint2*)&Bs[(kq >> 1) * 1536 + bn * 12 + (kq & 1) * 4] = wv;
    }
    __syncthreads();
    bf16x8 af[4], bfr[4];
#pragma unroll
    for (int mt = 0; mt < 4; ++mt)
      af[mt] = *(const bf16x8*)&As[(wm + mt * 16 + rl) * 40 + g * 8];
#pragma unroll
    for (int nt = 0; nt < 4; ++nt) {
      const u16* p = &Bs[g * 1536 + (wn + nt * 16 + rl) * 12];
      union { bf16x8 v; uint2 u2[2]; } tmp;
      tmp.u2[0] = *(const uint2*)p;
      tmp.u2[1] = *(const uint2*)(p + 4);
      bfr[nt] = tmp.v;
    }
#pragma unroll
    for (int mt = 0; mt < 4; ++mt)
#pragma unroll
      for (int nt = 0; nt < 4; ++nt)
        acc[mt][nt] = __builtin_amdgcn_mfma_f32_16x16x32_bf16(af[mt], bfr[nt],
                                                              acc[mt][nt], 0, 0, 0);
  }
#pragma unroll
  for (int mt = 0; mt < 4; ++mt)
#pragma unroll
    for (int nt = 0; nt < 4; ++nt) {
      int col = n0 + wn + nt * 16 + rl;
      if (col >= N) continue;
#pragma unroll
      for (int r2 = 0; r2 < 4; ++r2) {
        int row = m0 + wm + mt * 16 + g * 4 + r2;
        outf[(size_t)row * N + col] = acc[mt][nt][r2];
      }
    }
}

extern "C" void kernel_launch(void* const* d_in, const int* in_sizes, int n_in,
                              void* d_out, int out_size, void* d_ws, size_t ws_size,
                              hipStream_t stream) {
  (void)in_sizes; (void)n_in; (void)out_size;
  const int*   idx  = (const int*)  d_in[0];
  const float* wte  = (const float*)d_in[1];
  const float* ln1g = (const float*)d_in[2];
  const float* ln1b = (const float*)d_in[3];
  const float* Wqkv = (const float*)d_in[4];
  const float* bqkv = (const float*)d_in[5];
  const float* Wo   = (const float*)d_in[6];
  const float* bo   = (const float*)d_in[7];
  const float* ln2g = (const float*)d_in[8];
  const float* ln2b = (const float*)d_in[9];
  const float* Wfc  = (const float*)d_in[10];
  const float* bfc  = (const float*)d_in[11];
  const float* Wp   = (const float*)d_in[12];
  const float* bp   = (const float*)d_in[13];
  const float* lnfg = (const float*)d_in[14];
  const float* lnfb = (const float*)d_in[15];
  const float* Wlm  = (const float*)d_in[16];
  float* out = (float*)d_out;

  // Scratch packed into d_out (all dead before the logits GEMM rewrites d_out).
  char* sb = (char*)d_out;
  size_t off = 0;
  auto alloc = [&](size_t bytes) {
    char* p = sb + off;
    off += (bytes + 255) & ~(size_t)255;
    return (void*)p;
  };
  float* xf  = (float*)alloc((size_t)BT * DM * 4);
  u16* h1b   = (u16*)alloc((size_t)BT * DM * 2);
  u16* h2b   = (u16*)alloc((size_t)BT * DM * 2);
  u16* qr    = (u16*)alloc((size_t)BT * DM * 2);
  u16* kr    = (u16*)alloc((size_t)BT * DM * 2);
  u16* vT    = (u16*)alloc((size_t)BT * DM * 2);
  u16* yb    = (u16*)alloc((size_t)BT * DM * 2);
  u16* hgel  = (u16*)alloc((size_t)BT * 4 * DM * 2);
  float* ctab = (float*)alloc((size_t)SEQ * 16 * 4);
  float* stab = (float*)alloc((size_t)SEQ * 16 * 4);
  // transposed bf16 weights (also dead before logits GEMM)
  u16* wqkvT = (u16*)alloc((size_t)NLAYER * 3 * DM * DM * 2);
  u16* woT   = (u16*)alloc((size_t)NLAYER * DM * DM * 2);
  u16* wfcT  = (u16*)alloc((size_t)NLAYER * 4 * DM * DM * 2);
  u16* wpT   = (u16*)alloc((size_t)NLAYER * 4 * DM * DM * 2);

  // Wlm^T (77 MB) must survive the logits GEMM -> d_ws if it fits.
  size_t wlmT_bytes = (size_t)NVOCAB * DM * 2;
  size_t xlnf_bytes = (size_t)BT * DM * 2;
  bool fast_lm = ws_size >= wlmT_bytes + xlnf_bytes + 512;
  u16* wlmT = (u16*)d_ws;
  u16* xlnf = fast_lm ? (u16*)((char*)d_ws + ((wlmT_bytes + 255) & ~(size_t)255))
                      : (u16*)d_ws;

  // ---- single mega-prologue dispatch: embed + trig + all weight conversion -
  int prep_blocks = BT + 64 + NLAYER * 1728 + (fast_lm ? 9432 : 0);
  k_prep<<<prep_blocks, 256, 0, stream>>>(idx, wte, xf, ctab, stab,
                                          Wqkv, Wo, Wfc, Wp, Wlm,
                                          wqkvT, woT, wfcT, wpT, wlmT);

  for (int l = 0; l < NLAYER; ++l) {
    k_ln<<<BT / 4, 256, 0, stream>>>(xf, ln1g + l * DM, ln1b + l * DM,
                                     ln2g + l * DM, ln2b + l * DM, h1b, h2b);
    // fused qkv GEMM + bias + rope (+q/8) + v-transpose (64x128 tile, 576 blk)
    k_gw<4><<<(BT / 64) * (3 * DM / 128), 256, 0, stream>>>(
        h1b, wqkvT + (size_t)l * 3 * DM * DM, bqkv + (size_t)l * 3 * DM,
        nullptr, BT, 3 * DM, DM, BT / 64, ctab, stab, qr, kr, vT);
    k_attn<<<dim3(SEQ / 64, 2 * NH), 256, 0, stream>>>(qr, kr, vT, yb);
    k_g64r<<<dim3((BT / 64) * (DM / 64), 2), 256, 0, stream>>>(
        yb, woT + (size_t)l * DM * DM, bo + (size_t)l * DM, xf, BT, DM, DM, BT / 64);
    // fc GEMM + bias + gelu (64x128 tile, 768 blocks)
    k_gw<1><<<(BT / 64) * (4 * DM / 128), 256, 0, stream>>>(
        h2b, wfcT + (size_t)l * 4 * DM * DM, bfc + (size_t)l * 4 * DM,
        hgel, BT, 4 * DM, DM, BT / 64, nullptr, nullptr, nullptr, nullptr, nullptr);
    k_g64r<<<dim3((BT / 64) * (DM / 64), 4), 256, 0, stream>>>(
        hgel, wpT + (size_t)l * 4 * DM * DM, bp + (size_t)l * DM, xf, BT, DM, 4 * DM,
        BT / 64);
  }
  k_ln<<<BT / 4, 256, 0, stream>>>(xf, lnfg, lnfb, nullptr, nullptr, xlnf, nullptr);
  if (fast_lm) {
    int nt = (NVOCAB + 127) / 128;
    k_g128<3><<<(BT / 128) * nt, 256, 0, stream>>>(
        xlnf, wlmT, out, BT, NVOCAB, DM, BT / 128);
  } else {
    k_gemm_f32b<<<dim3(BT / 128, (NVOCAB + 127) / 128), 256, 0, stream>>>(
        xlnf, Wlm, out, BT, NVOCAB, DM);
  }
}

// Round 14
// 876.460 us; speedup vs baseline: 6.2462x; 1.0246x over previous
//
#include <hip/hip_runtime.h>

typedef unsigned short u16;
typedef unsigned int u32;
typedef __attribute__((ext_vector_type(8))) short bf16x8;
typedef __attribute__((ext_vector_type(4))) float f32x4;

#define SEQ 1024
#define DM 768
#define NH 12
#define HD2 64
#define NLAYER 4
#define NVOCAB 50257
#define BT 2048  // B*T

__device__ __forceinline__ u16 f2bf(float f) {
  union { float f; u32 u; } v; v.f = f;
  u32 r = v.u + 0x7FFFu + ((v.u >> 16) & 1u);
  return (u16)(r >> 16);
}
__device__ __forceinline__ float bf2f(u16 u) {
  union { u32 u; float f; } v; v.u = ((u32)u) << 16;
  return v.f;
}

__device__ __forceinline__ void glds16(const u16* g, u16* l) {
  __builtin_amdgcn_global_load_lds(
      (const __attribute__((address_space(1))) u32*)(const void*)g,
      (__attribute__((address_space(3))) u32*)(void*)l, 16, 0, 0);
}

// ---- transpose+cvt one 64x64 tile: in[R,C] f32 -> out[C,R] bf16 ------------
__device__ __forceinline__ void cvt_tile(const float* __restrict__ in,
                                         u16* __restrict__ out, int R, int C,
                                         int cx, int ry, u16 (*t)[68]) {
  int c0 = cx * 64, r0 = ry * 64;  // R always multiple of 64
  int tx = threadIdx.x & 15, ty = threadIdx.x >> 4;
  int c = c0 + tx * 4;
#pragma unroll
  for (int i = 0; i < 4; ++i) {
    int r = r0 + ty + i * 16;
    float4 v = make_float4(0.f, 0.f, 0.f, 0.f);
    if (c + 3 < C) {
      v = *(const float4*)&in[(size_t)r * C + c];
    } else {
      if (c + 0 < C) v.x = in[(size_t)r * C + c];
      if (c + 1 < C) v.y = in[(size_t)r * C + c + 1];
      if (c + 2 < C) v.z = in[(size_t)r * C + c + 2];
      if (c + 3 < C) v.w = in[(size_t)r * C + c + 3];
    }
    t[ty + i * 16][tx * 4 + 0] = f2bf(v.x);
    t[ty + i * 16][tx * 4 + 1] = f2bf(v.y);
    t[ty + i * 16][tx * 4 + 2] = f2bf(v.z);
    t[ty + i * 16][tx * 4 + 3] = f2bf(v.w);
  }
  __syncthreads();
  int wl = threadIdx.x & 31, grp = threadIdx.x >> 5;
#pragma unroll
  for (int it = 0; it < 8; ++it) {
    int cc = it * 8 + grp;
    int gcol = c0 + cc;
    if (gcol < C) {
      u32 wv = (u32)t[2 * wl][cc] | ((u32)t[2 * wl + 1][cc] << 16);
      *(u32*)&out[(size_t)gcol * R + r0 + 2 * wl] = wv;
    }
  }
}

// ---- mega prologue: embed | rope trig | all weight cvt+transpose -----------
__global__ void k_prep(const int* __restrict__ idx, const float* __restrict__ wte,
                       float* __restrict__ xf, float* __restrict__ ctab,
                       float* __restrict__ stab, const float* __restrict__ Wqkv,
                       const float* __restrict__ Wo, const float* __restrict__ Wfc,
                       const float* __restrict__ Wp, const float* __restrict__ Wlm,
                       u16* __restrict__ wqkvT, u16* __restrict__ woT,
                       u16* __restrict__ wfcT, u16* __restrict__ wpT,
                       u16* __restrict__ wlmT) {
  __shared__ u16 t[64][68];
  int bid = blockIdx.x;
  if (bid < BT) {  // embedding
    int tok = idx[bid];
    const float* s = wte + (size_t)tok * DM;
    float* d = xf + (size_t)bid * DM;
    for (int c = threadIdx.x; c < DM; c += 256) d[c] = s[c];
    return;
  }
  bid -= BT;
  if (bid < 64) {  // trig tables [SEQ][16]
    int gid = bid * 256 + threadIdx.x;
    int tt = gid >> 4, j = gid & 15;
    float inv = powf(10000.f, -(float)j * (1.f / 32.f));
    float ang = (float)tt * inv;
    ctab[gid] = cosf(ang);
    stab[gid] = sinf(ang);
    return;
  }
  bid -= 64;
  if (bid < NLAYER * 1728) {
    int layer = bid / 1728, r = bid % 1728;
    if (r < 432) {
      cvt_tile(Wqkv + (size_t)layer * DM * 3 * DM,
               wqkvT + (size_t)layer * 3 * DM * DM, DM, 3 * DM, r % 36, r / 36, t);
      return;
    }
    r -= 432;
    if (r < 144) {
      cvt_tile(Wo + (size_t)layer * DM * DM, woT + (size_t)layer * DM * DM,
               DM, DM, r % 12, r / 12, t);
      return;
    }
    r -= 144;
    if (r < 576) {
      cvt_tile(Wfc + (size_t)layer * DM * 4 * DM,
               wfcT + (size_t)layer * 4 * DM * DM, DM, 4 * DM, r % 48, r / 48, t);
      return;
    }
    r -= 576;
    cvt_tile(Wp + (size_t)layer * 4 * DM * DM, wpT + (size_t)layer * 4 * DM * DM,
             4 * DM, DM, r % 12, r / 12, t);
    return;
  }
  bid -= NLAYER * 1728;  // Wlm [DM, NVOCAB]: 786 x, 12 y
  cvt_tile(Wlm, wlmT, DM, NVOCAB, bid % 786, bid / 786, t);
}

// ---------------- layernorm: wave-per-row, shuffle-only reductions ----------
__global__ void k_ln(const float* __restrict__ x, const float* __restrict__ g1,
                     const float* __restrict__ b1, const float* __restrict__ g2,
                     const float* __restrict__ b2, u16* __restrict__ o1,
                     u16* __restrict__ o2) {
  int w = threadIdx.x >> 6, l = threadIdx.x & 63;
  int r = blockIdx.x * 4 + w;
  const float* xr = x + (size_t)r * DM;
  float2 v[6];
  float s = 0.f;
#pragma unroll
  for (int i = 0; i < 6; ++i) {
    v[i] = *(const float2*)&xr[2 * l + i * 128];
    s += v[i].x + v[i].y;
  }
#pragma unroll
  for (int o = 1; o < 64; o <<= 1) s += __shfl_xor(s, o);
  float mean = s * (1.f / DM);
  float vs = 0.f;
#pragma unroll
  for (int i = 0; i < 6; ++i) {
    float dx = v[i].x - mean, dy = v[i].y - mean;
    vs += dx * dx + dy * dy;
  }
#pragma unroll
  for (int o = 1; o < 64; o <<= 1) vs += __shfl_xor(vs, o);
  float rstd = rsqrtf(vs * (1.f / DM) + 1e-5f);
  u16* p1 = o1 + (size_t)r * DM;
#pragma unroll
  for (int i = 0; i < 6; ++i) {
    int c = 2 * l + i * 128;
    float2 gg = *(const float2*)&g1[c];
    float2 bb = *(const float2*)&b1[c];
    u32 wv = (u32)f2bf((v[i].x - mean) * rstd * gg.x + bb.x) |
             ((u32)f2bf((v[i].y - mean) * rstd * gg.y + bb.y) << 16);
    *(u32*)&p1[c] = wv;
  }
  if (o2) {
    u16* p2 = o2 + (size_t)r * DM;
#pragma unroll
    for (int i = 0; i < 6; ++i) {
      int c = 2 * l + i * 128;
      float2 gg = *(const float2*)&g2[c];
      float2 bb = *(const float2*)&b2[c];
      u32 wv = (u32)f2bf((v[i].x - mean) * rstd * gg.x + bb.x) |
               ((u32)f2bf((v[i].y - mean) * rstd * gg.y + bb.y) << 16);
      *(u32*)&p2[c] = wv;
    }
  }
}

// ---------------- fused flash attention, glds-staged double-buffered K/V ----
// q pre-scaled by 1/8; ballot defer-max (common path: no cross-lane max).
__global__ void k_attn(const u16* __restrict__ qr, const u16* __restrict__ kr,
                       const u16* __restrict__ vT, u16* __restrict__ yb) {
  int ti = (int)gridDim.x - 1 - (int)blockIdx.x;  // big tiles first
  int bh = blockIdx.y;
  __shared__ u16 Ps[64 * 72];       // Q staging, then P tile (wave-private rows)
  __shared__ u16 Ks[2][4096];       // [64][64] XOR-swizzled
  __shared__ u16 Vs[2][4096];
  int tid = threadIdx.x;
  int rr = tid >> 2, cc = tid & 3;
  int w = tid >> 6, l = tid & 63;
  int rl = l & 15, g = l >> 4;
  {
    const u16* gq = qr + ((size_t)bh * SEQ + ti * 64 + rr) * HD2;
    *(uint4*)&Ps[rr * 72 + cc * 8]      = *(const uint4*)(gq + cc * 8);
    *(uint4*)&Ps[rr * 72 + cc * 8 + 32] = *(const uint4*)(gq + cc * 8 + 32);
  }
  int srow = w * 8 + (l >> 3);
  int gs = (l & 7) ^ (l >> 3);
  const u16* gkb = kr + (size_t)bh * SEQ * HD2;
  const u16* gvb = vT + (size_t)bh * HD2 * SEQ;
  glds16(gkb + (size_t)srow * 64 + gs * 8,        &Ks[0][w * 512]);
  glds16(gkb + (size_t)(32 + srow) * 64 + gs * 8, &Ks[0][2048 + w * 512]);
  glds16(gvb + (size_t)srow * SEQ + gs * 8,       &Vs[0][w * 512]);
  glds16(gvb + (size_t)(32 + srow) * SEQ + gs * 8,&Vs[0][2048 + w * 512]);
  __syncthreads();
  bf16x8 aq0 = *(const bf16x8*)&Ps[(w * 16 + rl) * 72 + g * 8];
  bf16x8 aq1 = *(const bf16x8*)&Ps[(w * 16 + rl) * 72 + 32 + g * 8];
  float m[4], lsum[4];
  f32x4 oacc[4] = {};
#pragma unroll
  for (int r2 = 0; r2 < 4; ++r2) { m[r2] = -3.0e38f; lsum[r2] = 0.f; }
  int qloc = w * 16 + g * 4;
  int sw = rl & 7;
  int cur = 0;
  for (int kt = 0; kt <= ti; ++kt) {
    if (kt < ti) {
      int nx = cur ^ 1;
      glds16(gkb + (size_t)((kt + 1) * 64 + srow) * 64 + gs * 8,      &Ks[nx][w * 512]);
      glds16(gkb + (size_t)((kt + 1) * 64 + 32 + srow) * 64 + gs * 8, &Ks[nx][2048 + w * 512]);
      glds16(gvb + (size_t)srow * SEQ + (kt + 1) * 64 + gs * 8,       &Vs[nx][w * 512]);
      glds16(gvb + (size_t)(32 + srow) * SEQ + (kt + 1) * 64 + gs * 8,&Vs[nx][2048 + w * 512]);
    }
    f32x4 s[4] = {};
    __builtin_amdgcn_s_setprio(1);
#pragma unroll
    for (int nt = 0; nt < 4; ++nt) {
      int r = (nt * 16 + rl) * 64;
      bf16x8 b0 = *(const bf16x8*)&Ks[cur][r + ((0 + g) ^ sw) * 8];
      bf16x8 b1 = *(const bf16x8*)&Ks[cur][r + ((4 + g) ^ sw) * 8];
      s[nt] = __builtin_amdgcn_mfma_f32_16x16x32_bf16(aq0, b0, s[nt], 0, 0, 0);
      s[nt] = __builtin_amdgcn_mfma_f32_16x16x32_bf16(aq1, b1, s[nt], 0, 0, 0);
    }
    __builtin_amdgcn_s_setprio(0);
    if (kt == ti) {
#pragma unroll
      for (int nt = 0; nt < 4; ++nt) {
        int col = nt * 16 + rl;
#pragma unroll
        for (int r2 = 0; r2 < 4; ++r2)
          if (col > qloc + r2) s[nt][r2] = -3.0e38f;
      }
    }
    // ---- ballot defer-max: cheap local check, rare slow path ----
    float lmax[4];
#pragma unroll
    for (int r2 = 0; r2 < 4; ++r2)
      lmax[r2] = fmaxf(fmaxf(s[0][r2], s[1][r2]), fmaxf(s[2][r2], s[3][r2]));
    bool need = (lmax[0] > m[0] + 8.f) || (lmax[1] > m[1] + 8.f) ||
                (lmax[2] > m[2] + 8.f) || (lmax[3] > m[3] + 8.f);
    if (__any(need)) {
#pragma unroll
      for (int r2 = 0; r2 < 4; ++r2) {
        float pm = lmax[r2];
#pragma unroll
        for (int o = 1; o < 16; o <<= 1) pm = fmaxf(pm, __shfl_xor(pm, o));
        if (pm > m[r2] + 8.f) {
          float corr = __expf(m[r2] - pm);
          m[r2] = pm;
          lsum[r2] *= corr;
          oacc[0][r2] *= corr; oacc[1][r2] *= corr;
          oacc[2][r2] *= corr; oacc[3][r2] *= corr;
        }
      }
    }
#pragma unroll
    for (int r2 = 0; r2 < 4; ++r2) {
      float p0 = __expf(s[0][r2] - m[r2]);
      float p1 = __expf(s[1][r2] - m[r2]);
      float p2 = __expf(s[2][r2] - m[r2]);
      float p3 = __expf(s[3][r2] - m[r2]);
      float ps = p0 + p1 + p2 + p3;
#pragma unroll
      for (int o = 1; o < 16; o <<= 1) ps += __shfl_xor(ps, o);
      lsum[r2] += ps;
      int prow = (qloc + r2) * 72;
      Ps[prow + rl]      = f2bf(p0);
      Ps[prow + 16 + rl] = f2bf(p1);
      Ps[prow + 32 + rl] = f2bf(p2);
      Ps[prow + 48 + rl] = f2bf(p3);
    }
    bf16x8 pa0 = *(const bf16x8*)&Ps[(w * 16 + rl) * 72 + g * 8];
    bf16x8 pa1 = *(const bf16x8*)&Ps[(w * 16 + rl) * 72 + 32 + g * 8];
    __builtin_amdgcn_s_setprio(1);
#pragma unroll
    for (int nt = 0; nt < 4; ++nt) {
      int r = (nt * 16 + rl) * 64;
      bf16x8 b0 = *(const bf16x8*)&Vs[cur][r + ((0 + g) ^ sw) * 8];
      bf16x8 b1 = *(const bf16x8*)&Vs[cur][r + ((4 + g) ^ sw) * 8];
      oacc[nt] = __builtin_amdgcn_mfma_f32_16x16x32_bf16(pa0, b0, oacc[nt], 0, 0, 0);
      oacc[nt] = __builtin_amdgcn_mfma_f32_16x16x32_bf16(pa1, b1, oacc[nt], 0, 0, 0);
    }
    __builtin_amdgcn_s_setprio(0);
    __syncthreads();
    cur ^= 1;
  }
  int b = bh / NH, h = bh % NH;
  float invl[4];
#pragma unroll
  for (int r2 = 0; r2 < 4; ++r2) invl[r2] = 1.f / lsum[r2];
#pragma unroll
  for (int nt = 0; nt < 4; ++nt) {
    int d = nt * 16 + rl;
#pragma unroll
    for (int r2 = 0; r2 < 4; ++r2) {
      int trow = ti * 64 + qloc + r2;
      yb[((size_t)(b * SEQ + trow)) * DM + h * HD2 + d] = f2bf(oacc[nt][r2] * invl[r2]);
    }
  }
}

// ------- 128x128 GEMM, BK=32, dbuf single-sync loop — logits (f32 NT out) ---
template <int MODE>
__global__ void k_g128(const u16* __restrict__ A, const u16* __restrict__ Bt,
                       float* __restrict__ outf, int M, int N, int K, int MT) {
  __shared__ u16 SM[16384];
  float* cw = (float*)SM;
  int nwg = gridDim.x;
  int id = blockIdx.x;
  if ((nwg & 7) == 0) id = (id & 7) * (nwg >> 3) + (id >> 3);  // XCD swizzle
  int mt = id % MT, nt = id / MT;
  int m0 = mt * 128, n0 = nt * 128;
  int tid = threadIdx.x;
  int w = tid >> 6, l = tid & 63;
  int srow = w * 16 + (l >> 2);
  int gs = (l & 3) ^ ((l >> 3) & 3);
  const u16* gA0 = A + (size_t)(m0 + srow) * K + gs * 8;
  const u16* gA1 = A + (size_t)(m0 + 64 + srow) * K + gs * 8;
  int rb0 = n0 + srow;      if (rb0 > N - 1) rb0 = N - 1;
  int rb1 = n0 + 64 + srow; if (rb1 > N - 1) rb1 = N - 1;
  const u16* gB0 = Bt + (size_t)rb0 * K + gs * 8;
  const u16* gB1 = Bt + (size_t)rb1 * K + gs * 8;
  int wm = (w >> 1) * 64, wn = (w & 1) * 64;
  int rl = l & 15, g = l >> 4;
  int sla = g ^ ((rl >> 1) & 3);
  f32x4 acc[4][4] = {};
  int nK = K >> 5;
  int cur = 0;
  {
    u16* dA = SM + w * 512;
    glds16(gA0, dA); glds16(gA1, dA + 2048);
    u16* dB = SM + 4096 + w * 512;
    glds16(gB0, dB); glds16(gB1, dB + 2048);
  }
  __syncthreads();
  for (int kt = 0; kt < nK; ++kt) {
    if (kt + 1 < nK) {
      u16* dA = SM + (cur ^ 1) * 8192 + w * 512;
      glds16(gA0 + (kt + 1) * 32, dA); glds16(gA1 + (kt + 1) * 32, dA + 2048);
      u16* dB = dA + 4096;
      glds16(gB0 + (kt + 1) * 32, dB); glds16(gB1 + (kt + 1) * 32, dB + 2048);
    }
    const u16* As = SM + cur * 8192;
    const u16* Bs = As + 4096;
    bf16x8 af[4], bfr[4];
    __builtin_amdgcn_s_setprio(1);
#pragma unroll
    for (int i = 0; i < 4; ++i)
      af[i] = *(const bf16x8*)&As[(wm + i * 16 + rl) * 32 + sla * 8];
#pragma unroll
    for (int j = 0; j < 4; ++j)
      bfr[j] = *(const bf16x8*)&Bs[(wn + j * 16 + rl) * 32 + sla * 8];
#pragma unroll
    for (int i = 0; i < 4; ++i)
#pragma unroll
      for (int j = 0; j < 4; ++j)
        acc[i][j] = __builtin_amdgcn_mfma_f32_16x16x32_bf16(af[i], bfr[j],
                                                            acc[i][j], 0, 0, 0);
    __builtin_amdgcn_s_setprio(0);
    __syncthreads();
    cur ^= 1;
  }
#pragma unroll
  for (int ch = 0; ch < 4; ++ch) {
    if ((w >> 1) == (ch >> 1)) {
      int ib = (ch & 1) * 2;
#pragma unroll
      for (int ii = 0; ii < 2; ++ii) {
#pragma unroll
        for (int j = 0; j < 4; ++j) {
          int col = wn + j * 16 + rl;
#pragma unroll
          for (int r2 = 0; r2 < 4; ++r2) {
            int rowc = ii * 16 + g * 4 + r2;
            cw[rowc * 132 + col] = acc[ib + ii][j][r2];
          }
        }
      }
    }
    __syncthreads();
    for (int t = tid; t < 4096; t += 256) {
      int rowc = t >> 7, col = t & 127;
      int gc = n0 + col;
      if (gc < N)
        __builtin_nontemporal_store(cw[rowc * 132 + col],
                                    &outf[(size_t)(m0 + ch * 32 + rowc) * N + gc]);
    }
    __syncthreads();
  }
}

// ------- 64x128 block-tile GEMM, BK=64, dbuf (qkv fused epilogue) -----------
// MODE 4: fused qkv: bias + rope(q*1/8, k) -> qr/kr; v -> vT (2 heads/tile)
template <int MODE>
__global__ void k_gw(const u16* __restrict__ A, const u16* __restrict__ Bt,
                     const float* __restrict__ bias, u16* __restrict__ outb,
                     int M, int N, int K, int MT,
                     const float* __restrict__ ctab,
                     const float* __restrict__ stab, u16* __restrict__ qrp,
                     u16* __restrict__ krp, u16* __restrict__ vTp) {
  __shared__ u16 SM2[24576];
  float* cw = (float*)SM2;
  int nwg = gridDim.x;
  int id = blockIdx.x;
  if ((nwg & 7) == 0) id = (id & 7) * (nwg >> 3) + (id >> 3);  // XCD swizzle
  int mt = id % MT, nt = id / MT;
  int m0 = mt * 64, n0 = nt * 128;
  int tid = threadIdx.x;
  int w = tid >> 6, l = tid & 63;
  int row0 = tid >> 3, slot0 = tid & 7;
  int gs0 = slot0 ^ (row0 & 7);
  const u16* gA0 = A + (size_t)(m0 + row0) * K + gs0 * 8;
  const u16* gA1 = gA0 + (size_t)32 * K;
  const u16* gB0 = Bt + (size_t)(n0 + row0) * K + gs0 * 8;
  const u16* gB1 = gB0 + (size_t)32 * K;
  const u16* gB2 = gB0 + (size_t)64 * K;
  const u16* gB3 = gB0 + (size_t)96 * K;
  int wm = (w >> 1) * 32, wn = (w & 1) * 64;
  int rl = l & 15, g = l >> 4;
  int sl0 = g ^ (rl & 7), sl1 = (4 + g) ^ (rl & 7);
  f32x4 acc[2][4] = {};
  int nK = K >> 6;
  int cur = 0;
  {
    u16* dA = SM2;
    glds16(gA0, dA + w * 512); glds16(gA1, dA + 2048 + w * 512);
    u16* dB = SM2 + 8192;
    glds16(gB0, dB + w * 512);        glds16(gB1, dB + 2048 + w * 512);
    glds16(gB2, dB + 4096 + w * 512); glds16(gB3, dB + 6144 + w * 512);
  }
  __syncthreads();
  for (int kt = 0; kt < nK; ++kt) {
    if (kt + 1 < nK) {
      int ka = (kt + 1) * 64;
      u16* dA = SM2 + (cur ^ 1) * 4096;
      glds16(gA0 + ka, dA + w * 512); glds16(gA1 + ka, dA + 2048 + w * 512);
      u16* dB = SM2 + 8192 + (cur ^ 1) * 8192;
      glds16(gB0 + ka, dB + w * 512);        glds16(gB1 + ka, dB + 2048 + w * 512);
      glds16(gB2 + ka, dB + 4096 + w * 512); glds16(gB3 + ka, dB + 6144 + w * 512);
    }
    const u16* Ac = SM2 + cur * 4096;
    const u16* Bc = SM2 + 8192 + cur * 8192;
    bf16x8 a0[2], a1[2], b0[4], b1[4];
    __builtin_amdgcn_s_setprio(1);
#pragma unroll
    for (int i = 0; i < 2; ++i) {
      int r = (wm + i * 16 + rl) * 64;
      a0[i] = *(const bf16x8*)&Ac[r + sl0 * 8];
      a1[i] = *(const bf16x8*)&Ac[r + sl1 * 8];
    }
#pragma unroll
    for (int j = 0; j < 4; ++j) {
      int r = (wn + j * 16 + rl) * 64;
      b0[j] = *(const bf16x8*)&Bc[r + sl0 * 8];
      b1[j] = *(const bf16x8*)&Bc[r + sl1 * 8];
    }
#pragma unroll
    for (int i = 0; i < 2; ++i)
#pragma unroll
      for (int j = 0; j < 4; ++j) {
        acc[i][j] = __builtin_amdgcn_mfma_f32_16x16x32_bf16(a0[i], b0[j],
                                                            acc[i][j], 0, 0, 0);
        acc[i][j] = __builtin_amdgcn_mfma_f32_16x16x32_bf16(a1[i], b1[j],
                                                            acc[i][j], 0, 0, 0);
      }
    __builtin_amdgcn_s_setprio(0);
    __syncthreads();
    cur ^= 1;
  }
#pragma unroll
  for (int i = 0; i < 2; ++i) {
#pragma unroll
    for (int j = 0; j < 4; ++j) {
      int col = wn + j * 16 + rl;
      float bv = bias[n0 + col];
#pragma unroll
      for (int r2 = 0; r2 < 4; ++r2) {
        float v = acc[i][j][r2] + bv;
        if (MODE == 1) {
          float u = 0.7978845608028654f * (v + 0.044715f * v * v * v);
          v = 0.5f * v * (1.f + tanhf(u));
        }
        cw[(wm + i * 16 + g * 4 + r2) * 133 + col] = v;
      }
    }
  }
  __syncthreads();
  if (MODE == 1) {
    for (int t = tid; t < 4096; t += 256) {
      int rowc = t >> 6, cp = t & 63;
      u32 wv = (u32)f2bf(cw[rowc * 133 + 2 * cp]) |
               ((u32)f2bf(cw[rowc * 133 + 2 * cp + 1]) << 16);
      *(u32*)&outb[(size_t)(m0 + rowc) * N + n0 + 2 * cp] = wv;
    }
  } else {  // MODE 4
    int reg = n0 / DM;
    int h0 = (n0 % DM) / 64;
    int bb = m0 >> 10;
    int t0 = m0 & (SEQ - 1);
    size_t bhb = (size_t)bb * NH + h0;
    if (reg < 2) {
      u16* dst = (reg == 0) ? qrp : krp;
      float qs = (reg == 0) ? 0.125f : 1.f;
      for (int t = tid; t < 4096; t += 256) {
        int rowc = t >> 6, cp = t & 63;
        int c = 2 * cp;
        int hh = c >> 6, d = c & 63;
        int tt = t0 + rowc;
        float x0 = cw[rowc * 133 + c];
        float x1 = cw[rowc * 133 + c + 1];
        float o0, o1;
        if (d < 32) {
          float y0 = cw[rowc * 133 + c + 32];
          float y1 = cw[rowc * 133 + c + 33];
          float c0 = 1.f, s0 = 0.f, c1 = 1.f, s1 = 0.f;
          if (d < 16) {
            c0 = ctab[tt * 16 + d];     s0 = stab[tt * 16 + d];
            c1 = ctab[tt * 16 + d + 1]; s1 = stab[tt * 16 + d + 1];
          }
          o0 = x0 * c0 - y0 * s0;
          o1 = x1 * c1 - y1 * s1;
        } else {
          int j = d - 32;
          float y0 = cw[rowc * 133 + c - 32];
          float y1 = cw[rowc * 133 + c - 31];
          float c0 = 1.f, s0 = 0.f, c1 = 1.f, s1 = 0.f;
          if (j < 16) {
            c0 = ctab[tt * 16 + j];     s0 = stab[tt * 16 + j];
            c1 = ctab[tt * 16 + j + 1]; s1 = stab[tt * 16 + j + 1];
          }
          o0 = x0 * c0 + y0 * s0;
          o1 = x1 * c1 + y1 * s1;
        }
        u32 wv = (u32)f2bf(o0 * qs) | ((u32)f2bf(o1 * qs) << 16);
        *(u32*)&dst[((bhb + hh) * SEQ + tt) * HD2 + d] = wv;
      }
    } else {
      for (int t = tid; t < 4096; t += 256) {
        int dcol = t >> 5, p = t & 31;
        int hh = dcol >> 6, d = dcol & 63;
        int tt = t0 + 2 * p;
        u32 wv = (u32)f2bf(cw[(2 * p) * 133 + dcol]) |
                 ((u32)f2bf(cw[(2 * p + 1) * 133 + dcol]) << 16);
        *(u32*)&vTp[((bhb + hh) * HD2 + d) * SEQ + tt] = wv;
      }
    }
  }
}

// ------- merged wo+fc dispatch (independent after attn) ---------------------
// blocks [0, 768): fc 64x128 gelu (k_gw<1> body); [768, 1536): wo 64^2 splitK=2
__global__ void k_wofc(const u16* __restrict__ yb, const u16* __restrict__ woT,
                       const float* __restrict__ bo, float* __restrict__ xf,
                       const u16* __restrict__ h2b, const u16* __restrict__ wfcT,
                       const float* __restrict__ bfc, u16* __restrict__ hgel) {
  __shared__ u16 SM2[24576];
  int nwg = gridDim.x;
  int id = blockIdx.x;
  id = (id & 7) * (nwg >> 3) + (id >> 3);  // XCD swizzle (1536 % 8 == 0)
  int tid = threadIdx.x;
  int w = tid >> 6, l = tid & 63;
  int rl = l & 15, g = l >> 4;
  int row0 = tid >> 3, slot0 = tid & 7;
  int gs0 = slot0 ^ (row0 & 7);
  int sl0 = g ^ (rl & 7), sl1 = (4 + g) ^ (rl & 7);
  if (id < 768) {
    // ---- fc body: C[2048,3072] = h2b * wfcT^T, gelu, bf16 out ----
    float* cw = (float*)SM2;
    int mt = id % 32, nt = id / 32;
    int m0 = mt * 64, n0 = nt * 128;
    const int K = DM, N = 4 * DM;
    const u16* gA0 = h2b + (size_t)(m0 + row0) * K + gs0 * 8;
    const u16* gA1 = gA0 + (size_t)32 * K;
    const u16* gB0 = wfcT + (size_t)(n0 + row0) * K + gs0 * 8;
    const u16* gB1 = gB0 + (size_t)32 * K;
    const u16* gB2 = gB0 + (size_t)64 * K;
    const u16* gB3 = gB0 + (size_t)96 * K;
    int wm = (w >> 1) * 32, wn = (w & 1) * 64;
    f32x4 acc[2][4] = {};
    int nK = K >> 6;
    int cur = 0;
    {
      u16* dA = SM2;
      glds16(gA0, dA + w * 512); glds16(gA1, dA + 2048 + w * 512);
      u16* dB = SM2 + 8192;
      glds16(gB0, dB + w * 512);        glds16(gB1, dB + 2048 + w * 512);
      glds16(gB2, dB + 4096 + w * 512); glds16(gB3, dB + 6144 + w * 512);
    }
    __syncthreads();
    for (int kt = 0; kt < nK; ++kt) {
      if (kt + 1 < nK) {
        int ka = (kt + 1) * 64;
        u16* dA = SM2 + (cur ^ 1) * 4096;
        glds16(gA0 + ka, dA + w * 512); glds16(gA1 + ka, dA + 2048 + w * 512);
        u16* dB = SM2 + 8192 + (cur ^ 1) * 8192;
        glds16(gB0 + ka, dB + w * 512);        glds16(gB1 + ka, dB + 2048 + w * 512);
        glds16(gB2 + ka, dB + 4096 + w * 512); glds16(gB3 + ka, dB + 6144 + w * 512);
      }
      const u16* Ac = SM2 + cur * 4096;
      const u16* Bc = SM2 + 8192 + cur * 8192;
      bf16x8 a0[2], a1[2], b0[4], b1[4];
      __builtin_amdgcn_s_setprio(1);
#pragma unroll
      for (int i = 0; i < 2; ++i) {
        int r = (wm + i * 16 + rl) * 64;
        a0[i] = *(const bf16x8*)&Ac[r + sl0 * 8];
        a1[i] = *(const bf16x8*)&Ac[r + sl1 * 8];
      }
#pragma unroll
      for (int j = 0; j < 4; ++j) {
        int r = (wn + j * 16 + rl) * 64;
        b0[j] = *(const bf16x8*)&Bc[r + sl0 * 8];
        b1[j] = *(const bf16x8*)&Bc[r + sl1 * 8];
      }
#pragma unroll
      for (int i = 0; i < 2; ++i)
#pragma unroll
        for (int j = 0; j < 4; ++j) {
          acc[i][j] = __builtin_amdgcn_mfma_f32_16x16x32_bf16(a0[i], b0[j],
                                                              acc[i][j], 0, 0, 0);
          acc[i][j] = __builtin_amdgcn_mfma_f32_16x16x32_bf16(a1[i], b1[j],
                                                              acc[i][j], 0, 0, 0);
        }
      __builtin_amdgcn_s_setprio(0);
      __syncthreads();
      cur ^= 1;
    }
#pragma unroll
    for (int i = 0; i < 2; ++i) {
#pragma unroll
      for (int j = 0; j < 4; ++j) {
        int col = wn + j * 16 + rl;
        float bv = bfc[n0 + col];
#pragma unroll
        for (int r2 = 0; r2 < 4; ++r2) {
          float v = acc[i][j][r2] + bv;
          float u = 0.7978845608028654f * (v + 0.044715f * v * v * v);
          v = 0.5f * v * (1.f + tanhf(u));
          cw[(wm + i * 16 + g * 4 + r2) * 133 + col] = v;
        }
      }
    }
    __syncthreads();
    for (int t = tid; t < 4096; t += 256) {
      int rowc = t >> 6, cp = t & 63;
      u32 wv = (u32)f2bf(cw[rowc * 133 + 2 * cp]) |
               ((u32)f2bf(cw[rowc * 133 + 2 * cp + 1]) << 16);
      *(u32*)&hgel[(size_t)(m0 + rowc) * N + n0 + 2 * cp] = wv;
    }
    return;
  }
  // ---- wo body: xf += yb * woT^T (+bo at sk0), 64^2, split-K 2 ----
  {
    int id2 = id - 768;
    int sk = id2 / 384, t = id2 % 384;
    int mt = t % 32, nt = t / 32;
    int m0 = mt * 64, n0 = nt * 64;
    const int K = DM, N = DM;
    int Kc = K / 2, k0 = sk * Kc;
    u16* As = SM2;
    u16* Bs = SM2 + 8192;
    const u16* gA0 = yb + (size_t)(m0 + row0) * K + k0 + gs0 * 8;
    const u16* gA1 = gA0 + (size_t)32 * K;
    const u16* gB0 = woT + (size_t)(n0 + row0) * K + k0 + gs0 * 8;
    const u16* gB1 = gB0 + (size_t)32 * K;
    int wm = (w >> 1) * 32, wn = (w & 1) * 32;
    f32x4 acc[2][2] = {};
    int nK = Kc >> 6;
    int cur = 0;
    {
      glds16(gA0, As + w * 512); glds16(gA1, As + 2048 + w * 512);
      glds16(gB0, Bs + w * 512); glds16(gB1, Bs + 2048 + w * 512);
    }
    __syncthreads();
    for (int kt = 0; kt < nK; ++kt) {
      if (kt + 1 < nK) {
        int nx = (cur ^ 1) * 4096;
        glds16(gA0 + (kt + 1) * 64, As + nx + w * 512);
        glds16(gA1 + (kt + 1) * 64, As + nx + 2048 + w * 512);
        glds16(gB0 + (kt + 1) * 64, Bs + nx + w * 512);
        glds16(gB1 + (kt + 1) * 64, Bs + nx + 2048 + w * 512);
      }
      const u16* Ac = As + cur * 4096;
      const u16* Bc = Bs + cur * 4096;
      bf16x8 a0[2], a1[2], b0[2], b1[2];
      __builtin_amdgcn_s_setprio(1);
#pragma unroll
      for (int i = 0; i < 2; ++i) {
        int r = (wm + i * 16 + rl) * 64;
        a0[i] = *(const bf16x8*)&Ac[r + sl0 * 8];
        a1[i] = *(const bf16x8*)&Ac[r + sl1 * 8];
      }
#pragma unroll
      for (int j = 0; j < 2; ++j) {
        int r = (wn + j * 16 + rl) * 64;
        b0[j] = *(const bf16x8*)&Bc[r + sl0 * 8];
        b1[j] = *(const bf16x8*)&Bc[r + sl1 * 8];
      }
#pragma unroll
      for (int i = 0; i < 2; ++i)
#pragma unroll
        for (int j = 0; j < 2; ++j) {
          acc[i][j] = __builtin_amdgcn_mfma_f32_16x16x32_bf16(a0[i], b0[j],
                                                              acc[i][j], 0, 0, 0);
          acc[i][j] = __builtin_amdgcn_mfma_f32_16x16x32_bf16(a1[i], b1[j],
                                                              acc[i][j], 0, 0, 0);
        }
      __builtin_amdgcn_s_setprio(0);
      __syncthreads();
      cur ^= 1;
    }
#pragma unroll
    for (int i = 0; i < 2; ++i) {
#pragma unroll
      for (int j = 0; j < 2; ++j) {
        int col = n0 + wn + j * 16 + rl;
        float bv = bo[col];
#pragma unroll
        for (int r2 = 0; r2 < 4; ++r2) {
          int row = m0 + wm + i * 16 + g * 4 + r2;
          float v = acc[i][j][r2];
          if (sk == 0) v += bv;
          atomicAdd(&xf[(size_t)row * N + col], v);
        }
      }
    }
  }
}

// ------- 64x64-tile GEMM, BK=64, dbuf, split-K residual add (wp) ------------
__global__ void k_g64r(const u16* __restrict__ A, const u16* __restrict__ Bt,
                       const float* __restrict__ bias,
                       float* __restrict__ outf, int M, int N, int K, int MT) {
  __shared__ u16 As[8192];
  __shared__ u16 Bs[8192];
  int nwg = gridDim.x;
  int id = blockIdx.x;
  if ((nwg & 7) == 0) id = (id & 7) * (nwg >> 3) + (id >> 3);  // XCD swizzle
  int mt = id % MT, nt = id / MT;
  int sk = blockIdx.y, nsk = gridDim.y;
  int Kc = K / nsk, k0 = sk * Kc;
  int m0 = mt * 64, n0 = nt * 64;
  int tid = threadIdx.x;
  int w = tid >> 6, l = tid & 63;
  int row0 = tid >> 3, slot0 = tid & 7;
  int gs0 = slot0 ^ (row0 & 7);
  const u16* gA0 = A + (size_t)(m0 + row0) * K + k0 + gs0 * 8;
  const u16* gA1 = gA0 + (size_t)32 * K;
  const u16* gB0 = Bt + (size_t)(n0 + row0) * K + k0 + gs0 * 8;
  const u16* gB1 = gB0 + (size_t)32 * K;
  int wm = (w >> 1) * 32, wn = (w & 1) * 32;
  int rl = l & 15, g = l >> 4;
  int sl0 = g ^ (rl & 7), sl1 = (4 + g) ^ (rl & 7);
  f32x4 acc[2][2] = {};
  int nK = Kc >> 6;
  int cur = 0;
  {
    glds16(gA0, As + w * 512); glds16(gA1, As + 2048 + w * 512);
    glds16(gB0, Bs + w * 512); glds16(gB1, Bs + 2048 + w * 512);
  }
  __syncthreads();
  for (int kt = 0; kt < nK; ++kt) {
    if (kt + 1 < nK) {
      int nx = (cur ^ 1) * 4096;
      glds16(gA0 + (kt + 1) * 64, As + nx + w * 512);
      glds16(gA1 + (kt + 1) * 64, As + nx + 2048 + w * 512);
      glds16(gB0 + (kt + 1) * 64, Bs + nx + w * 512);
      glds16(gB1 + (kt + 1) * 64, Bs + nx + 2048 + w * 512);
    }
    const u16* Ac = As + cur * 4096;
    const u16* Bc = Bs + cur * 4096;
    bf16x8 a0[2], a1[2], b0[2], b1[2];
    __builtin_amdgcn_s_setprio(1);
#pragma unroll
    for (int i = 0; i < 2; ++i) {
      int r = (wm + i * 16 + rl) * 64;
      a0[i] = *(const bf16x8*)&Ac[r + sl0 * 8];
      a1[i] = *(const bf16x8*)&Ac[r + sl1 * 8];
    }
#pragma unroll
    for (int j = 0; j < 2; ++j) {
      int r = (wn + j * 16 + rl) * 64;
      b0[j] = *(const bf16x8*)&Bc[r + sl0 * 8];
      b1[j] = *(const bf16x8*)&Bc[r + sl1 * 8];
    }
#pragma unroll
    for (int i = 0; i < 2; ++i)
#pragma unroll
      for (int j = 0; j < 2; ++j) {
        acc[i][j] = __builtin_amdgcn_mfma_f32_16x16x32_bf16(a0[i], b0[j],
                                                            acc[i][j], 0, 0, 0);
        acc[i][j] = __builtin_amdgcn_mfma_f32_16x16x32_bf16(a1[i], b1[j],
                                                            acc[i][j], 0, 0, 0);
      }
    __builtin_amdgcn_s_setprio(0);
    __syncthreads();
    cur ^= 1;
  }
#pragma unroll
  for (int i = 0; i < 2; ++i) {
#pragma unroll
    for (int j = 0; j < 2; ++j) {
      int col = n0 + wn + j * 16 + rl;
      float bv = bias ? bias[col] : 0.f;
#pragma unroll
      for (int r2 = 0; r2 < 4; ++r2) {
        int row = m0 + wm + i * 16 + g * 4 + r2;
        float v = acc[i][j][r2];
        if (sk == 0) v += bv;
        atomicAdd(&outf[(size_t)row * N + col], v);
      }
    }
  }
}

// ---------------- fallback GEMM (f32 B, on-the-fly cvt) — logits only --------
__global__ void k_gemm_f32b(const u16* __restrict__ A, const float* __restrict__ B,
                            float* __restrict__ outf, int M, int N, int K) {
  __shared__ u16 As[128 * 40];
  __shared__ u16 Bs[4 * 128 * 12];
  int tid = threadIdx.x;
  int wid = tid >> 6, lane = tid & 63;
  int rl = lane & 15, g = lane >> 4;
  int m0 = blockIdx.x * 128, n0 = blockIdx.y * 128;
  int wm = (wid >> 1) * 64, wn = (wid & 1) * 64;
  int ar = tid >> 2, ac = tid & 3;
  int bn = tid & 127, bq = tid >> 7;
  f32x4 acc[4][4] = {};
  int nK = K / 32;
  for (int kt = 0; kt < nK; ++kt) {
    __syncthreads();
    {
      const u16* ga = A + (size_t)(m0 + ar) * K + kt * 32 + ac * 8;
      *(uint4*)&As[ar * 40 + ac * 8] = *(const uint4*)ga;
      *(uint4*)&As[(ar + 64) * 40 + ac * 8] = *(const uint4*)(ga + (size_t)64 * K);
    }
    int col = n0 + bn;
#pragma unroll
    for (int r = 0; r < 4; ++r) {
      int kq = bq + 2 * r;
      int kk = kt * 32 + kq * 4;
      float f0 = 0.f, f1 = 0.f, f2v = 0.f, f3 = 0.f;
      if (col < N) {
        const float* gb = B + (size_t)kk * N + col;
        f0 = gb[0]; f1 = gb[(size_t)N]; f2v = gb[(size_t)2 * N]; f3 = gb[(size_t)3 * N];
      }
      uint2 wv;
      wv.x = (u32)f2bf(f0) | ((u32)f2bf(f1) << 16);
      wv.y = (u32)f2bf(f2v) | ((u32)f2bf(f3) << 16);
      *(uint2*)&Bs[(kq >> 1) * 1536 + bn * 12 + (kq & 1) * 4] = wv;
    }
    __syncthreads();
    bf16x8 af[4], bfr[4];
#pragma unroll
    for (int mt = 0; mt < 4; ++mt)
      af[mt] = *(const bf16x8*)&As[(wm + mt * 16 + rl) * 40 + g * 8];
#pragma unroll
    for (int nt = 0; nt < 4; ++nt) {
      const u16* p = &Bs[g * 1536 + (wn + nt * 16 + rl) * 12];
      union { bf16x8 v; uint2 u2[2]; } tmp;
      tmp.u2[0] = *(const uint2*)p;
      tmp.u2[1] = *(const uint2*)(p + 4);
      bfr[nt] = tmp.v;
    }
#pragma unroll
    for (int mt = 0; mt < 4; ++mt)
#pragma unroll
      for (int nt = 0; nt < 4; ++nt)
        acc[mt][nt] = __builtin_amdgcn_mfma_f32_16x16x32_bf16(af[mt], bfr[nt],
                                                              acc[mt][nt], 0, 0, 0);
  }
#pragma unroll
  for (int mt = 0; mt < 4; ++mt)
#pragma unroll
    for (int nt = 0; nt < 4; ++nt) {
      int col = n0 + wn + nt * 16 + rl;
      if (col >= N) continue;
#pragma unroll
      for (int r2 = 0; r2 < 4; ++r2) {
        int row = m0 + wm + mt * 16 + g * 4 + r2;
        outf[(size_t)row * N + col] = acc[mt][nt][r2];
      }
    }
}

extern "C" void kernel_launch(void* const* d_in, const int* in_sizes, int n_in,
                              void* d_out, int out_size, void* d_ws, size_t ws_size,
                              hipStream_t stream) {
  (void)in_sizes; (void)n_in; (void)out_size;
  const int*   idx  = (const int*)  d_in[0];
  const float* wte  = (const float*)d_in[1];
  const float* ln1g = (const float*)d_in[2];
  const float* ln1b = (const float*)d_in[3];
  const float* Wqkv = (const float*)d_in[4];
  const float* bqkv = (const float*)d_in[5];
  const float* Wo   = (const float*)d_in[6];
  const float* bo   = (const float*)d_in[7];
  const float* ln2g = (const float*)d_in[8];
  const float* ln2b = (const float*)d_in[9];
  const float* Wfc  = (const float*)d_in[10];
  const float* bfc  = (const float*)d_in[11];
  const float* Wp   = (const float*)d_in[12];
  const float* bp   = (const float*)d_in[13];
  const float* lnfg = (const float*)d_in[14];
  const float* lnfb = (const float*)d_in[15];
  const float* Wlm  = (const float*)d_in[16];
  float* out = (float*)d_out;

  // Scratch packed into d_out (all dead before the logits GEMM rewrites d_out).
  char* sb = (char*)d_out;
  size_t off = 0;
  auto alloc = [&](size_t bytes) {
    char* p = sb + off;
    off += (bytes + 255) & ~(size_t)255;
    return (void*)p;
  };
  float* xf  = (float*)alloc((size_t)BT * DM * 4);
  u16* h1b   = (u16*)alloc((size_t)BT * DM * 2);
  u16* h2b   = (u16*)alloc((size_t)BT * DM * 2);
  u16* qr    = (u16*)alloc((size_t)BT * DM * 2);
  u16* kr    = (u16*)alloc((size_t)BT * DM * 2);
  u16* vT    = (u16*)alloc((size_t)BT * DM * 2);
  u16* yb    = (u16*)alloc((size_t)BT * DM * 2);
  u16* hgel  = (u16*)alloc((size_t)BT * 4 * DM * 2);
  float* ctab = (float*)alloc((size_t)SEQ * 16 * 4);
  float* stab = (float*)alloc((size_t)SEQ * 16 * 4);
  // transposed bf16 weights (also dead before logits GEMM)
  u16* wqkvT = (u16*)alloc((size_t)NLAYER * 3 * DM * DM * 2);
  u16* woT   = (u16*)alloc((size_t)NLAYER * DM * DM * 2);
  u16* wfcT  = (u16*)alloc((size_t)NLAYER * 4 * DM * DM * 2);
  u16* wpT   = (u16*)alloc((size_t)NLAYER * 4 * DM * DM * 2);

  // Wlm^T (77 MB) must survive the logits GEMM -> d_ws if it fits.
  size_t wlmT_bytes = (size_t)NVOCAB * DM * 2;
  size_t xlnf_bytes = (size_t)BT * DM * 2;
  bool fast_lm = ws_size >= wlmT_bytes + xlnf_bytes + 512;
  u16* wlmT = (u16*)d_ws;
  u16* xlnf = fast_lm ? (u16*)((char*)d_ws + ((wlmT_bytes + 255) & ~(size_t)255))
                      : (u16*)d_ws;

  // ---- single mega-prologue dispatch: embed + trig + all weight conversion -
  int prep_blocks = BT + 64 + NLAYER * 1728 + (fast_lm ? 9432 : 0);
  k_prep<<<prep_blocks, 256, 0, stream>>>(idx, wte, xf, ctab, stab,
                                          Wqkv, Wo, Wfc, Wp, Wlm,
                                          wqkvT, woT, wfcT, wpT, wlmT);

  for (int l = 0; l < NLAYER; ++l) {
    k_ln<<<BT / 4, 256, 0, stream>>>(xf, ln1g + l * DM, ln1b + l * DM,
                                     ln2g + l * DM, ln2b + l * DM, h1b, h2b);
    k_gw<4><<<(BT / 64) * (3 * DM / 128), 256, 0, stream>>>(
        h1b, wqkvT + (size_t)l * 3 * DM * DM, bqkv + (size_t)l * 3 * DM,
        nullptr, BT, 3 * DM, DM, BT / 64, ctab, stab, qr, kr, vT);
    k_attn<<<dim3(SEQ / 64, 2 * NH), 256, 0, stream>>>(qr, kr, vT, yb);
    // merged wo (residual) + fc (gelu) — independent after attn
    k_wofc<<<1536, 256, 0, stream>>>(
        yb, woT + (size_t)l * DM * DM, bo + (size_t)l * DM, xf,
        h2b, wfcT + (size_t)l * 4 * DM * DM, bfc + (size_t)l * 4 * DM, hgel);
    k_g64r<<<dim3((BT / 64) * (DM / 64), 4), 256, 0, stream>>>(
        hgel, wpT + (size_t)l * 4 * DM * DM, bp + (size_t)l * DM, xf, BT, DM, 4 * DM,
        BT / 64);
  }
  k_ln<<<BT / 4, 256, 0, stream>>>(xf, lnfg, lnfb, nullptr, nullptr, xlnf, nullptr);
  if (fast_lm) {
    int nt = (NVOCAB + 127) / 128;
    k_g128<3><<<(BT / 128) * nt, 256, 0, stream>>>(
        xlnf, wlmT, out, BT, NVOCAB, DM, BT / 128);
  } else {
    k_gemm_f32b<<<dim3(BT / 128, (NVOCAB + 127) / 128), 256, 0, stream>>>(
        xlnf, Wlm, out, BT, NVOCAB, DM);
  }
}